// Round 1
// baseline (533.695 us; speedup 1.0000x reference)
//
#include <hip/hip_runtime.h>
#include <cstdint>
#include <cstddef>

// Problem constants (match reference setup_inputs)
#define B_TOK   16384
#define IN_DIM  2048
#define D_DIM   1024
#define NEXP    3
#define TOPK    2
#define H1_DIM  1024
#define H2_DIM  512

typedef __bf16 bf16x8 __attribute__((ext_vector_type(8)));
typedef float  f32x4  __attribute__((ext_vector_type(4)));
typedef unsigned short ushort8_t __attribute__((ext_vector_type(8)));

__device__ __forceinline__ unsigned short f2bf(float f) {
    unsigned int u = __builtin_bit_cast(unsigned int, f);
    return (unsigned short)((u + 0x7fffu + ((u >> 16) & 1u)) >> 16);
}

// async global->LDS, 16B per lane. LDS dest is wave-uniform base + lane*16.
__device__ __forceinline__ void glds16(const void* gsrc, void* ldst) {
    __builtin_amdgcn_global_load_lds(
        (__attribute__((address_space(1))) void*)(gsrc),
        (__attribute__((address_space(3))) void*)(ldst),
        16, 0, 0);
}

// ---------------- prepass kernels ----------------

__global__ __launch_bounds__(256) void convert_f32_bf16(
    const float* __restrict__ in, unsigned short* __restrict__ out, size_t n)
{
    size_t i = ((size_t)blockIdx.x * blockDim.x + threadIdx.x) * 8;
    size_t stride = (size_t)gridDim.x * blockDim.x * 8;
    for (; i < n; i += stride) {
        float4 a = *(const float4*)(in + i);
        float4 b = *(const float4*)(in + i + 4);
        ushort8_t o;
        o[0] = f2bf(a.x); o[1] = f2bf(a.y); o[2] = f2bf(a.z); o[3] = f2bf(a.w);
        o[4] = f2bf(b.x); o[5] = f2bf(b.y); o[6] = f2bf(b.z); o[7] = f2bf(b.w);
        *(ushort8_t*)(out + i) = o;
    }
}

// W [E][K][N] f32 -> Wt [E][N][K] bf16, 64x64 tiles through LDS
__global__ __launch_bounds__(256) void transpose_convert(
    const float* __restrict__ W, unsigned short* __restrict__ Wt, int K, int N)
{
    __shared__ unsigned short tile[64][68];
    int e = blockIdx.z;
    const float* Wp = W + (size_t)e * K * N;
    unsigned short* Wtp = Wt + (size_t)e * N * K;
    int n0 = blockIdx.x * 64, k0 = blockIdx.y * 64;
    int t = threadIdx.x;
    int nn = (t & 15) * 4;
    int kk = t >> 4;
    #pragma unroll
    for (int r = 0; r < 4; ++r) {
        int k = kk + r * 16;
        float4 v = *(const float4*)(Wp + (size_t)(k0 + k) * N + (n0 + nn));
        tile[k][nn + 0] = f2bf(v.x);
        tile[k][nn + 1] = f2bf(v.y);
        tile[k][nn + 2] = f2bf(v.z);
        tile[k][nn + 3] = f2bf(v.w);
    }
    __syncthreads();
    int n  = t >> 2;
    int kb = (t & 3) * 16;
    ushort8_t o0, o1;
    #pragma unroll
    for (int i = 0; i < 8; ++i) o0[i] = tile[kb + i][n];
    #pragma unroll
    for (int i = 0; i < 8; ++i) o1[i] = tile[kb + 8 + i][n];
    unsigned short* dst = Wtp + (size_t)(n0 + n) * K + (k0 + kb);
    *(ushort8_t*)dst = o0;
    *(ushort8_t*)(dst + 8) = o1;
}

// wcomb[e][b] = sum_k probs[b,k] * (idx[b,k]==e)
__global__ __launch_bounds__(256) void compute_wcomb(
    const float* __restrict__ probs, const int* __restrict__ idx,
    float* __restrict__ wcomb, int Bn)
{
    int b = blockIdx.x * blockDim.x + threadIdx.x;
    if (b >= Bn) return;
    float p0 = probs[b * TOPK + 0], p1 = probs[b * TOPK + 1];
    int   i0 = idx[b * TOPK + 0],   i1 = idx[b * TOPK + 1];
    #pragma unroll
    for (int e = 0; e < NEXP; ++e) {
        float w = (i0 == e ? p0 : 0.f) + (i1 == e ? p1 : 0.f);
        wcomb[(size_t)e * Bn + b] = w;
    }
}

// ---------------- GEMM: C = act(A[M,K] @ Bt[N,K]^T + bias) ----------------
// m97-structure: 128x128 tile, BK=32, 4 waves (2x2), mfma 16x16x32 bf16,
// linear LDS + global_load_lds(16B), 2 barriers per K-step.
template<int ACT, int FINAL, int ACCUM>
__global__ __launch_bounds__(256, 2) void gemm_bf16(
    const unsigned short* __restrict__ A,   // [M][K] bf16
    const unsigned short* __restrict__ Bt,  // [N][K] bf16
    const float* __restrict__ bias,         // [N]
    unsigned short* __restrict__ H,         // [M][N] bf16 (if !FINAL)
    float* __restrict__ out,                // [M][N] f32  (if FINAL)
    const float* __restrict__ wrow,         // [M]          (if FINAL)
    int M, int N, int K)
{
    __shared__ unsigned short lds[8192];    // A tile 8KB @0, B tile 8KB @8192
    char* ldsc = (char*)lds;
    const int tid  = threadIdx.x;
    const int lane = tid & 63;
    const int wid  = tid >> 6;
    const int bm = blockIdx.y << 7;
    const int bn = blockIdx.x << 7;
    const int wr = wid >> 1, wc = wid & 1;

    f32x4 acc[4][4] = {};

    // staging: wave wid covers rows [wid*32, wid*32+32) of the 128-row tile,
    // two 1KB segments (16 rows each); lane -> (row = seg + lane/4, col8 = (lane&3)*8)
    const int srow = (wid << 5) + (lane >> 2);
    const unsigned short* pa = A  + (size_t)(bm + srow) * K + ((lane & 3) << 3);
    const unsigned short* pb = Bt + (size_t)(bn + srow) * K + ((lane & 3) << 3);
    char* la0 = ldsc + (wid << 11);
    char* lb0 = ldsc + 8192 + (wid << 11);
    const size_t rowK16 = (size_t)16 * K;

    // fragment read pointers: row = warp_row*64 + (lane&15) (+ mi*16), kbyte = (lane>>4)*16
    const char* fA = ldsc + ((wr << 6) + (lane & 15)) * 64 + ((lane >> 4) << 4);
    const char* fB = ldsc + 8192 + ((wc << 6) + (lane & 15)) * 64 + ((lane >> 4) << 4);

    for (int k0 = 0; k0 < K; k0 += 32) {
        glds16(pa + k0,          la0);
        glds16(pa + k0 + rowK16, la0 + 1024);
        glds16(pb + k0,          lb0);
        glds16(pb + k0 + rowK16, lb0 + 1024);
        __syncthreads();   // drains vmcnt + lgkm before compute
        bf16x8 av[4], bv[4];
        #pragma unroll
        for (int mi = 0; mi < 4; ++mi) av[mi] = *(const bf16x8*)(fA + (mi << 10));
        #pragma unroll
        for (int ni = 0; ni < 4; ++ni) bv[ni] = *(const bf16x8*)(fB + (ni << 10));
        #pragma unroll
        for (int mi = 0; mi < 4; ++mi)
            #pragma unroll
            for (int ni = 0; ni < 4; ++ni)
                acc[mi][ni] = __builtin_amdgcn_mfma_f32_16x16x32_bf16(
                    av[mi], bv[ni], acc[mi][ni], 0, 0, 0);
        __syncthreads();   // compute done before next-stage overwrite
    }

    // epilogue. C/D layout (m89-verified): col = lane&15, row = (lane>>4)*4 + j
    const int coffs = lane & 15;
    const int rbase = (lane >> 4) << 2;
    const int r0 = bm + (wr << 6) + rbase;
    const int c0 = bn + (wc << 6) + coffs;

    if constexpr (!FINAL) {
        #pragma unroll
        for (int mi = 0; mi < 4; ++mi) {
            #pragma unroll
            for (int j = 0; j < 4; ++j) {
                int r = r0 + mi * 16 + j;
                size_t ro = (size_t)r * N;
                #pragma unroll
                for (int ni = 0; ni < 4; ++ni) {
                    int c = c0 + ni * 16;
                    float v = acc[mi][ni][j] + bias[c];
                    if (ACT) v = v > 0.f ? v : 0.2f * v;
                    H[ro + c] = f2bf(v);
                }
            }
        }
    } else {
        #pragma unroll
        for (int mi = 0; mi < 4; ++mi) {
            #pragma unroll
            for (int j = 0; j < 4; ++j) {
                int r = r0 + mi * 16 + j;
                size_t ro = (size_t)r * N;
                float w = wrow[r];
                #pragma unroll
                for (int ni = 0; ni < 4; ++ni) {
                    int c = c0 + ni * 16;
                    float v = (acc[mi][ni][j] + bias[c]) * w;
                    if (ACCUM) out[ro + c] += v;
                    else       out[ro + c] = v;
                }
            }
        }
    }
}

// ---------------- host launch ----------------

extern "C" void kernel_launch(void* const* d_in, const int* in_sizes, int n_in,
                              void* d_out, int out_size, void* d_ws, size_t ws_size,
                              hipStream_t stream)
{
    const float* x     = (const float*)d_in[0];
    // d_in[1] = gate (unused by reference forward)
    const float* probs = (const float*)d_in[2];
    const int*   tidx  = (const int*)d_in[3];
    const float* W1    = (const float*)d_in[4];
    const float* b1    = (const float*)d_in[5];
    const float* W2    = (const float*)d_in[6];
    const float* b2    = (const float*)d_in[7];
    const float* W3    = (const float*)d_in[8];
    const float* b3    = (const float*)d_in[9];
    float* out = (float*)d_out;

    // workspace layout (bytes)
    char* ws = (char*)d_ws;
    const size_t xb_off  = 0;                                       // 67108864
    const size_t w1t_off = xb_off  + (size_t)B_TOK * IN_DIM * 2;    // 12582912
    const size_t w2t_off = w1t_off + (size_t)NEXP * IN_DIM * H1_DIM * 2;
    const size_t w3t_off = w2t_off + (size_t)NEXP * H1_DIM * H2_DIM * 2;
    const size_t h1_off  = w3t_off + (size_t)NEXP * H2_DIM * D_DIM * 2;
    const size_t h2_off  = h1_off  + (size_t)B_TOK * H1_DIM * 2;
    const size_t wc_off  = h2_off  + (size_t)B_TOK * H2_DIM * 2;

    unsigned short* xb  = (unsigned short*)(ws + xb_off);
    unsigned short* W1t = (unsigned short*)(ws + w1t_off);
    unsigned short* W2t = (unsigned short*)(ws + w2t_off);
    unsigned short* W3t = (unsigned short*)(ws + w3t_off);
    unsigned short* h1  = (unsigned short*)(ws + h1_off);
    unsigned short* h2  = (unsigned short*)(ws + h2_off);
    float*          wcb = (float*)(ws + wc_off);

    // prepass
    convert_f32_bf16<<<2048, 256, 0, stream>>>(x, xb, (size_t)B_TOK * IN_DIM);
    transpose_convert<<<dim3(H1_DIM / 64, IN_DIM / 64, NEXP), 256, 0, stream>>>(W1, W1t, IN_DIM, H1_DIM);
    transpose_convert<<<dim3(H2_DIM / 64, H1_DIM / 64, NEXP), 256, 0, stream>>>(W2, W2t, H1_DIM, H2_DIM);
    transpose_convert<<<dim3(D_DIM / 64, H2_DIM / 64, NEXP), 256, 0, stream>>>(W3, W3t, H2_DIM, D_DIM);
    compute_wcomb<<<B_TOK / 256, 256, 0, stream>>>(probs, tidx, wcb, B_TOK);

    // per-expert 3-layer MLP + weighted accumulate into out
    for (int e = 0; e < NEXP; ++e) {
        gemm_bf16<1, 0, 0><<<dim3(H1_DIM / 128, B_TOK / 128), 256, 0, stream>>>(
            xb, W1t + (size_t)e * H1_DIM * IN_DIM, b1 + (size_t)e * H1_DIM,
            h1, nullptr, nullptr, B_TOK, H1_DIM, IN_DIM);
        gemm_bf16<1, 0, 0><<<dim3(H2_DIM / 128, B_TOK / 128), 256, 0, stream>>>(
            h1, W2t + (size_t)e * H2_DIM * H1_DIM, b2 + (size_t)e * H2_DIM,
            h2, nullptr, nullptr, B_TOK, H2_DIM, H1_DIM);
        if (e == 0) {
            gemm_bf16<0, 1, 0><<<dim3(D_DIM / 128, B_TOK / 128), 256, 0, stream>>>(
                h2, W3t + (size_t)e * D_DIM * H2_DIM, b3 + (size_t)e * D_DIM,
                nullptr, out, wcb + (size_t)e * B_TOK, B_TOK, D_DIM, H2_DIM);
        } else {
            gemm_bf16<0, 1, 1><<<dim3(D_DIM / 128, B_TOK / 128), 256, 0, stream>>>(
                h2, W3t + (size_t)e * D_DIM * H2_DIM, b3 + (size_t)e * D_DIM,
                nullptr, out, wcb + (size_t)e * B_TOK, B_TOK, D_DIM, H2_DIM);
        }
    }
}

// Round 2
// 437.545 us; speedup vs baseline: 1.2197x; 1.2197x over previous
//
#include <hip/hip_runtime.h>
#include <cstdint>
#include <cstddef>

// Problem constants (match reference setup_inputs)
#define B_TOK   16384
#define IN_DIM  2048
#define D_DIM   1024
#define NEXP    3
#define TOPK    2
#define H1_DIM  1024
#define H2_DIM  512

typedef __bf16 bf16x8 __attribute__((ext_vector_type(8)));
typedef float  f32x4  __attribute__((ext_vector_type(4)));
typedef unsigned short ushort8_t __attribute__((ext_vector_type(8)));

__device__ __forceinline__ unsigned short f2bf(float f) {
    unsigned int u = __builtin_bit_cast(unsigned int, f);
    return (unsigned short)((u + 0x7fffu + ((u >> 16) & 1u)) >> 16);
}

// async global->LDS, 16B per lane. LDS dest is wave-uniform base + lane*16;
// global source address IS per-lane (enables gather).
__device__ __forceinline__ void glds16(const void* gsrc, void* ldst) {
    __builtin_amdgcn_global_load_lds(
        (__attribute__((address_space(1))) void*)(gsrc),
        (__attribute__((address_space(3))) void*)(ldst),
        16, 0, 0);
}

// ---------------- prepass kernels ----------------

__global__ __launch_bounds__(256) void convert_f32_bf16(
    const float* __restrict__ in, unsigned short* __restrict__ out, size_t n)
{
    size_t i = ((size_t)blockIdx.x * blockDim.x + threadIdx.x) * 8;
    size_t stride = (size_t)gridDim.x * blockDim.x * 8;
    for (; i < n; i += stride) {
        float4 a = *(const float4*)(in + i);
        float4 b = *(const float4*)(in + i + 4);
        ushort8_t o;
        o[0] = f2bf(a.x); o[1] = f2bf(a.y); o[2] = f2bf(a.z); o[3] = f2bf(a.w);
        o[4] = f2bf(b.x); o[5] = f2bf(b.y); o[6] = f2bf(b.z); o[7] = f2bf(b.w);
        *(ushort8_t*)(out + i) = o;
    }
}

// W [E][K][N] f32 -> Wt [E][N][K] bf16, 64x64 tiles through LDS
__global__ __launch_bounds__(256) void transpose_convert(
    const float* __restrict__ W, unsigned short* __restrict__ Wt, int K, int N)
{
    __shared__ unsigned short tile[64][68];
    int e = blockIdx.z;
    const float* Wp = W + (size_t)e * K * N;
    unsigned short* Wtp = Wt + (size_t)e * N * K;
    int n0 = blockIdx.x * 64, k0 = blockIdx.y * 64;
    int t = threadIdx.x;
    int nn = (t & 15) * 4;
    int kk = t >> 4;
    #pragma unroll
    for (int r = 0; r < 4; ++r) {
        int k = kk + r * 16;
        float4 v = *(const float4*)(Wp + (size_t)(k0 + k) * N + (n0 + nn));
        tile[k][nn + 0] = f2bf(v.x);
        tile[k][nn + 1] = f2bf(v.y);
        tile[k][nn + 2] = f2bf(v.z);
        tile[k][nn + 3] = f2bf(v.w);
    }
    __syncthreads();
    int n  = t >> 2;
    int kb = (t & 3) * 16;
    ushort8_t o0, o1;
    #pragma unroll
    for (int i = 0; i < 8; ++i) o0[i] = tile[kb + i][n];
    #pragma unroll
    for (int i = 0; i < 8; ++i) o1[i] = tile[kb + 8 + i][n];
    unsigned short* dst = Wtp + (size_t)(n0 + n) * K + (k0 + kb);
    *(ushort8_t*)dst = o0;
    *(ushort8_t*)(dst + 8) = o1;
}

// Two-phase token routing: per-block LDS count+stage, one global atomicAdd
// per (block, expert), then compact write of token ids + combine weights.
// List order is nondeterministic across replays, but every per-token output
// value is independent of its slot, so d_out stays deterministic.
__global__ __launch_bounds__(256) void route_tokens(
    const float* __restrict__ probs, const int* __restrict__ idx,
    int* __restrict__ cnt, int* __restrict__ list, float* __restrict__ wl)
{
    __shared__ int lcnt[NEXP];
    __shared__ int lbase[NEXP];
    __shared__ int ltok[NEXP][256];
    __shared__ float lww[NEXP][256];
    int t = threadIdx.x;
    int b = blockIdx.x * 256 + t;
    if (t < NEXP) lcnt[t] = 0;
    __syncthreads();
    float p0 = probs[b * TOPK + 0], p1 = probs[b * TOPK + 1];
    int   i0 = idx[b * TOPK + 0],   i1 = idx[b * TOPK + 1];
    #pragma unroll
    for (int e = 0; e < NEXP; ++e) {
        bool m0 = (i0 == e), m1 = (i1 == e);
        if (m0 || m1) {
            float w = (m0 ? p0 : 0.f) + (m1 ? p1 : 0.f);
            int s = atomicAdd(&lcnt[e], 1);
            ltok[e][s] = b; lww[e][s] = w;
        }
    }
    __syncthreads();
    if (t < NEXP) lbase[t] = atomicAdd(&cnt[t], lcnt[t]);
    __syncthreads();
    #pragma unroll
    for (int e = 0; e < NEXP; ++e) {
        int n = lcnt[e], base = lbase[e];
        for (int s = t; s < n; s += 256) {
            list[e * B_TOK + base + s] = ltok[e][s];
            wl[e * B_TOK + base + s]   = lww[e][s];
        }
    }
}

// round counts up to tile multiple; pad list with token 0 (weight 0)
__global__ void finalize_counts(const int* __restrict__ cnt, int* __restrict__ cntp,
                                int* __restrict__ list, float* __restrict__ wl)
{
    int e = blockIdx.x;
    int c = cnt[e];
    int cp = (c + 127) & ~127;
    if (threadIdx.x == 0) cntp[e] = cp;
    for (int s = c + threadIdx.x; s < cp; s += blockDim.x) {
        list[e * B_TOK + s] = 0;
        wl[e * B_TOK + s] = 0.f;
    }
}

// ---------------- GEMM: C = act(A[M,K] @ Bt[N,K]^T + bias) ----------------
// m97-structure: 128x128 tile, BK=32, 4 waves (2x2), mfma 16x16x32 bf16,
// linear LDS + global_load_lds(16B), 2 barriers per K-step.
// GATHER: A rows indexed via list (compact slot -> token row of A).
// FINAL : scatter-accumulate out[token] += w * (acc + bias), slot < cnt.
// All variants early-exit M-tiles past cntp (padded expert count).
template<int ACT, int FINAL, int GATHER>
__global__ __launch_bounds__(256, 2) void gemm_bf16(
    const unsigned short* __restrict__ A,   // [*][K] bf16
    const unsigned short* __restrict__ Bt,  // [N][K] bf16
    const float* __restrict__ bias,         // [N]
    unsigned short* __restrict__ H,         // [slots][N] bf16 (if !FINAL)
    float* __restrict__ out,                // [B_TOK][N] f32  (if FINAL)
    const float* __restrict__ wl,           // [slots] weight  (if FINAL)
    const int* __restrict__ list,           // [slots] token id (GATHER/FINAL)
    const int* __restrict__ cnt_p,          // &cnt[e]
    const int* __restrict__ cntp_p,         // &cntp[e]
    int N, int K)
{
    // XCD-aware bijective swizzle: xcd = bid&7 (dispatch heuristic), each XCD
    // walks M-tiles {xcd, xcd+8, ...} with all N-tiles consecutive -> A-tile
    // shared within one XCD's L2, active tiles balanced under early-exit.
    const int gx = gridDim.x;
    const int bid = blockIdx.y * gx + blockIdx.x;
    const int g = bid >> 3;
    const int by = (bid & 7) + ((g / gx) << 3);
    const int bx = g % gx;
    const int CP = *cntp_p;
    const int bm = by << 7;
    if (bm >= CP) return;
    const int bn = bx << 7;

    __shared__ unsigned short lds[8192];    // A tile 8KB @0, B tile 8KB @8192
    char* ldsc = (char*)lds;
    const int tid  = threadIdx.x;
    const int lane = tid & 63;
    const int wid  = tid >> 6;
    const int wr = wid >> 1, wc = wid & 1;

    f32x4 acc[4][4] = {};

    // staging: wave wid covers rows [wid*32, wid*32+32) of the 128-row tile,
    // two 1KB segments (16 rows each); lane -> (row = seg + lane/4, col8 = (lane&3)*8)
    const int srow = (wid << 5) + (lane >> 2);
    int arow;
    if constexpr (GATHER) arow = list[bm + srow];
    else                  arow = bm + srow;
    const unsigned short* pa = A  + (size_t)arow * K + ((lane & 3) << 3);
    const unsigned short* pb = Bt + (size_t)(bn + srow) * K + ((lane & 3) << 3);
    char* la0 = ldsc + (wid << 11);
    char* lb0 = ldsc + 8192 + (wid << 11);
    size_t arow16;
    if constexpr (GATHER) {
        int arow2 = list[bm + srow + 16];
        arow16 = (size_t)(arow2 - arow) * K;   // delta to 2nd staged row
    } else {
        arow16 = (size_t)16 * K;
    }
    const size_t rowK16 = (size_t)16 * K;

    // fragment read pointers: row = warp_row*64 + (lane&15) (+ mi*16), kbyte = (lane>>4)*16
    const char* fA = ldsc + ((wr << 6) + (lane & 15)) * 64 + ((lane >> 4) << 4);
    const char* fB = ldsc + 8192 + ((wc << 6) + (lane & 15)) * 64 + ((lane >> 4) << 4);

    for (int k0 = 0; k0 < K; k0 += 32) {
        glds16(pa + k0,          la0);
        glds16(pa + k0 + arow16, la0 + 1024);
        glds16(pb + k0,          lb0);
        glds16(pb + k0 + rowK16, lb0 + 1024);
        __syncthreads();   // drains vmcnt + lgkm before compute
        bf16x8 av[4], bv[4];
        #pragma unroll
        for (int mi = 0; mi < 4; ++mi) av[mi] = *(const bf16x8*)(fA + (mi << 10));
        #pragma unroll
        for (int ni = 0; ni < 4; ++ni) bv[ni] = *(const bf16x8*)(fB + (ni << 10));
        #pragma unroll
        for (int mi = 0; mi < 4; ++mi)
            #pragma unroll
            for (int ni = 0; ni < 4; ++ni)
                acc[mi][ni] = __builtin_amdgcn_mfma_f32_16x16x32_bf16(
                    av[mi], bv[ni], acc[mi][ni], 0, 0, 0);
        __syncthreads();   // compute done before next-stage overwrite
    }

    // epilogue. C/D layout (m89-verified): col = lane&15, row = (lane>>4)*4 + j
    const int coffs = lane & 15;
    const int rbase = (lane >> 4) << 2;
    const int r0 = bm + (wr << 6) + rbase;
    const int c0 = bn + (wc << 6) + coffs;

    if constexpr (!FINAL) {
        #pragma unroll
        for (int mi = 0; mi < 4; ++mi) {
            #pragma unroll
            for (int j = 0; j < 4; ++j) {
                int r = r0 + mi * 16 + j;
                size_t ro = (size_t)r * N;
                #pragma unroll
                for (int ni = 0; ni < 4; ++ni) {
                    int c = c0 + ni * 16;
                    float v = acc[mi][ni][j] + bias[c];
                    if (ACT) v = v > 0.f ? v : 0.2f * v;
                    H[ro + c] = f2bf(v);
                }
            }
        }
    } else {
        const int C = *cnt_p;
        #pragma unroll
        for (int mi = 0; mi < 4; ++mi) {
            #pragma unroll
            for (int j = 0; j < 4; ++j) {
                int slot = r0 + mi * 16 + j;
                if (slot < C) {
                    int tok = list[slot];
                    float w = wl[slot];
                    size_t ro = (size_t)tok * N;
                    #pragma unroll
                    for (int ni = 0; ni < 4; ++ni) {
                        int c = c0 + ni * 16;
                        out[ro + c] += (acc[mi][ni][j] + bias[c]) * w;
                    }
                }
            }
        }
    }
}

// ---------------- host launch ----------------

extern "C" void kernel_launch(void* const* d_in, const int* in_sizes, int n_in,
                              void* d_out, int out_size, void* d_ws, size_t ws_size,
                              hipStream_t stream)
{
    const float* x     = (const float*)d_in[0];
    // d_in[1] = gate (unused by reference forward)
    const float* probs = (const float*)d_in[2];
    const int*   tidx  = (const int*)d_in[3];
    const float* W1    = (const float*)d_in[4];
    const float* b1    = (const float*)d_in[5];
    const float* W2    = (const float*)d_in[6];
    const float* b2    = (const float*)d_in[7];
    const float* W3    = (const float*)d_in[8];
    const float* b3    = (const float*)d_in[9];
    float* out = (float*)d_out;

    // workspace layout (bytes)
    char* ws = (char*)d_ws;
    const size_t xb_off  = 0;                                       // 67,108,864
    const size_t w1t_off = xb_off  + (size_t)B_TOK * IN_DIM * 2;    // +12,582,912
    const size_t w2t_off = w1t_off + (size_t)NEXP * IN_DIM * H1_DIM * 2;
    const size_t w3t_off = w2t_off + (size_t)NEXP * H1_DIM * H2_DIM * 2;
    const size_t h1_off  = w3t_off + (size_t)NEXP * H2_DIM * D_DIM * 2;
    const size_t h2_off  = h1_off  + (size_t)B_TOK * H1_DIM * 2;
    const size_t li_off  = h2_off  + (size_t)B_TOK * H2_DIM * 2;
    const size_t wl_off  = li_off  + (size_t)NEXP * B_TOK * 4;
    const size_t cn_off  = wl_off  + (size_t)NEXP * B_TOK * 4;
    const size_t cp_off  = cn_off  + 256;

    unsigned short* xb  = (unsigned short*)(ws + xb_off);
    unsigned short* W1t = (unsigned short*)(ws + w1t_off);
    unsigned short* W2t = (unsigned short*)(ws + w2t_off);
    unsigned short* W3t = (unsigned short*)(ws + w3t_off);
    unsigned short* h1  = (unsigned short*)(ws + h1_off);
    unsigned short* h2  = (unsigned short*)(ws + h2_off);
    int*            lst = (int*)(ws + li_off);
    float*          wl  = (float*)(ws + wl_off);
    int*            cnt = (int*)(ws + cn_off);
    int*            cnp = (int*)(ws + cp_off);

    // init (graph-capture-safe async memsets)
    hipMemsetAsync(out, 0, (size_t)out_size * sizeof(float), stream);
    hipMemsetAsync(cnt, 0, 256, stream);

    // prepass
    convert_f32_bf16<<<2048, 256, 0, stream>>>(x, xb, (size_t)B_TOK * IN_DIM);
    transpose_convert<<<dim3(H1_DIM / 64, IN_DIM / 64, NEXP), 256, 0, stream>>>(W1, W1t, IN_DIM, H1_DIM);
    transpose_convert<<<dim3(H2_DIM / 64, H1_DIM / 64, NEXP), 256, 0, stream>>>(W2, W2t, H1_DIM, H2_DIM);
    transpose_convert<<<dim3(D_DIM / 64, H2_DIM / 64, NEXP), 256, 0, stream>>>(W3, W3t, H2_DIM, D_DIM);
    route_tokens<<<B_TOK / 256, 256, 0, stream>>>(probs, tidx, cnt, lst, wl);
    finalize_counts<<<NEXP, 128, 0, stream>>>(cnt, cnp, lst, wl);

    // per-expert gathered 3-layer MLP + weighted scatter-accumulate into out.
    // Expert dispatches are stream-ordered, so the += in FINAL is race-free.
    for (int e = 0; e < NEXP; ++e) {
        const int* le = lst + (size_t)e * B_TOK;
        gemm_bf16<1, 0, 1><<<dim3(H1_DIM / 128, B_TOK / 128), 256, 0, stream>>>(
            xb, W1t + (size_t)e * H1_DIM * IN_DIM, b1 + (size_t)e * H1_DIM,
            h1, nullptr, nullptr, le, cnt + e, cnp + e, H1_DIM, IN_DIM);
        gemm_bf16<1, 0, 0><<<dim3(H2_DIM / 128, B_TOK / 128), 256, 0, stream>>>(
            h1, W2t + (size_t)e * H2_DIM * H1_DIM, b2 + (size_t)e * H2_DIM,
            h2, nullptr, nullptr, le, cnt + e, cnp + e, H2_DIM, H1_DIM);
        gemm_bf16<0, 1, 0><<<dim3(D_DIM / 128, B_TOK / 128), 256, 0, stream>>>(
            h2, W3t + (size_t)e * D_DIM * H2_DIM, b3 + (size_t)e * D_DIM,
            nullptr, out, wl + (size_t)e * B_TOK, le, cnt + e, cnp + e, D_DIM, H2_DIM);
    }
}

// Round 3
// 398.609 us; speedup vs baseline: 1.3389x; 1.0977x over previous
//
#include <hip/hip_runtime.h>
#include <cstdint>
#include <cstddef>

// Problem constants (match reference setup_inputs)
#define B_TOK   16384
#define IN_DIM  2048
#define D_DIM   1024
#define NEXP    3
#define TOPK    2
#define H1_DIM  1024
#define H2_DIM  512

typedef __bf16 bf16x8 __attribute__((ext_vector_type(8)));
typedef float  f32x4  __attribute__((ext_vector_type(4)));
typedef unsigned short ushort8_t __attribute__((ext_vector_type(8)));

__device__ __forceinline__ unsigned short f2bf(float f) {
    unsigned int u = __builtin_bit_cast(unsigned int, f);
    return (unsigned short)((u + 0x7fffu + ((u >> 16) & 1u)) >> 16);
}

// async global->LDS, 16B per lane. LDS dest is wave-uniform base + lane*16;
// global source address IS per-lane (enables gather + inverse-swizzle).
__device__ __forceinline__ void glds16(const void* gsrc, void* ldst) {
    __builtin_amdgcn_global_load_lds(
        (__attribute__((address_space(1))) void*)(gsrc),
        (__attribute__((address_space(3))) void*)(ldst),
        16, 0, 0);
}

// ---------------- prepass kernels ----------------

__global__ __launch_bounds__(256) void convert_f32_bf16(
    const float* __restrict__ in, unsigned short* __restrict__ out, size_t n)
{
    size_t i = ((size_t)blockIdx.x * blockDim.x + threadIdx.x) * 8;
    size_t stride = (size_t)gridDim.x * blockDim.x * 8;
    for (; i < n; i += stride) {
        float4 a = *(const float4*)(in + i);
        float4 b = *(const float4*)(in + i + 4);
        ushort8_t o;
        o[0] = f2bf(a.x); o[1] = f2bf(a.y); o[2] = f2bf(a.z); o[3] = f2bf(a.w);
        o[4] = f2bf(b.x); o[5] = f2bf(b.y); o[6] = f2bf(b.z); o[7] = f2bf(b.w);
        *(ushort8_t*)(out + i) = o;
    }
}

// W [E][K][N] f32 -> Wt [E][N][K] bf16, 64x64 tiles through LDS
__global__ __launch_bounds__(256) void transpose_convert(
    const float* __restrict__ W, unsigned short* __restrict__ Wt, int K, int N)
{
    __shared__ unsigned short tile[64][68];
    int e = blockIdx.z;
    const float* Wp = W + (size_t)e * K * N;
    unsigned short* Wtp = Wt + (size_t)e * N * K;
    int n0 = blockIdx.x * 64, k0 = blockIdx.y * 64;
    int t = threadIdx.x;
    int nn = (t & 15) * 4;
    int kk = t >> 4;
    #pragma unroll
    for (int r = 0; r < 4; ++r) {
        int k = kk + r * 16;
        float4 v = *(const float4*)(Wp + (size_t)(k0 + k) * N + (n0 + nn));
        tile[k][nn + 0] = f2bf(v.x);
        tile[k][nn + 1] = f2bf(v.y);
        tile[k][nn + 2] = f2bf(v.z);
        tile[k][nn + 3] = f2bf(v.w);
    }
    __syncthreads();
    int n  = t >> 2;
    int kb = (t & 3) * 16;
    ushort8_t o0, o1;
    #pragma unroll
    for (int i = 0; i < 8; ++i) o0[i] = tile[kb + i][n];
    #pragma unroll
    for (int i = 0; i < 8; ++i) o1[i] = tile[kb + 8 + i][n];
    unsigned short* dst = Wtp + (size_t)(n0 + n) * K + (k0 + kb);
    *(ushort8_t*)dst = o0;
    *(ushort8_t*)(dst + 8) = o1;
}

// Two-phase token routing: per-block LDS count+stage, one global atomicAdd
// per (block, expert), then compact write of token ids + combine weights.
// Slot order is nondeterministic across replays, but each per-token output
// value is independent of its slot, so d_out stays deterministic.
__global__ __launch_bounds__(256) void route_tokens(
    const float* __restrict__ probs, const int* __restrict__ idx,
    int* __restrict__ cnt, int* __restrict__ list, float* __restrict__ wl)
{
    __shared__ int lcnt[NEXP];
    __shared__ int lbase[NEXP];
    __shared__ int ltok[NEXP][256];
    __shared__ float lww[NEXP][256];
    int t = threadIdx.x;
    int b = blockIdx.x * 256 + t;
    if (t < NEXP) lcnt[t] = 0;
    __syncthreads();
    float p0 = probs[b * TOPK + 0], p1 = probs[b * TOPK + 1];
    int   i0 = idx[b * TOPK + 0],   i1 = idx[b * TOPK + 1];
    #pragma unroll
    for (int e = 0; e < NEXP; ++e) {
        bool m0 = (i0 == e), m1 = (i1 == e);
        if (m0 || m1) {
            float w = (m0 ? p0 : 0.f) + (m1 ? p1 : 0.f);
            int s = atomicAdd(&lcnt[e], 1);
            ltok[e][s] = b; lww[e][s] = w;
        }
    }
    __syncthreads();
    if (t < NEXP) lbase[t] = atomicAdd(&cnt[t], lcnt[t]);
    __syncthreads();
    #pragma unroll
    for (int e = 0; e < NEXP; ++e) {
        int n = lcnt[e], base = lbase[e];
        for (int s = t; s < n; s += 256) {
            list[e * B_TOK + base + s] = ltok[e][s];
            wl[e * B_TOK + base + s]   = lww[e][s];
        }
    }
}

// round counts up to 256-tile multiple; pad list with token 0 (weight 0)
__global__ void finalize_counts(const int* __restrict__ cnt, int* __restrict__ cntp,
                                int* __restrict__ list, float* __restrict__ wl)
{
    int e = blockIdx.x;
    int c = cnt[e];
    int cp = (c + 255) & ~255;
    if (threadIdx.x == 0) cntp[e] = cp;
    for (int s = c + threadIdx.x; s < cp; s += blockDim.x) {
        list[e * B_TOK + s] = 0;
        wl[e * B_TOK + s] = 0.f;
    }
}

// ---------------- 8-phase 256x256 GEMM (m201 template, plain HIP) ----------
// C = act(A[slots,K] @ Bt[N,K]^T + bias). BM=BN=256, BK=64, 8 waves (512 thr),
// LDS 128KiB = 2 dbuf x {A,B} x 2 half x [128][64] bf16.
// Per phase: 12 ds_read_b128 (4 A + 8 B) || stage 1 half-tile (2 glds16)
// -> barrier -> lgkmcnt(0) -> setprio(1) 16 MFMA setprio(0) -> barrier.
// vmcnt(4) only at phases 4 and 8 (2 half-tiles in flight, never drained to 0).
// XOR swizzle: 16B unit u at row r lives at u^(r&7); inverse applied to the
// per-lane GLOBAL source addr (LDS dest of glds16 is linear, rule #21).
template<int ACT, int FINAL, int GATHER>
__global__ __launch_bounds__(512, 2) void gemm8(
    const unsigned short* __restrict__ Ab, size_t Aplane,  // bf16 [slots][K] (per-expert plane if !GATHER)
    const unsigned short* __restrict__ Bb,                 // bf16 [E][N][K]
    const float* __restrict__ biasb,                       // [E][N]
    unsigned short* __restrict__ Hb, size_t Hplane,        // bf16 [E][slots][N] (if !FINAL)
    float* __restrict__ outb,                              // f32 [B_TOK][D]    (if FINAL)
    const float* __restrict__ wlb,                         // [E][B_TOK]
    const int* __restrict__ listb,                         // [E][B_TOK]
    const int* __restrict__ cnt,                           // [E] actual count
    const int* __restrict__ cntp,                          // [E] padded count
    int N, int K, int NT, int e0)
{
    // bijective tile->XCD mapping: xcd=bid&7; XCD x walks A-tiles {x,x+8,...}
    // with the NT N-blocks of each A-tile consecutive (L2 A-reuse); live
    // tiles (early-exit) spread evenly across XCDs.
    const int bid  = blockIdx.x;
    const int xcd  = bid & 7;
    const int slot = bid >> 3;
    const int q    = slot / NT;
    const int nt   = slot % NT;
    const int ti   = q * 8 + xcd;
    const int e    = e0 + (ti >> 6);
    const int mt   = ti & 63;
    const int bm   = mt << 8;
    if (bm >= cntp[e]) return;
    const int bn   = nt << 8;

    __shared__ char smem[131072];   // A: [0,64K)  B: [64K,128K)

    const int tid  = threadIdx.x;
    const int lane = tid & 63;
    const int w    = tid >> 6;      // wave 0..7
    const int wl3  = w & 3;         // A 32-row band within half
    const int wn1  = w >> 2;        // B 64-col band within half
    const int l15  = lane & 15;
    const int ug8  = (((tid & 7) ^ ((tid >> 3) & 7)) << 3);          // src swz (shorts)
    const int sw0  = ((((lane >> 4) + 0) ^ (lane & 7)) << 4);        // read swz k0 (bytes)
    const int sw1  = ((((lane >> 4) + 4) ^ (lane & 7)) << 4);        // read swz k1 (bytes)

    const int* listp = listb + (size_t)e * B_TOK;
    const unsigned short* Ae = Ab + (size_t)e * Aplane;
    const unsigned short* Be = Bb + (size_t)e * ((size_t)N * K);
    const float* biasp = biasb + (size_t)e * N;

    // per-thread stage source pointers: half h, load j covers tile row
    // h*128 + j*64 + (tid>>3); 16B unit = (tid&7) ^ ((tid>>3)&7)  (inverse swz)
    const unsigned short* sA[2][2];
    const unsigned short* sB[2][2];
    #pragma unroll
    for (int h = 0; h < 2; ++h)
        #pragma unroll
        for (int j = 0; j < 2; ++j) {
            int lrow = h * 128 + j * 64 + (tid >> 3);
            int arow;
            if constexpr (GATHER) arow = listp[bm + lrow];
            else                  arow = bm + lrow;
            sA[h][j] = Ae + (size_t)arow * K + ug8;
            sB[h][j] = Be + (size_t)(bn + lrow) * K + ug8;
        }

    char* const stA = smem + (w << 10);            // + db*32768 + h*16384 (+8192 for j=1)
    char* const stB = smem + 65536 + (w << 10);
    const char* const rA = smem + (wl3 * 32 + l15) * 128;           // + db*32768 + Qm*16384 + ml*2048 + sw
    const char* const rB = smem + 65536 + (wn1 * 64 + l15) * 128;   // + db*32768 + Qn*16384 + nl*2048 + sw

    f32x4 acc[2][2][2][4] = {};   // [Qm][ml][Qn][nl]

#define STA(db, h, kt) do {                                                     \
    glds16(sA[h][0] + (size_t)(kt) * 64, stA + (db) * 32768 + (h) * 16384);     \
    glds16(sA[h][1] + (size_t)(kt) * 64, stA + (db) * 32768 + (h) * 16384 + 8192); } while (0)
#define STB(db, h, kt) do {                                                     \
    glds16(sB[h][0] + (size_t)(kt) * 64, stB + (db) * 32768 + (h) * 16384);     \
    glds16(sB[h][1] + (size_t)(kt) * 64, stB + (db) * 32768 + (h) * 16384 + 8192); } while (0)

#define PHASE(db, Qm, Qn, STAGE_STMT, VM_STMT) do {                             \
    bf16x8 av[2][2], bv[4][2];                                                  \
    _Pragma("unroll")                                                           \
    for (int ml = 0; ml < 2; ++ml) {                                            \
        av[ml][0] = *(const bf16x8*)(rA + (db)*32768 + (Qm)*16384 + ml*2048 + sw0); \
        av[ml][1] = *(const bf16x8*)(rA + (db)*32768 + (Qm)*16384 + ml*2048 + sw1); \
    }                                                                           \
    _Pragma("unroll")                                                           \
    for (int nl = 0; nl < 4; ++nl) {                                            \
        bv[nl][0] = *(const bf16x8*)(rB + (db)*32768 + (Qn)*16384 + nl*2048 + sw0); \
        bv[nl][1] = *(const bf16x8*)(rB + (db)*32768 + (Qn)*16384 + nl*2048 + sw1); \
    }                                                                           \
    STAGE_STMT;                                                                 \
    VM_STMT;                                                                    \
    __builtin_amdgcn_s_barrier();                                               \
    asm volatile("s_waitcnt lgkmcnt(0)" ::: "memory");                          \
    __builtin_amdgcn_sched_barrier(0);                                          \
    __builtin_amdgcn_s_setprio(1);                                              \
    _Pragma("unroll")                                                           \
    for (int ml = 0; ml < 2; ++ml)                                              \
        _Pragma("unroll")                                                       \
        for (int nl = 0; nl < 4; ++nl) {                                        \
            acc[Qm][ml][Qn][nl] = __builtin_amdgcn_mfma_f32_16x16x32_bf16(      \
                av[ml][0], bv[nl][0], acc[Qm][ml][Qn][nl], 0, 0, 0);            \
            acc[Qm][ml][Qn][nl] = __builtin_amdgcn_mfma_f32_16x16x32_bf16(      \
                av[ml][1], bv[nl][1], acc[Qm][ml][Qn][nl], 0, 0, 0);            \
        }                                                                       \
    __builtin_amdgcn_s_setprio(0);                                              \
    __builtin_amdgcn_sched_barrier(0);                                          \
    __builtin_amdgcn_s_barrier();                                               \
} while (0)

    const int nkt = K >> 6;           // 64-wide K-tiles (>= 8 for all layers)
    // prologue: tile0 full into buf0; tile1 {B-half0, A-half1} into buf1
    STA(0, 0, 0); STA(0, 1, 0); STB(0, 0, 0); STB(0, 1, 0);
    STB(1, 0, 1); STA(1, 1, 1);
    asm volatile("s_waitcnt vmcnt(4)" ::: "memory");   // tile0's 8 loads landed
    __builtin_amdgcn_s_barrier();

    const int niter = nkt >> 1;
    for (int it = 0; it < niter; ++it) {
        const int t1 = 2 * it + 1;
        const int t2 = (2 * it + 2 < nkt) ? 2 * it + 2 : nkt - 1;  // clamped: dead stages
        const int t3 = (2 * it + 3 < nkt) ? 2 * it + 3 : nkt - 1;
        PHASE(0, 1, 0, STA(1, 0, t1), ((void)0));
        PHASE(0, 0, 0, STB(1, 1, t1), ((void)0));
        PHASE(0, 1, 1, STB(0, 0, t2), ((void)0));
        PHASE(0, 0, 1, STA(0, 1, t2), asm volatile("s_waitcnt vmcnt(4)" ::: "memory"));
        PHASE(1, 1, 0, STA(0, 0, t2), ((void)0));
        PHASE(1, 0, 0, STB(0, 1, t2), ((void)0));
        PHASE(1, 1, 1, STB(1, 0, t3), ((void)0));
        PHASE(1, 0, 1, STA(1, 1, t3), asm volatile("s_waitcnt vmcnt(4)" ::: "memory"));
    }
    asm volatile("s_waitcnt vmcnt(0)" ::: "memory");   // drain tail stages

    // epilogue. C/D (m89-verified): col = lane&15 (B side), row = (lane>>4)*4+jj
    const int rl = (lane >> 4) << 2;
    float bsv[2][4];
    #pragma unroll
    for (int Qn = 0; Qn < 2; ++Qn)
        #pragma unroll
        for (int nl = 0; nl < 4; ++nl)
            bsv[Qn][nl] = biasp[bn + Qn * 128 + wn1 * 64 + nl * 16 + l15];

    if constexpr (!FINAL) {
        unsigned short* Hp = Hb + (size_t)e * Hplane;
        #pragma unroll
        for (int Qm = 0; Qm < 2; ++Qm)
        #pragma unroll
        for (int ml = 0; ml < 2; ++ml)
        #pragma unroll
        for (int jj = 0; jj < 4; ++jj) {
            int srow = bm + Qm * 128 + wl3 * 32 + ml * 16 + rl + jj;
            size_t ro = (size_t)srow * N;
            #pragma unroll
            for (int Qn = 0; Qn < 2; ++Qn)
            #pragma unroll
            for (int nl = 0; nl < 4; ++nl) {
                int col = bn + Qn * 128 + wn1 * 64 + nl * 16 + l15;
                float v = acc[Qm][ml][Qn][nl][jj] + bsv[Qn][nl];
                if (ACT) v = v > 0.f ? v : 0.2f * v;
                Hp[ro + col] = f2bf(v);
            }
        }
    } else {
        const int C = cnt[e];
        const float* wlp = wlb + (size_t)e * B_TOK;
        #pragma unroll
        for (int Qm = 0; Qm < 2; ++Qm)
        #pragma unroll
        for (int ml = 0; ml < 2; ++ml)
        #pragma unroll
        for (int jj = 0; jj < 4; ++jj) {
            int srow = bm + Qm * 128 + wl3 * 32 + ml * 16 + rl + jj;
            if (srow < C) {
                int tok = listp[srow];
                float wv = wlp[srow];
                size_t ro = (size_t)tok * D_DIM;
                #pragma unroll
                for (int Qn = 0; Qn < 2; ++Qn)
                #pragma unroll
                for (int nl = 0; nl < 4; ++nl) {
                    int col = bn + Qn * 128 + wn1 * 64 + nl * 16 + l15;
                    outb[ro + col] += (acc[Qm][ml][Qn][nl][jj] + bsv[Qn][nl]) * wv;
                }
            }
        }
    }
#undef PHASE
#undef STA
#undef STB
}

// ---------------- host launch ----------------

extern "C" void kernel_launch(void* const* d_in, const int* in_sizes, int n_in,
                              void* d_out, int out_size, void* d_ws, size_t ws_size,
                              hipStream_t stream)
{
    const float* x     = (const float*)d_in[0];
    // d_in[1] = gate (unused by reference forward)
    const float* probs = (const float*)d_in[2];
    const int*   tidx  = (const int*)d_in[3];
    const float* W1    = (const float*)d_in[4];
    const float* b1    = (const float*)d_in[5];
    const float* W2    = (const float*)d_in[6];
    const float* b2    = (const float*)d_in[7];
    const float* W3    = (const float*)d_in[8];
    const float* b3    = (const float*)d_in[9];
    float* out = (float*)d_out;

    // workspace layout (bytes); total ~237 MB (d_ws is 512 MiB per profile)
    char* ws = (char*)d_ws;
    const size_t xb_off  = 0;
    const size_t w1t_off = xb_off  + (size_t)B_TOK * IN_DIM * 2;
    const size_t w2t_off = w1t_off + (size_t)NEXP * IN_DIM * H1_DIM * 2;
    const size_t w3t_off = w2t_off + (size_t)NEXP * H1_DIM * H2_DIM * 2;
    const size_t h1_off  = w3t_off + (size_t)NEXP * H2_DIM * D_DIM * 2;
    const size_t h2_off  = h1_off  + (size_t)NEXP * B_TOK * H1_DIM * 2;   // per-expert planes
    const size_t li_off  = h2_off  + (size_t)NEXP * B_TOK * H2_DIM * 2;
    const size_t wl_off  = li_off  + (size_t)NEXP * B_TOK * 4;
    const size_t cn_off  = wl_off  + (size_t)NEXP * B_TOK * 4;
    const size_t cp_off  = cn_off  + 256;

    unsigned short* xb  = (unsigned short*)(ws + xb_off);
    unsigned short* W1t = (unsigned short*)(ws + w1t_off);
    unsigned short* W2t = (unsigned short*)(ws + w2t_off);
    unsigned short* W3t = (unsigned short*)(ws + w3t_off);
    unsigned short* h1  = (unsigned short*)(ws + h1_off);
    unsigned short* h2  = (unsigned short*)(ws + h2_off);
    int*            lst = (int*)(ws + li_off);
    float*          wl  = (float*)(ws + wl_off);
    int*            cnt = (int*)(ws + cn_off);
    int*            cnp = (int*)(ws + cp_off);

    hipMemsetAsync(out, 0, (size_t)out_size * sizeof(float), stream);
    hipMemsetAsync(cnt, 0, 256, stream);

    convert_f32_bf16<<<2048, 256, 0, stream>>>(x, xb, (size_t)B_TOK * IN_DIM);
    transpose_convert<<<dim3(H1_DIM / 64, IN_DIM / 64, NEXP), 256, 0, stream>>>(W1, W1t, IN_DIM, H1_DIM);
    transpose_convert<<<dim3(H2_DIM / 64, H1_DIM / 64, NEXP), 256, 0, stream>>>(W2, W2t, H1_DIM, H2_DIM);
    transpose_convert<<<dim3(D_DIM / 64, H2_DIM / 64, NEXP), 256, 0, stream>>>(W3, W3t, H2_DIM, D_DIM);
    route_tokens<<<B_TOK / 256, 256, 0, stream>>>(probs, tidx, cnt, lst, wl);
    finalize_counts<<<NEXP, 256, 0, stream>>>(cnt, cnp, lst, wl);

    const size_t h1pl = (size_t)B_TOK * H1_DIM;
    const size_t h2pl = (size_t)B_TOK * H2_DIM;

    // L1 grouped across experts: gathered x rows -> h1 planes
    gemm8<1, 0, 1><<<dim3(NEXP * 64 * 4), 512, 0, stream>>>(
        xb, 0, W1t, b1, h1, h1pl, nullptr, nullptr,
        lst, cnt, cnp, H1_DIM, IN_DIM, 4, 0);
    // L2 grouped: h1 planes -> h2 planes
    gemm8<1, 0, 0><<<dim3(NEXP * 64 * 2), 512, 0, stream>>>(
        h1, h1pl, W2t, b2, h2, h2pl, nullptr, nullptr,
        lst, cnt, cnp, H2_DIM, H1_DIM, 2, 0);
    // L3 per expert (stream-ordered +=, race-free): h2 plane -> out
    for (int e = 0; e < NEXP; ++e) {
        gemm8<0, 1, 0><<<dim3(64 * 4), 512, 0, stream>>>(
            h2, h2pl, W3t, b3, nullptr, 0, out, wl,
            lst, cnt, cnp, D_DIM, H2_DIM, 4, e);
    }
}

// Round 4
// 369.105 us; speedup vs baseline: 1.4459x; 1.0799x over previous
//
#include <hip/hip_runtime.h>
#include <cstdint>
#include <cstddef>

// Problem constants (match reference setup_inputs)
#define B_TOK   16384
#define IN_DIM  2048
#define D_DIM   1024
#define NEXP    3
#define TOPK    2
#define H1_DIM  1024
#define H2_DIM  512

typedef __bf16 bf16x8 __attribute__((ext_vector_type(8)));
typedef float  f32x4  __attribute__((ext_vector_type(4)));
typedef unsigned short ushort8_t __attribute__((ext_vector_type(8)));

__device__ __forceinline__ unsigned short f2bf(float f) {
    unsigned int u = __builtin_bit_cast(unsigned int, f);
    return (unsigned short)((u + 0x7fffu + ((u >> 16) & 1u)) >> 16);
}

// async global->LDS, 16B per lane. LDS dest is wave-uniform base + lane*16;
// global source address IS per-lane (enables gather + inverse-swizzle).
__device__ __forceinline__ void glds16(const void* gsrc, void* ldst) {
    __builtin_amdgcn_global_load_lds(
        (__attribute__((address_space(1))) void*)(gsrc),
        (__attribute__((address_space(3))) void*)(ldst),
        16, 0, 0);
}

// ---------------- prepass kernels ----------------

__global__ __launch_bounds__(256) void convert_f32_bf16(
    const float* __restrict__ in, unsigned short* __restrict__ out, size_t n)
{
    size_t i = ((size_t)blockIdx.x * blockDim.x + threadIdx.x) * 8;
    size_t stride = (size_t)gridDim.x * blockDim.x * 8;
    for (; i < n; i += stride) {
        float4 a = *(const float4*)(in + i);
        float4 b = *(const float4*)(in + i + 4);
        ushort8_t o;
        o[0] = f2bf(a.x); o[1] = f2bf(a.y); o[2] = f2bf(a.z); o[3] = f2bf(a.w);
        o[4] = f2bf(b.x); o[5] = f2bf(b.y); o[6] = f2bf(b.z); o[7] = f2bf(b.w);
        *(ushort8_t*)(out + i) = o;
    }
}

// W [E][K][N] f32 -> Wt [E][N][K] bf16, 64x64 tiles through LDS
__global__ __launch_bounds__(256) void transpose_convert(
    const float* __restrict__ W, unsigned short* __restrict__ Wt, int K, int N)
{
    __shared__ unsigned short tile[64][68];
    int e = blockIdx.z;
    const float* Wp = W + (size_t)e * K * N;
    unsigned short* Wtp = Wt + (size_t)e * N * K;
    int n0 = blockIdx.x * 64, k0 = blockIdx.y * 64;
    int t = threadIdx.x;
    int nn = (t & 15) * 4;
    int kk = t >> 4;
    #pragma unroll
    for (int r = 0; r < 4; ++r) {
        int k = kk + r * 16;
        float4 v = *(const float4*)(Wp + (size_t)(k0 + k) * N + (n0 + nn));
        tile[k][nn + 0] = f2bf(v.x);
        tile[k][nn + 1] = f2bf(v.y);
        tile[k][nn + 2] = f2bf(v.z);
        tile[k][nn + 3] = f2bf(v.w);
    }
    __syncthreads();
    int n  = t >> 2;
    int kb = (t & 3) * 16;
    ushort8_t o0, o1;
    #pragma unroll
    for (int i = 0; i < 8; ++i) o0[i] = tile[kb + i][n];
    #pragma unroll
    for (int i = 0; i < 8; ++i) o1[i] = tile[kb + 8 + i][n];
    unsigned short* dst = Wtp + (size_t)(n0 + n) * K + (k0 + kb);
    *(ushort8_t*)dst = o0;
    *(ushort8_t*)(dst + 8) = o1;
}

// Two-phase token routing: per-block LDS count+stage, one global atomicAdd
// per (block, expert), then compact write of token ids + combine weights.
// Slot order is nondeterministic across replays, but each per-token output
// value is independent of its slot, so d_out stays deterministic.
__global__ __launch_bounds__(256) void route_tokens(
    const float* __restrict__ probs, const int* __restrict__ idx,
    int* __restrict__ cnt, int* __restrict__ list, float* __restrict__ wl)
{
    __shared__ int lcnt[NEXP];
    __shared__ int lbase[NEXP];
    __shared__ int ltok[NEXP][256];
    __shared__ float lww[NEXP][256];
    int t = threadIdx.x;
    int b = blockIdx.x * 256 + t;
    if (t < NEXP) lcnt[t] = 0;
    __syncthreads();
    float p0 = probs[b * TOPK + 0], p1 = probs[b * TOPK + 1];
    int   i0 = idx[b * TOPK + 0],   i1 = idx[b * TOPK + 1];
    #pragma unroll
    for (int e = 0; e < NEXP; ++e) {
        bool m0 = (i0 == e), m1 = (i1 == e);
        if (m0 || m1) {
            float w = (m0 ? p0 : 0.f) + (m1 ? p1 : 0.f);
            int s = atomicAdd(&lcnt[e], 1);
            ltok[e][s] = b; lww[e][s] = w;
        }
    }
    __syncthreads();
    if (t < NEXP) lbase[t] = atomicAdd(&cnt[t], lcnt[t]);
    __syncthreads();
    #pragma unroll
    for (int e = 0; e < NEXP; ++e) {
        int n = lcnt[e], base = lbase[e];
        for (int s = t; s < n; s += 256) {
            list[e * B_TOK + base + s] = ltok[e][s];
            wl[e * B_TOK + base + s]   = lww[e][s];
        }
    }
}

// round counts up to 256-tile multiple; pad list with token 0 (weight 0)
__global__ void finalize_counts(const int* __restrict__ cnt, int* __restrict__ cntp,
                                int* __restrict__ list, float* __restrict__ wl)
{
    int e = blockIdx.x;
    int c = cnt[e];
    int cp = (c + 255) & ~255;
    if (threadIdx.x == 0) cntp[e] = cp;
    for (int s = c + threadIdx.x; s < cp; s += blockDim.x) {
        list[e * B_TOK + s] = 0;
        wl[e * B_TOK + s] = 0.f;
    }
}

// ---------------- 8-phase 256x256 GEMM (m201 template, plain HIP) ----------
// C = act(A[slots,K] @ Bt[N,K]^T + bias). BM=BN=256, BK=64, 8 waves (512 thr),
// LDS 128KiB = 2 dbuf x {A,B} x 2 half x [128][64] bf16.
// Snake quadrant order (1,0)->(0,0)->(0,1)->(1,1) with PERSISTENT register
// operands: per phase only the CHANGED operand is re-read from LDS
// (12,4,8,4 ds_read_b128 per phase vs 12 every phase) -- LDS read pipe was
// the round-3 bottleneck (96 b128/CU/phase ~ 384cy vs 155cy MFMA).
// Stage slots re-derived for the new order (each stage targets a region whose
// last ds_read is in an earlier phase):
//   ph1:A1(t1) ph2:B1(t1) ph3:A0(t2) ph4:B0(t2)+vmcnt(4)
//   ph5:A0h1(t2) ph6:B0h1(t2) ph7:A1h0(t3) ph8:B1h0(t3)+vmcnt(4)
// vmcnt(4)@ph4 -> prologue-tail + ph1/ph2 landed (buf1 complete);
// vmcnt(4)@ph8 -> ph3..ph6 landed (buf0 complete). Never drained in-loop.
template<int ACT, int FINAL, int GATHER>
__global__ __launch_bounds__(512, 2) void gemm8(
    const unsigned short* __restrict__ Ab, size_t Aplane,  // bf16 [slots][K] (per-expert plane if !GATHER)
    const unsigned short* __restrict__ Bb,                 // bf16 [E][N][K]
    const float* __restrict__ biasb,                       // [E][N]
    unsigned short* __restrict__ Hb, size_t Hplane,        // bf16 [E][slots][N] (if !FINAL)
    float* __restrict__ outb,                              // f32 [B_TOK][D]    (if FINAL)
    const float* __restrict__ wlb,                         // [E][B_TOK]
    const int* __restrict__ listb,                         // [E][B_TOK]
    const int* __restrict__ cnt,                           // [E] actual count
    const int* __restrict__ cntp,                          // [E] padded count
    int N, int K, int NT, int e0)
{
    // bijective tile->XCD mapping: xcd=bid&7; XCD x walks A-tiles {x,x+8,...}
    // with the NT N-blocks of each A-tile consecutive (L2 A-reuse); live
    // tiles (early-exit) spread evenly across XCDs.
    const int bid  = blockIdx.x;
    const int xcd  = bid & 7;
    const int slot = bid >> 3;
    const int q    = slot / NT;
    const int nt   = slot % NT;
    const int ti   = q * 8 + xcd;
    const int e    = e0 + (ti >> 6);
    const int mt   = ti & 63;
    const int bm   = mt << 8;
    if (bm >= cntp[e]) return;
    const int bn   = nt << 8;

    __shared__ char smem[131072];   // A: [0,64K)  B: [64K,128K)

    const int tid  = threadIdx.x;
    const int lane = tid & 63;
    const int w    = tid >> 6;      // wave 0..7
    const int wl3  = w & 3;         // A 32-row band within half
    const int wn1  = w >> 2;        // B 64-col band within half
    const int l15  = lane & 15;
    const int ug8  = (((tid & 7) ^ ((tid >> 3) & 7)) << 3);          // src swz (shorts)
    const int sw0  = ((((lane >> 4) + 0) ^ (lane & 7)) << 4);        // read swz k0 (bytes)
    const int sw1  = ((((lane >> 4) + 4) ^ (lane & 7)) << 4);        // read swz k1 (bytes)

    const int* listp = listb + (size_t)e * B_TOK;
    const unsigned short* Ae = Ab + (size_t)e * Aplane;
    const unsigned short* Be = Bb + (size_t)e * ((size_t)N * K);
    const float* biasp = biasb + (size_t)e * N;

    // per-thread stage source pointers: half h, load j covers tile row
    // h*128 + j*64 + (tid>>3); 16B unit = (tid&7) ^ ((tid>>3)&7)  (inverse swz)
    const unsigned short* sA[2][2];
    const unsigned short* sB[2][2];
    #pragma unroll
    for (int h = 0; h < 2; ++h)
        #pragma unroll
        for (int j = 0; j < 2; ++j) {
            int lrow = h * 128 + j * 64 + (tid >> 3);
            int arow;
            if constexpr (GATHER) arow = listp[bm + lrow];
            else                  arow = bm + lrow;
            sA[h][j] = Ae + (size_t)arow * K + ug8;
            sB[h][j] = Be + (size_t)(bn + lrow) * K + ug8;
        }

    char* const stA = smem + (w << 10);            // + db*32768 + h*16384 (+8192 for j=1)
    char* const stB = smem + 65536 + (w << 10);
    const char* const rA = smem + (wl3 * 32 + l15) * 128;           // + db*32768 + Qm*16384 + ml*2048 + sw
    const char* const rB = smem + 65536 + (wn1 * 64 + l15) * 128;   // + db*32768 + Qn*16384 + nl*2048 + sw

    f32x4 acc[2][2][2][4] = {};   // [Qm][ml][Qn][nl]
    bf16x8 av[2][2];              // persistent A operand (current Qm half)
    bf16x8 bv[4][2];              // persistent B operand (current Qn half)

#define STA(db, h, kt) do {                                                     \
    glds16(sA[h][0] + (size_t)(kt) * 64, stA + (db) * 32768 + (h) * 16384);     \
    glds16(sA[h][1] + (size_t)(kt) * 64, stA + (db) * 32768 + (h) * 16384 + 8192); } while (0)
#define STB(db, h, kt) do {                                                     \
    glds16(sB[h][0] + (size_t)(kt) * 64, stB + (db) * 32768 + (h) * 16384);     \
    glds16(sB[h][1] + (size_t)(kt) * 64, stB + (db) * 32768 + (h) * 16384 + 8192); } while (0)

#define LA(db, Qm) do {                                                         \
    _Pragma("unroll")                                                           \
    for (int ml = 0; ml < 2; ++ml) {                                            \
        av[ml][0] = *(const bf16x8*)(rA + (db)*32768 + (Qm)*16384 + ml*2048 + sw0); \
        av[ml][1] = *(const bf16x8*)(rA + (db)*32768 + (Qm)*16384 + ml*2048 + sw1); \
    } } while (0)
#define LB(db, Qn) do {                                                         \
    _Pragma("unroll")                                                           \
    for (int nl = 0; nl < 4; ++nl) {                                            \
        bv[nl][0] = *(const bf16x8*)(rB + (db)*32768 + (Qn)*16384 + nl*2048 + sw0); \
        bv[nl][1] = *(const bf16x8*)(rB + (db)*32768 + (Qn)*16384 + nl*2048 + sw1); \
    } } while (0)

#define PHASE(Qm, Qn, LOADS, STAGE_STMT, VM_STMT) do {                          \
    LOADS;                                                                      \
    STAGE_STMT;                                                                 \
    VM_STMT;                                                                    \
    __builtin_amdgcn_s_barrier();                                               \
    asm volatile("s_waitcnt lgkmcnt(0)" ::: "memory");                          \
    __builtin_amdgcn_sched_barrier(0);                                          \
    __builtin_amdgcn_s_setprio(1);                                              \
    _Pragma("unroll")                                                           \
    for (int ml = 0; ml < 2; ++ml)                                              \
        _Pragma("unroll")                                                       \
        for (int nl = 0; nl < 4; ++nl) {                                        \
            acc[Qm][ml][Qn][nl] = __builtin_amdgcn_mfma_f32_16x16x32_bf16(      \
                av[ml][0], bv[nl][0], acc[Qm][ml][Qn][nl], 0, 0, 0);            \
            acc[Qm][ml][Qn][nl] = __builtin_amdgcn_mfma_f32_16x16x32_bf16(      \
                av[ml][1], bv[nl][1], acc[Qm][ml][Qn][nl], 0, 0, 0);            \
        }                                                                       \
    __builtin_amdgcn_s_setprio(0);                                              \
    __builtin_amdgcn_sched_barrier(0);                                          \
    __builtin_amdgcn_s_barrier();                                               \
} while (0)

    const int nkt = K >> 6;           // 64-wide K-tiles (even for all layers)
    // prologue: buf0 = tile0 full; buf1 = tile1 {A-h0, B-h0} (ph7/ph8 slots)
    STA(0, 0, 0); STA(0, 1, 0); STB(0, 0, 0); STB(0, 1, 0);
    STA(1, 0, 1); STB(1, 0, 1);
    asm volatile("s_waitcnt vmcnt(4)" ::: "memory");   // tile0's 8 loads landed
    __builtin_amdgcn_s_barrier();

    const int niter = nkt >> 1;
    for (int it = 0; it < niter; ++it) {
        const int t1 = 2 * it + 1;
        const int t2 = (2 * it + 2 < nkt) ? 2 * it + 2 : nkt - 1;  // clamped: dead stages
        const int t3 = (2 * it + 3 < nkt) ? 2 * it + 3 : nkt - 1;
        PHASE(1, 0, LA(0,1); LB(0,0), STA(1, 1, t1), ((void)0));
        PHASE(0, 0, LA(0,0),          STB(1, 1, t1), ((void)0));
        PHASE(0, 1, LB(0,1),          STA(0, 0, t2), ((void)0));
        PHASE(1, 1, LA(0,1),          STB(0, 0, t2), asm volatile("s_waitcnt vmcnt(4)" ::: "memory"));
        PHASE(1, 0, LA(1,1); LB(1,0), STA(0, 1, t2), ((void)0));
        PHASE(0, 0, LA(1,0),          STB(0, 1, t2), ((void)0));
        PHASE(0, 1, LB(1,1),          STA(1, 0, t3), ((void)0));
        PHASE(1, 1, LA(1,1),          STB(1, 0, t3), asm volatile("s_waitcnt vmcnt(4)" ::: "memory"));
    }
    asm volatile("s_waitcnt vmcnt(0)" ::: "memory");   // drain tail stages

    // epilogue. C/D (m89-verified): col = lane&15 (B side), row = (lane>>4)*4+jj
    const int rl = (lane >> 4) << 2;
    float bsv[2][4];
    #pragma unroll
    for (int Qn = 0; Qn < 2; ++Qn)
        #pragma unroll
        for (int nl = 0; nl < 4; ++nl)
            bsv[Qn][nl] = biasp[bn + Qn * 128 + wn1 * 64 + nl * 16 + l15];

    if constexpr (!FINAL) {
        unsigned short* Hp = Hb + (size_t)e * Hplane;
        #pragma unroll
        for (int Qm = 0; Qm < 2; ++Qm)
        #pragma unroll
        for (int ml = 0; ml < 2; ++ml)
        #pragma unroll
        for (int jj = 0; jj < 4; ++jj) {
            int srow = bm + Qm * 128 + wl3 * 32 + ml * 16 + rl + jj;
            size_t ro = (size_t)srow * N;
            #pragma unroll
            for (int Qn = 0; Qn < 2; ++Qn)
            #pragma unroll
            for (int nl = 0; nl < 4; ++nl) {
                int col = bn + Qn * 128 + wn1 * 64 + nl * 16 + l15;
                float v = acc[Qm][ml][Qn][nl][jj] + bsv[Qn][nl];
                if (ACT) v = v > 0.f ? v : 0.2f * v;
                Hp[ro + col] = f2bf(v);
            }
        }
    } else {
        const int C = cnt[e];
        const float* wlp = wlb + (size_t)e * B_TOK;
        #pragma unroll
        for (int Qm = 0; Qm < 2; ++Qm)
        #pragma unroll
        for (int ml = 0; ml < 2; ++ml)
        #pragma unroll
        for (int jj = 0; jj < 4; ++jj) {
            int srow = bm + Qm * 128 + wl3 * 32 + ml * 16 + rl + jj;
            if (srow < C) {
                int tok = listp[srow];
                float wv = wlp[srow];
                size_t ro = (size_t)tok * D_DIM;
                #pragma unroll
                for (int Qn = 0; Qn < 2; ++Qn)
                #pragma unroll
                for (int nl = 0; nl < 4; ++nl) {
                    int col = bn + Qn * 128 + wn1 * 64 + nl * 16 + l15;
                    outb[ro + col] += (acc[Qm][ml][Qn][nl][jj] + bsv[Qn][nl]) * wv;
                }
            }
        }
    }
#undef PHASE
#undef LA
#undef LB
#undef STA
#undef STB
}

// ---------------- host launch ----------------

extern "C" void kernel_launch(void* const* d_in, const int* in_sizes, int n_in,
                              void* d_out, int out_size, void* d_ws, size_t ws_size,
                              hipStream_t stream)
{
    const float* x     = (const float*)d_in[0];
    // d_in[1] = gate (unused by reference forward)
    const float* probs = (const float*)d_in[2];
    const int*   tidx  = (const int*)d_in[3];
    const float* W1    = (const float*)d_in[4];
    const float* b1    = (const float*)d_in[5];
    const float* W2    = (const float*)d_in[6];
    const float* b2    = (const float*)d_in[7];
    const float* W3    = (const float*)d_in[8];
    const float* b3    = (const float*)d_in[9];
    float* out = (float*)d_out;

    // workspace layout (bytes); total ~237 MB
    char* ws = (char*)d_ws;
    const size_t xb_off  = 0;
    const size_t w1t_off = xb_off  + (size_t)B_TOK * IN_DIM * 2;
    const size_t w2t_off = w1t_off + (size_t)NEXP * IN_DIM * H1_DIM * 2;
    const size_t w3t_off = w2t_off + (size_t)NEXP * H1_DIM * H2_DIM * 2;
    const size_t h1_off  = w3t_off + (size_t)NEXP * H2_DIM * D_DIM * 2;
    const size_t h2_off  = h1_off  + (size_t)NEXP * B_TOK * H1_DIM * 2;   // per-expert planes
    const size_t li_off  = h2_off  + (size_t)NEXP * B_TOK * H2_DIM * 2;
    const size_t wl_off  = li_off  + (size_t)NEXP * B_TOK * 4;
    const size_t cn_off  = wl_off  + (size_t)NEXP * B_TOK * 4;
    const size_t cp_off  = cn_off  + 256;

    unsigned short* xb  = (unsigned short*)(ws + xb_off);
    unsigned short* W1t = (unsigned short*)(ws + w1t_off);
    unsigned short* W2t = (unsigned short*)(ws + w2t_off);
    unsigned short* W3t = (unsigned short*)(ws + w3t_off);
    unsigned short* h1  = (unsigned short*)(ws + h1_off);
    unsigned short* h2  = (unsigned short*)(ws + h2_off);
    int*            lst = (int*)(ws + li_off);
    float*          wl  = (float*)(ws + wl_off);
    int*            cnt = (int*)(ws + cn_off);
    int*            cnp = (int*)(ws + cp_off);

    hipMemsetAsync(out, 0, (size_t)out_size * sizeof(float), stream);
    hipMemsetAsync(cnt, 0, 256, stream);

    convert_f32_bf16<<<2048, 256, 0, stream>>>(x, xb, (size_t)B_TOK * IN_DIM);
    transpose_convert<<<dim3(H1_DIM / 64, IN_DIM / 64, NEXP), 256, 0, stream>>>(W1, W1t, IN_DIM, H1_DIM);
    transpose_convert<<<dim3(H2_DIM / 64, H1_DIM / 64, NEXP), 256, 0, stream>>>(W2, W2t, H1_DIM, H2_DIM);
    transpose_convert<<<dim3(D_DIM / 64, H2_DIM / 64, NEXP), 256, 0, stream>>>(W3, W3t, H2_DIM, D_DIM);
    route_tokens<<<B_TOK / 256, 256, 0, stream>>>(probs, tidx, cnt, lst, wl);
    finalize_counts<<<NEXP, 256, 0, stream>>>(cnt, cnp, lst, wl);

    const size_t h1pl = (size_t)B_TOK * H1_DIM;
    const size_t h2pl = (size_t)B_TOK * H2_DIM;

    // L1 grouped across experts: gathered x rows -> h1 planes
    gemm8<1, 0, 1><<<dim3(NEXP * 64 * 4), 512, 0, stream>>>(
        xb, 0, W1t, b1, h1, h1pl, nullptr, nullptr,
        lst, cnt, cnp, H1_DIM, IN_DIM, 4, 0);
    // L2 grouped: h1 planes -> h2 planes
    gemm8<1, 0, 0><<<dim3(NEXP * 64 * 2), 512, 0, stream>>>(
        h1, h1pl, W2t, b2, h2, h2pl, nullptr, nullptr,
        lst, cnt, cnp, H2_DIM, H1_DIM, 2, 0);
    // L3 per expert (stream-ordered +=, race-free): h2 plane -> out
    for (int e = 0; e < NEXP; ++e) {
        gemm8<0, 1, 0><<<dim3(64 * 4), 512, 0, stream>>>(
            h2, h2pl, W3t, b3, nullptr, 0, out, wl,
            lst, cnt, cnp, D_DIM, H2_DIM, 4, e);
    }
}

// Round 5
// 338.917 us; speedup vs baseline: 1.5747x; 1.0891x over previous
//
#include <hip/hip_runtime.h>
#include <cstdint>
#include <cstddef>

// Problem constants (match reference setup_inputs)
#define B_TOK   16384
#define IN_DIM  2048
#define D_DIM   1024
#define NEXP    3
#define TOPK    2
#define H1_DIM  1024
#define H2_DIM  512

typedef __bf16 bf16x8 __attribute__((ext_vector_type(8)));
typedef float  f32x4  __attribute__((ext_vector_type(4)));
typedef unsigned short ushort8_t __attribute__((ext_vector_type(8)));

__device__ __forceinline__ unsigned short f2bf(float f) {
    unsigned int u = __builtin_bit_cast(unsigned int, f);
    return (unsigned short)((u + 0x7fffu + ((u >> 16) & 1u)) >> 16);
}

// async global->LDS, 16B per lane. LDS dest is wave-uniform base + lane*16;
// global source address IS per-lane (enables gather + inverse-swizzle).
__device__ __forceinline__ void glds16(const void* gsrc, void* ldst) {
    __builtin_amdgcn_global_load_lds(
        (__attribute__((address_space(1))) void*)(gsrc),
        (__attribute__((address_space(3))) void*)(ldst),
        16, 0, 0);
}

// ---------------- prepass kernels ----------------

__global__ __launch_bounds__(256) void convert_f32_bf16(
    const float* __restrict__ in, unsigned short* __restrict__ out, size_t n)
{
    size_t i = ((size_t)blockIdx.x * blockDim.x + threadIdx.x) * 8;
    size_t stride = (size_t)gridDim.x * blockDim.x * 8;
    for (; i < n; i += stride) {
        float4 a = *(const float4*)(in + i);
        float4 b = *(const float4*)(in + i + 4);
        ushort8_t o;
        o[0] = f2bf(a.x); o[1] = f2bf(a.y); o[2] = f2bf(a.z); o[3] = f2bf(a.w);
        o[4] = f2bf(b.x); o[5] = f2bf(b.y); o[6] = f2bf(b.z); o[7] = f2bf(b.w);
        *(ushort8_t*)(out + i) = o;
    }
}

// W [E][K][N] f32 -> Wt [E][N][K] bf16, 64x64 tiles through LDS
__global__ __launch_bounds__(256) void transpose_convert(
    const float* __restrict__ W, unsigned short* __restrict__ Wt, int K, int N)
{
    __shared__ unsigned short tile[64][68];
    int e = blockIdx.z;
    const float* Wp = W + (size_t)e * K * N;
    unsigned short* Wtp = Wt + (size_t)e * N * K;
    int n0 = blockIdx.x * 64, k0 = blockIdx.y * 64;
    int t = threadIdx.x;
    int nn = (t & 15) * 4;
    int kk = t >> 4;
    #pragma unroll
    for (int r = 0; r < 4; ++r) {
        int k = kk + r * 16;
        float4 v = *(const float4*)(Wp + (size_t)(k0 + k) * N + (n0 + nn));
        tile[k][nn + 0] = f2bf(v.x);
        tile[k][nn + 1] = f2bf(v.y);
        tile[k][nn + 2] = f2bf(v.z);
        tile[k][nn + 3] = f2bf(v.w);
    }
    __syncthreads();
    int n  = t >> 2;
    int kb = (t & 3) * 16;
    ushort8_t o0, o1;
    #pragma unroll
    for (int i = 0; i < 8; ++i) o0[i] = tile[kb + i][n];
    #pragma unroll
    for (int i = 0; i < 8; ++i) o1[i] = tile[kb + 8 + i][n];
    unsigned short* dst = Wtp + (size_t)(n0 + n) * K + (k0 + kb);
    *(ushort8_t*)dst = o0;
    *(ushort8_t*)(dst + 8) = o1;
}

// Two-phase token routing: per-block LDS count+stage, one global atomicAdd
// per (block, expert), then compact write of token ids + combine weights.
// Slot order is nondeterministic across replays, but each per-token output
// value is independent of its slot, so d_out stays deterministic.
__global__ __launch_bounds__(256) void route_tokens(
    const float* __restrict__ probs, const int* __restrict__ idx,
    int* __restrict__ cnt, int* __restrict__ list, float* __restrict__ wl)
{
    __shared__ int lcnt[NEXP];
    __shared__ int lbase[NEXP];
    __shared__ int ltok[NEXP][256];
    __shared__ float lww[NEXP][256];
    int t = threadIdx.x;
    int b = blockIdx.x * 256 + t;
    if (t < NEXP) lcnt[t] = 0;
    __syncthreads();
    float p0 = probs[b * TOPK + 0], p1 = probs[b * TOPK + 1];
    int   i0 = idx[b * TOPK + 0],   i1 = idx[b * TOPK + 1];
    #pragma unroll
    for (int e = 0; e < NEXP; ++e) {
        bool m0 = (i0 == e), m1 = (i1 == e);
        if (m0 || m1) {
            float w = (m0 ? p0 : 0.f) + (m1 ? p1 : 0.f);
            int s = atomicAdd(&lcnt[e], 1);
            ltok[e][s] = b; lww[e][s] = w;
        }
    }
    __syncthreads();
    if (t < NEXP) lbase[t] = atomicAdd(&cnt[t], lcnt[t]);
    __syncthreads();
    #pragma unroll
    for (int e = 0; e < NEXP; ++e) {
        int n = lcnt[e], base = lbase[e];
        for (int s = t; s < n; s += 256) {
            list[e * B_TOK + base + s] = ltok[e][s];
            wl[e * B_TOK + base + s]   = lww[e][s];
        }
    }
}

// round counts up to 256-tile multiple; pad list with token 0 (weight 0)
__global__ void finalize_counts(const int* __restrict__ cnt, int* __restrict__ cntp,
                                int* __restrict__ list, float* __restrict__ wl)
{
    int e = blockIdx.x;
    int c = cnt[e];
    int cp = (c + 255) & ~255;
    if (threadIdx.x == 0) cntp[e] = cp;
    for (int s = c + threadIdx.x; s < cp; s += blockDim.x) {
        list[e * B_TOK + s] = 0;
        wl[e * B_TOK + s] = 0.f;
    }
}

// ---------------- 8-phase 256x256 GEMM, pipelined windows ----------------
// C = act(A[slots,K] @ Bt[N,K]^T + bias). BM=BN=256, BK=64, 8 waves (512 thr),
// LDS 128KiB = 2 dbuf x {A,B} x 2 half x [128][64] bf16.
// Round-4 post-mortem: lockstep {reads; barrier; MFMA; barrier} serializes the
// LDS pipe (224cy) with MFMA (155cy) -> 38% MfmaUtil. This version issues the
// NEXT window's ds_reads AFTER the current MFMA cluster (double-buffer makes
// the read buffer stable all iteration) and uses ONE barrier per window:
//   window i: {stage; lgkmcnt(0); MFMA(regs from i-1); [vmcnt(4)]; reads(i+1); barrier}
// WAR ledger (read-issue -> stage of same region, >=1 barrier between):
//   A00:r@1,s@3  B01:r@2,s@6  A01:r@3/8,s@5  A11:r@4/7,s@1'  B10:r@4,s@8
//   A10:r@5,s@7  B11:r@6,s@2'  B00:r@8,s@4'   (all hold)
// RAW: vmcnt(4)@ph4 drains stages through ph2 (covers buf1 reads @4);
//      vmcnt(4)@ph8 drains through ph6 (covers buf0 reads @8). Never 0 in-loop.
template<int ACT, int FINAL, int GATHER>
__global__ __launch_bounds__(512, 2) void gemm8(
    const unsigned short* __restrict__ Ab, size_t Aplane,  // bf16 [slots][K] (per-expert plane if !GATHER)
    const unsigned short* __restrict__ Bb,                 // bf16 [E][N][K]
    const float* __restrict__ biasb,                       // [E][N]
    unsigned short* __restrict__ Hb, size_t Hplane,        // bf16 [E][slots][N] (if !FINAL)
    float* __restrict__ outb,                              // f32 [B_TOK][D]    (if FINAL, atomicAdd)
    const float* __restrict__ wlb,                         // [E][B_TOK]
    const int* __restrict__ listb,                         // [E][B_TOK]
    const int* __restrict__ cnt,                           // [E] actual count
    const int* __restrict__ cntp,                          // [E] padded count
    int N, int K, int NT, int e0)
{
    // bijective tile->XCD mapping: xcd=bid&7; XCD x walks A-tiles {x,x+8,...}
    // with the NT N-blocks of each A-tile consecutive (L2 A-reuse); live
    // tiles (early-exit) spread evenly across XCDs.
    const int bid  = blockIdx.x;
    const int xcd  = bid & 7;
    const int slot = bid >> 3;
    const int q    = slot / NT;
    const int nt   = slot % NT;
    const int ti   = q * 8 + xcd;
    const int e    = e0 + (ti >> 6);
    const int mt   = ti & 63;
    const int bm   = mt << 8;
    if (bm >= cntp[e]) return;
    const int bn   = nt << 8;

    __shared__ char smem[131072];   // A: [0,64K)  B: [64K,128K)

    const int tid  = threadIdx.x;
    const int lane = tid & 63;
    const int w    = tid >> 6;      // wave 0..7
    const int wl3  = w & 3;         // A 32-row band within half
    const int wn1  = w >> 2;        // B 64-col band within half
    const int l15  = lane & 15;
    const int ug8  = (((tid & 7) ^ ((tid >> 3) & 7)) << 3);          // src swz (shorts)
    const int sw0  = ((((lane >> 4) + 0) ^ (lane & 7)) << 4);        // read swz k0 (bytes)
    const int sw1  = ((((lane >> 4) + 4) ^ (lane & 7)) << 4);        // read swz k1 (bytes)

    const int* listp = listb + (size_t)e * B_TOK;
    const unsigned short* Ae = Ab + (size_t)e * Aplane;
    const unsigned short* Be = Bb + (size_t)e * ((size_t)N * K);
    const float* biasp = biasb + (size_t)e * N;

    // per-thread stage source pointers: half h, load j covers tile row
    // h*128 + j*64 + (tid>>3); 16B unit = (tid&7) ^ ((tid>>3)&7)  (inverse swz)
    const unsigned short* sA[2][2];
    const unsigned short* sB[2][2];
    #pragma unroll
    for (int h = 0; h < 2; ++h)
        #pragma unroll
        for (int j = 0; j < 2; ++j) {
            int lrow = h * 128 + j * 64 + (tid >> 3);
            int arow;
            if constexpr (GATHER) arow = listp[bm + lrow];
            else                  arow = bm + lrow;
            sA[h][j] = Ae + (size_t)arow * K + ug8;
            sB[h][j] = Be + (size_t)(bn + lrow) * K + ug8;
        }

    char* const stA = smem + (w << 10);            // + db*32768 + h*16384 (+8192 for j=1)
    char* const stB = smem + 65536 + (w << 10);
    const char* const rA = smem + (wl3 * 32 + l15) * 128;           // + db*32768 + Qm*16384 + ml*2048 + sw
    const char* const rB = smem + 65536 + (wn1 * 64 + l15) * 128;   // + db*32768 + Qn*16384 + nl*2048 + sw

    f32x4 acc[2][2][2][4] = {};   // [Qm][ml][Qn][nl]
    bf16x8 av[2][2];              // A operand regs (current quadrant)
    bf16x8 bv[4][2];              // B operand regs (current quadrant)

#define STA(db, h, kt) do {                                                     \
    glds16(sA[h][0] + (size_t)(kt) * 64, stA + (db) * 32768 + (h) * 16384);     \
    glds16(sA[h][1] + (size_t)(kt) * 64, stA + (db) * 32768 + (h) * 16384 + 8192); } while (0)
#define STB(db, h, kt) do {                                                     \
    glds16(sB[h][0] + (size_t)(kt) * 64, stB + (db) * 32768 + (h) * 16384);     \
    glds16(sB[h][1] + (size_t)(kt) * 64, stB + (db) * 32768 + (h) * 16384 + 8192); } while (0)

#define LA(db, Qm) do {                                                         \
    _Pragma("unroll")                                                           \
    for (int ml = 0; ml < 2; ++ml) {                                            \
        av[ml][0] = *(const bf16x8*)(rA + (db)*32768 + (Qm)*16384 + ml*2048 + sw0); \
        av[ml][1] = *(const bf16x8*)(rA + (db)*32768 + (Qm)*16384 + ml*2048 + sw1); \
    } } while (0)
#define LB(db, Qn) do {                                                         \
    _Pragma("unroll")                                                           \
    for (int nl = 0; nl < 4; ++nl) {                                            \
        bv[nl][0] = *(const bf16x8*)(rB + (db)*32768 + (Qn)*16384 + nl*2048 + sw0); \
        bv[nl][1] = *(const bf16x8*)(rB + (db)*32768 + (Qn)*16384 + nl*2048 + sw1); \
    } } while (0)

// window: stage; wait prev reads; MFMA on current regs; (vmcnt); issue next
// window's reads; single barrier.
#define WINDOW(Qm, Qn, STAGE_STMT, VM_STMT, NEXT_LOADS) do {                    \
    STAGE_STMT;                                                                 \
    asm volatile("s_waitcnt lgkmcnt(0)" ::: "memory");                          \
    __builtin_amdgcn_sched_barrier(0);                                          \
    __builtin_amdgcn_s_setprio(1);                                              \
    _Pragma("unroll")                                                           \
    for (int ml = 0; ml < 2; ++ml)                                              \
        _Pragma("unroll")                                                       \
        for (int nl = 0; nl < 4; ++nl) {                                        \
            acc[Qm][ml][Qn][nl] = __builtin_amdgcn_mfma_f32_16x16x32_bf16(      \
                av[ml][0], bv[nl][0], acc[Qm][ml][Qn][nl], 0, 0, 0);            \
            acc[Qm][ml][Qn][nl] = __builtin_amdgcn_mfma_f32_16x16x32_bf16(      \
                av[ml][1], bv[nl][1], acc[Qm][ml][Qn][nl], 0, 0, 0);            \
        }                                                                       \
    __builtin_amdgcn_s_setprio(0);                                              \
    VM_STMT;                                                                    \
    NEXT_LOADS;                                                                 \
    __builtin_amdgcn_sched_barrier(0);                                          \
    __builtin_amdgcn_s_barrier();                                               \
} while (0)

    const int nkt = K >> 6;           // 64-wide K-tiles (even for all layers)
    // prologue: buf0 = tile0 full; buf1 h0 = tile1 {A,B}; then first reads
    STA(0, 0, 0); STA(0, 1, 0); STB(0, 0, 0); STB(0, 1, 0);
    STA(1, 0, 1); STB(1, 0, 1);
    asm volatile("s_waitcnt vmcnt(4)" ::: "memory");   // buf0's 8 loads landed
    __builtin_amdgcn_s_barrier();
    LA(0, 1); LB(0, 0);                                // regs for window 1

    const int niter = nkt >> 1;
    for (int it = 0; it < niter; ++it) {
        const int t1 = 2 * it + 1;
        const int t2 = (2 * it + 2 < nkt) ? 2 * it + 2 : nkt - 1;  // clamped: dead stages
        const int t3 = (2 * it + 3 < nkt) ? 2 * it + 3 : nkt - 1;
        WINDOW(1, 0, STA(1, 1, t1), ((void)0), LA(0, 0));
        WINDOW(0, 0, STB(1, 1, t1), ((void)0), LB(0, 1));
        WINDOW(0, 1, STA(0, 0, t2), ((void)0), LA(0, 1));
        WINDOW(1, 1, STB(0, 0, t2),
               asm volatile("s_waitcnt vmcnt(4)" ::: "memory"), LA(1, 1); LB(1, 0));
        WINDOW(1, 0, STA(0, 1, t2), ((void)0), LA(1, 0));
        WINDOW(0, 0, STB(0, 1, t2), ((void)0), LB(1, 1));
        WINDOW(0, 1, STA(1, 0, t3), ((void)0), LA(1, 1));
        WINDOW(1, 1, STB(1, 0, t3),
               asm volatile("s_waitcnt vmcnt(4)" ::: "memory"), LA(0, 1); LB(0, 0));
    }
    asm volatile("s_waitcnt vmcnt(0)" ::: "memory");   // drain tail stages

    // epilogue. C/D (m89-verified): col = lane&15 (B side), row = (lane>>4)*4+jj
    const int rl = (lane >> 4) << 2;
    float bsv[2][4];
    #pragma unroll
    for (int Qn = 0; Qn < 2; ++Qn)
        #pragma unroll
        for (int nl = 0; nl < 4; ++nl)
            bsv[Qn][nl] = biasp[bn + Qn * 128 + wn1 * 64 + nl * 16 + l15];

    if constexpr (!FINAL) {
        unsigned short* Hp = Hb + (size_t)e * Hplane;
        #pragma unroll
        for (int Qm = 0; Qm < 2; ++Qm)
        #pragma unroll
        for (int ml = 0; ml < 2; ++ml)
        #pragma unroll
        for (int jj = 0; jj < 4; ++jj) {
            int srow = bm + Qm * 128 + wl3 * 32 + ml * 16 + rl + jj;
            size_t ro = (size_t)srow * N;
            #pragma unroll
            for (int Qn = 0; Qn < 2; ++Qn)
            #pragma unroll
            for (int nl = 0; nl < 4; ++nl) {
                int col = bn + Qn * 128 + wn1 * 64 + nl * 16 + l15;
                float v = acc[Qm][ml][Qn][nl][jj] + bsv[Qn][nl];
                if (ACT) v = v > 0.f ? v : 0.2f * v;
                Hp[ro + col] = f2bf(v);
            }
        }
    } else {
        // grouped scatter-accumulate: each (tok,col) receives <=2 expert
        // contributions (route merges duplicate top-k); 0+c1+c2 is order-
        // invariant for two IEEE adds -> bitwise deterministic across replays.
        const int C = cnt[e];
        const float* wlp = wlb + (size_t)e * B_TOK;
        #pragma unroll
        for (int Qm = 0; Qm < 2; ++Qm)
        #pragma unroll
        for (int ml = 0; ml < 2; ++ml)
        #pragma unroll
        for (int jj = 0; jj < 4; ++jj) {
            int srow = bm + Qm * 128 + wl3 * 32 + ml * 16 + rl + jj;
            if (srow < C) {
                int tok = listp[srow];
                float wv = wlp[srow];
                size_t ro = (size_t)tok * D_DIM;
                #pragma unroll
                for (int Qn = 0; Qn < 2; ++Qn)
                #pragma unroll
                for (int nl = 0; nl < 4; ++nl) {
                    int col = bn + Qn * 128 + wn1 * 64 + nl * 16 + l15;
                    atomicAdd(&outb[ro + col],
                              (acc[Qm][ml][Qn][nl][jj] + bsv[Qn][nl]) * wv);
                }
            }
        }
    }
#undef WINDOW
#undef LA
#undef LB
#undef STA
#undef STB
}

// ---------------- host launch ----------------

extern "C" void kernel_launch(void* const* d_in, const int* in_sizes, int n_in,
                              void* d_out, int out_size, void* d_ws, size_t ws_size,
                              hipStream_t stream)
{
    const float* x     = (const float*)d_in[0];
    // d_in[1] = gate (unused by reference forward)
    const float* probs = (const float*)d_in[2];
    const int*   tidx  = (const int*)d_in[3];
    const float* W1    = (const float*)d_in[4];
    const float* b1    = (const float*)d_in[5];
    const float* W2    = (const float*)d_in[6];
    const float* b2    = (const float*)d_in[7];
    const float* W3    = (const float*)d_in[8];
    const float* b3    = (const float*)d_in[9];
    float* out = (float*)d_out;

    // workspace layout (bytes); total ~237 MB
    char* ws = (char*)d_ws;
    const size_t xb_off  = 0;
    const size_t w1t_off = xb_off  + (size_t)B_TOK * IN_DIM * 2;
    const size_t w2t_off = w1t_off + (size_t)NEXP * IN_DIM * H1_DIM * 2;
    const size_t w3t_off = w2t_off + (size_t)NEXP * H1_DIM * H2_DIM * 2;
    const size_t h1_off  = w3t_off + (size_t)NEXP * H2_DIM * D_DIM * 2;
    const size_t h2_off  = h1_off  + (size_t)NEXP * B_TOK * H1_DIM * 2;   // per-expert planes
    const size_t li_off  = h2_off  + (size_t)NEXP * B_TOK * H2_DIM * 2;
    const size_t wl_off  = li_off  + (size_t)NEXP * B_TOK * 4;
    const size_t cn_off  = wl_off  + (size_t)NEXP * B_TOK * 4;
    const size_t cp_off  = cn_off  + 256;

    unsigned short* xb  = (unsigned short*)(ws + xb_off);
    unsigned short* W1t = (unsigned short*)(ws + w1t_off);
    unsigned short* W2t = (unsigned short*)(ws + w2t_off);
    unsigned short* W3t = (unsigned short*)(ws + w3t_off);
    unsigned short* h1  = (unsigned short*)(ws + h1_off);
    unsigned short* h2  = (unsigned short*)(ws + h2_off);
    int*            lst = (int*)(ws + li_off);
    float*          wl  = (float*)(ws + wl_off);
    int*            cnt = (int*)(ws + cn_off);
    int*            cnp = (int*)(ws + cp_off);

    hipMemsetAsync(out, 0, (size_t)out_size * sizeof(float), stream);
    hipMemsetAsync(cnt, 0, 256, stream);

    convert_f32_bf16<<<2048, 256, 0, stream>>>(x, xb, (size_t)B_TOK * IN_DIM);
    transpose_convert<<<dim3(H1_DIM / 64, IN_DIM / 64, NEXP), 256, 0, stream>>>(W1, W1t, IN_DIM, H1_DIM);
    transpose_convert<<<dim3(H2_DIM / 64, H1_DIM / 64, NEXP), 256, 0, stream>>>(W2, W2t, H1_DIM, H2_DIM);
    transpose_convert<<<dim3(D_DIM / 64, H2_DIM / 64, NEXP), 256, 0, stream>>>(W3, W3t, H2_DIM, D_DIM);
    route_tokens<<<B_TOK / 256, 256, 0, stream>>>(probs, tidx, cnt, lst, wl);
    finalize_counts<<<NEXP, 256, 0, stream>>>(cnt, cnp, lst, wl);

    const size_t h1pl = (size_t)B_TOK * H1_DIM;
    const size_t h2pl = (size_t)B_TOK * H2_DIM;

    // L1 grouped across experts: gathered x rows -> h1 planes
    gemm8<1, 0, 1><<<dim3(NEXP * 64 * 4), 512, 0, stream>>>(
        xb, 0, W1t, b1, h1, h1pl, nullptr, nullptr,
        lst, cnt, cnp, H1_DIM, IN_DIM, 4, 0);
    // L2 grouped: h1 planes -> h2 planes
    gemm8<1, 0, 0><<<dim3(NEXP * 64 * 2), 512, 0, stream>>>(
        h1, h1pl, W2t, b2, h2, h2pl, nullptr, nullptr,
        lst, cnt, cnp, H2_DIM, H1_DIM, 2, 0);
    // L3 grouped: h2 planes -> out (atomicAdd; deterministic, see epilogue)
    gemm8<0, 1, 0><<<dim3(NEXP * 64 * 4), 512, 0, stream>>>(
        h2, h2pl, W3t, b3, nullptr, 0, out, wl,
        lst, cnt, cnp, D_DIM, H2_DIM, 4, 0);
}

// Round 6
// 302.655 us; speedup vs baseline: 1.7634x; 1.1198x over previous
//
#include <hip/hip_runtime.h>
#include <cstdint>
#include <cstddef>

// Problem constants (match reference setup_inputs)
#define B_TOK   16384
#define IN_DIM  2048
#define D_DIM   1024
#define NEXP    3
#define TOPK    2
#define H1_DIM  1024
#define H2_DIM  512

typedef __bf16 bf16x8 __attribute__((ext_vector_type(8)));
typedef float  f32x4  __attribute__((ext_vector_type(4)));
typedef unsigned short ushort8_t __attribute__((ext_vector_type(8)));

__device__ __forceinline__ unsigned short f2bf(float f) {
    unsigned int u = __builtin_bit_cast(unsigned int, f);
    return (unsigned short)((u + 0x7fffu + ((u >> 16) & 1u)) >> 16);
}

// async global->LDS, 16B per lane. LDS dest is wave-uniform base + lane*16;
// global source address IS per-lane (enables gather + inverse-swizzle).
__device__ __forceinline__ void glds16(const void* gsrc, void* ldst) {
    __builtin_amdgcn_global_load_lds(
        (__attribute__((address_space(1))) void*)(gsrc),
        (__attribute__((address_space(3))) void*)(ldst),
        16, 0, 0);
}

// ---------------- prepass kernels ----------------

__global__ __launch_bounds__(256) void convert_f32_bf16(
    const float* __restrict__ in, unsigned short* __restrict__ out, size_t n)
{
    size_t i = ((size_t)blockIdx.x * blockDim.x + threadIdx.x) * 8;
    size_t stride = (size_t)gridDim.x * blockDim.x * 8;
    for (; i < n; i += stride) {
        float4 a = *(const float4*)(in + i);
        float4 b = *(const float4*)(in + i + 4);
        ushort8_t o;
        o[0] = f2bf(a.x); o[1] = f2bf(a.y); o[2] = f2bf(a.z); o[3] = f2bf(a.w);
        o[4] = f2bf(b.x); o[5] = f2bf(b.y); o[6] = f2bf(b.z); o[7] = f2bf(b.w);
        *(ushort8_t*)(out + i) = o;
    }
}

// W [E][K][N] f32 -> Wt [E][N][K] bf16, 64x64 tiles through LDS
__global__ __launch_bounds__(256) void transpose_convert(
    const float* __restrict__ W, unsigned short* __restrict__ Wt, int K, int N)
{
    __shared__ unsigned short tile[64][68];
    int e = blockIdx.z;
    const float* Wp = W + (size_t)e * K * N;
    unsigned short* Wtp = Wt + (size_t)e * N * K;
    int n0 = blockIdx.x * 64, k0 = blockIdx.y * 64;
    int t = threadIdx.x;
    int nn = (t & 15) * 4;
    int kk = t >> 4;
    #pragma unroll
    for (int r = 0; r < 4; ++r) {
        int k = kk + r * 16;
        float4 v = *(const float4*)(Wp + (size_t)(k0 + k) * N + (n0 + nn));
        tile[k][nn + 0] = f2bf(v.x);
        tile[k][nn + 1] = f2bf(v.y);
        tile[k][nn + 2] = f2bf(v.z);
        tile[k][nn + 3] = f2bf(v.w);
    }
    __syncthreads();
    int n  = t >> 2;
    int kb = (t & 3) * 16;
    ushort8_t o0, o1;
    #pragma unroll
    for (int i = 0; i < 8; ++i) o0[i] = tile[kb + i][n];
    #pragma unroll
    for (int i = 0; i < 8; ++i) o1[i] = tile[kb + 8 + i][n];
    unsigned short* dst = Wtp + (size_t)(n0 + n) * K + (k0 + kb);
    *(ushort8_t*)dst = o0;
    *(ushort8_t*)(dst + 8) = o1;
}

// Two-phase token routing. Also writes inv[e][tok] = compact slot of tok in
// expert e's list (used by the combine pass). Slot order is nondeterministic
// across replays, but every per-token output value is slot-independent, so
// d_out stays deterministic.
__global__ __launch_bounds__(256) void route_tokens(
    const float* __restrict__ probs, const int* __restrict__ idx,
    int* __restrict__ cnt, int* __restrict__ list, int* __restrict__ inv)
{
    __shared__ int lcnt[NEXP];
    __shared__ int lbase[NEXP];
    __shared__ int ltok[NEXP][256];
    int t = threadIdx.x;
    int b = blockIdx.x * 256 + t;
    if (t < NEXP) lcnt[t] = 0;
    __syncthreads();
    int i0 = idx[b * TOPK + 0], i1 = idx[b * TOPK + 1];
    #pragma unroll
    for (int e = 0; e < NEXP; ++e) {
        if (i0 == e || i1 == e) {
            int s = atomicAdd(&lcnt[e], 1);
            ltok[e][s] = b;
        }
    }
    __syncthreads();
    if (t < NEXP) lbase[t] = atomicAdd(&cnt[t], lcnt[t]);
    __syncthreads();
    #pragma unroll
    for (int e = 0; e < NEXP; ++e) {
        int n = lcnt[e], base = lbase[e];
        for (int s = t; s < n; s += 256) {
            int tk = ltok[e][s];
            list[e * B_TOK + base + s] = tk;
            inv[e * B_TOK + tk] = base + s;
        }
    }
}

// round counts up to 256-tile multiple; pad list with token 0
__global__ void finalize_counts(const int* __restrict__ cnt, int* __restrict__ cntp,
                                int* __restrict__ list)
{
    int e = blockIdx.x;
    int c = cnt[e];
    int cp = (c + 255) & ~255;
    if (threadIdx.x == 0) cntp[e] = cp;
    for (int s = c + threadIdx.x; s < cp; s += blockDim.x)
        list[e * B_TOK + s] = 0;
}

// combine: out[tok] = p0 * y[i0][inv[i0][tok]] + p1 * y[i1][inv[i1][tok]]
// (handles i0==i1 naturally: (p0+p1)*y). Writes EVERY output element.
__global__ __launch_bounds__(256) void combine_out(
    const float* __restrict__ probs, const int* __restrict__ tidx,
    const int* __restrict__ inv, const float* __restrict__ y, size_t ypl,
    float* __restrict__ out)
{
    int gid = blockIdx.x * 256 + threadIdx.x;
    int tok = gid >> 7;              // 128 threads per token
    int dc  = (gid & 127) << 3;      // 8 cols per thread
    float p0 = probs[tok * TOPK + 0], p1 = probs[tok * TOPK + 1];
    int   i0 = tidx [tok * TOPK + 0], i1 = tidx [tok * TOPK + 1];
    size_t r0 = (size_t)i0 * ypl + (size_t)inv[(size_t)i0 * B_TOK + tok] * D_DIM + dc;
    size_t r1 = (size_t)i1 * ypl + (size_t)inv[(size_t)i1 * B_TOK + tok] * D_DIM + dc;
    float4 a0 = *(const float4*)(y + r0), a1 = *(const float4*)(y + r0 + 4);
    float4 b0 = *(const float4*)(y + r1), b1 = *(const float4*)(y + r1 + 4);
    float4 o0, o1;
    o0.x = p0 * a0.x + p1 * b0.x;  o0.y = p0 * a0.y + p1 * b0.y;
    o0.z = p0 * a0.z + p1 * b0.z;  o0.w = p0 * a0.w + p1 * b0.w;
    o1.x = p0 * a1.x + p1 * b1.x;  o1.y = p0 * a1.y + p1 * b1.y;
    o1.z = p0 * a1.z + p1 * b1.z;  o1.w = p0 * a1.w + p1 * b1.w;
    float* op = out + (size_t)tok * D_DIM + dc;
    *(float4*)op = o0;
    *(float4*)(op + 4) = o1;
}

// ---------------- 8-phase 256x256 GEMM, pipelined windows ----------------
// C = act(A[slots,K] @ Bt[N,K]^T + bias). BM=BN=256, BK=64, 8 waves (512 thr),
// LDS 128KiB = 2 dbuf x {A,B} x 2 half x [128][64] bf16.
// Round-5 post-mortem: explicit lgkmcnt(0)+sched_barrier at window head forced
// a FULL drain of the prior window's ds_reads before the first MFMA. This
// version lets the compiler insert COUNTED lgkm waits per MFMA operand use
// (guide: it does this reliably for non-asm ds reads), so early MFMAs overlap
// late read returns. Order pinned with sched_barrier(0) fences:
//   window i: {stage; || MFMA(regs, counted waits); [vmcnt(4)]; SB;
//              reads(i+1); SB; barrier}
// WAR ledger (reads complete by end of their use-window's MFMA cluster; the
// same region's re-stage is >=1 full barrier later):
//   A00:r@1,u@2,s@3  B01:r@2,u@3,s@6  A01:r@3,u@4,s@5  A11:r@4,u@5,s@1'
//   B10:r@4,u@5,s@8  A10:r@5,u@6,s@7  B11:r@6,u@7,s@2'  B00:r@8,u@1',s@4'
// RAW: vmcnt(4)@ph4 drains stages through ph2 (covers buf1 reads @4);
//      vmcnt(4)@ph8 drains through ph6 (covers buf0 reads @8). Never 0 in-loop.
template<int ACT, int OUT32, int GATHER>
__global__ __launch_bounds__(512, 2) void gemm8(
    const unsigned short* __restrict__ Ab, size_t Aplane,  // bf16 [slots][K] (per-expert plane if !GATHER)
    const unsigned short* __restrict__ Bb,                 // bf16 [E][N][K]
    const float* __restrict__ biasb,                       // [E][N]
    unsigned short* __restrict__ Hb,                       // bf16 planes (if !OUT32)
    float* __restrict__ Yb,                                // f32 planes  (if OUT32)
    size_t plane,                                          // elements per plane
    const int* __restrict__ listb,                         // [E][B_TOK]
    const int* __restrict__ cntp,                          // [E] padded count
    int N, int K, int NT, int e0)
{
    // bijective tile->XCD mapping: xcd=bid&7; XCD x walks A-tiles {x,x+8,...}
    // with the NT N-blocks of each A-tile consecutive (L2 A-reuse); live
    // tiles (early-exit) spread evenly across XCDs.
    const int bid  = blockIdx.x;
    const int xcd  = bid & 7;
    const int slot = bid >> 3;
    const int q    = slot / NT;
    const int nt   = slot % NT;
    const int ti   = q * 8 + xcd;
    const int e    = e0 + (ti >> 6);
    const int mt   = ti & 63;
    const int bm   = mt << 8;
    if (bm >= cntp[e]) return;
    const int bn   = nt << 8;

    __shared__ char smem[131072];   // A: [0,64K)  B: [64K,128K)

    const int tid  = threadIdx.x;
    const int lane = tid & 63;
    const int w    = tid >> 6;      // wave 0..7
    const int wl3  = w & 3;         // A 32-row band within half
    const int wn1  = w >> 2;        // B 64-col band within half
    const int l15  = lane & 15;
    const int ug8  = (((tid & 7) ^ ((tid >> 3) & 7)) << 3);          // src swz (shorts)
    const int sw0  = ((((lane >> 4) + 0) ^ (lane & 7)) << 4);        // read swz k0 (bytes)
    const int sw1  = ((((lane >> 4) + 4) ^ (lane & 7)) << 4);        // read swz k1 (bytes)

    const int* listp = listb + (size_t)e * B_TOK;
    const unsigned short* Ae = Ab + (size_t)e * Aplane;
    const unsigned short* Be = Bb + (size_t)e * ((size_t)N * K);
    const float* biasp = biasb + (size_t)e * N;

    // per-thread stage source pointers: half h, load j covers tile row
    // h*128 + j*64 + (tid>>3); 16B unit = (tid&7) ^ ((tid>>3)&7)  (inverse swz)
    const unsigned short* sA[2][2];
    const unsigned short* sB[2][2];
    #pragma unroll
    for (int h = 0; h < 2; ++h)
        #pragma unroll
        for (int j = 0; j < 2; ++j) {
            int lrow = h * 128 + j * 64 + (tid >> 3);
            int arow;
            if constexpr (GATHER) arow = listp[bm + lrow];
            else                  arow = bm + lrow;
            sA[h][j] = Ae + (size_t)arow * K + ug8;
            sB[h][j] = Be + (size_t)(bn + lrow) * K + ug8;
        }

    char* const stA = smem + (w << 10);            // + db*32768 + h*16384 (+8192 for j=1)
    char* const stB = smem + 65536 + (w << 10);
    const char* const rA = smem + (wl3 * 32 + l15) * 128;           // + db*32768 + Qm*16384 + ml*2048 + sw
    const char* const rB = smem + 65536 + (wn1 * 64 + l15) * 128;   // + db*32768 + Qn*16384 + nl*2048 + sw

    f32x4 acc[2][2][2][4] = {};   // [Qm][ml][Qn][nl]
    bf16x8 av[2][2];              // A operand regs (current quadrant)
    bf16x8 bv[4][2];              // B operand regs (current quadrant)

#define STA(db, h, kt) do {                                                     \
    glds16(sA[h][0] + (size_t)(kt) * 64, stA + (db) * 32768 + (h) * 16384);     \
    glds16(sA[h][1] + (size_t)(kt) * 64, stA + (db) * 32768 + (h) * 16384 + 8192); } while (0)
#define STB(db, h, kt) do {                                                     \
    glds16(sB[h][0] + (size_t)(kt) * 64, stB + (db) * 32768 + (h) * 16384);     \
    glds16(sB[h][1] + (size_t)(kt) * 64, stB + (db) * 32768 + (h) * 16384 + 8192); } while (0)

#define LA(db, Qm) do {                                                         \
    _Pragma("unroll")                                                           \
    for (int ml = 0; ml < 2; ++ml) {                                            \
        av[ml][0] = *(const bf16x8*)(rA + (db)*32768 + (Qm)*16384 + ml*2048 + sw0); \
        av[ml][1] = *(const bf16x8*)(rA + (db)*32768 + (Qm)*16384 + ml*2048 + sw1); \
    } } while (0)
#define LB(db, Qn) do {                                                         \
    _Pragma("unroll")                                                           \
    for (int nl = 0; nl < 4; ++nl) {                                            \
        bv[nl][0] = *(const bf16x8*)(rB + (db)*32768 + (Qn)*16384 + nl*2048 + sw0); \
        bv[nl][1] = *(const bf16x8*)(rB + (db)*32768 + (Qn)*16384 + nl*2048 + sw1); \
    } } while (0)

// window: stage; MFMA on current regs (compiler-counted lgkm waits);
// (vmcnt); next window's reads; single barrier. sched_barrier(0) fences pin
// the vmcnt <-> read ordering (reads of freshly-staged regions must not hoist
// above the counted vmcnt).
#define WINDOW(Qm, Qn, STAGE_STMT, VM_STMT, NEXT_LOADS) do {                    \
    STAGE_STMT;                                                                 \
    __builtin_amdgcn_sched_barrier(0);                                          \
    __builtin_amdgcn_s_setprio(1);                                              \
    _Pragma("unroll")                                                           \
    for (int ml = 0; ml < 2; ++ml)                                              \
        _Pragma("unroll")                                                       \
        for (int nl = 0; nl < 4; ++nl) {                                        \
            acc[Qm][ml][Qn][nl] = __builtin_amdgcn_mfma_f32_16x16x32_bf16(      \
                av[ml][0], bv[nl][0], acc[Qm][ml][Qn][nl], 0, 0, 0);            \
            acc[Qm][ml][Qn][nl] = __builtin_amdgcn_mfma_f32_16x16x32_bf16(      \
                av[ml][1], bv[nl][1], acc[Qm][ml][Qn][nl], 0, 0, 0);            \
        }                                                                       \
    __builtin_amdgcn_s_setprio(0);                                              \
    VM_STMT;                                                                    \
    __builtin_amdgcn_sched_barrier(0);                                          \
    NEXT_LOADS;                                                                 \
    __builtin_amdgcn_sched_barrier(0);                                          \
    __builtin_amdgcn_s_barrier();                                               \
} while (0)

    const int nkt = K >> 6;           // 64-wide K-tiles (even for all layers)
    // prologue: buf0 = tile0 full; buf1 h0 = tile1 {A,B}; then first reads
    STA(0, 0, 0); STA(0, 1, 0); STB(0, 0, 0); STB(0, 1, 0);
    STA(1, 0, 1); STB(1, 0, 1);
    asm volatile("s_waitcnt vmcnt(4)" ::: "memory");   // buf0's 8 loads landed
    __builtin_amdgcn_s_barrier();
    LA(0, 1); LB(0, 0);                                // regs for window 1

    const int niter = nkt >> 1;
    for (int it = 0; it < niter; ++it) {
        const int t1 = 2 * it + 1;
        const int t2 = (2 * it + 2 < nkt) ? 2 * it + 2 : nkt - 1;  // clamped: dead stages
        const int t3 = (2 * it + 3 < nkt) ? 2 * it + 3 : nkt - 1;
        WINDOW(1, 0, STA(1, 1, t1), ((void)0), LA(0, 0));
        WINDOW(0, 0, STB(1, 1, t1), ((void)0), LB(0, 1));
        WINDOW(0, 1, STA(0, 0, t2), ((void)0), LA(0, 1));
        WINDOW(1, 1, STB(0, 0, t2),
               asm volatile("s_waitcnt vmcnt(4)" ::: "memory"), LA(1, 1); LB(1, 0));
        WINDOW(1, 0, STA(0, 1, t2), ((void)0), LA(1, 0));
        WINDOW(0, 0, STB(0, 1, t2), ((void)0), LB(1, 1));
        WINDOW(0, 1, STA(1, 0, t3), ((void)0), LA(1, 1));
        WINDOW(1, 1, STB(1, 0, t3),
               asm volatile("s_waitcnt vmcnt(4)" ::: "memory"), LA(0, 1); LB(0, 0));
    }
    asm volatile("s_waitcnt vmcnt(0)" ::: "memory");   // drain tail stages

    // epilogue. C/D (m89-verified): col = lane&15 (B side), row = (lane>>4)*4+jj
    const int rl = (lane >> 4) << 2;
    float bsv[2][4];
    #pragma unroll
    for (int Qn = 0; Qn < 2; ++Qn)
        #pragma unroll
        for (int nl = 0; nl < 4; ++nl)
            bsv[Qn][nl] = biasp[bn + Qn * 128 + wn1 * 64 + nl * 16 + l15];

    if constexpr (!OUT32) {
        unsigned short* Hp = Hb + (size_t)e * plane;
        #pragma unroll
        for (int Qm = 0; Qm < 2; ++Qm)
        #pragma unroll
        for (int ml = 0; ml < 2; ++ml)
        #pragma unroll
        for (int jj = 0; jj < 4; ++jj) {
            int srow = bm + Qm * 128 + wl3 * 32 + ml * 16 + rl + jj;
            size_t ro = (size_t)srow * N;
            #pragma unroll
            for (int Qn = 0; Qn < 2; ++Qn)
            #pragma unroll
            for (int nl = 0; nl < 4; ++nl) {
                int col = bn + Qn * 128 + wn1 * 64 + nl * 16 + l15;
                float v = acc[Qm][ml][Qn][nl][jj] + bsv[Qn][nl];
                if (ACT) v = v > 0.f ? v : 0.2f * v;
                Hp[ro + col] = f2bf(v);
            }
        }
    } else {
        float* Yp = Yb + (size_t)e * plane;
        #pragma unroll
        for (int Qm = 0; Qm < 2; ++Qm)
        #pragma unroll
        for (int ml = 0; ml < 2; ++ml)
        #pragma unroll
        for (int jj = 0; jj < 4; ++jj) {
            int srow = bm + Qm * 128 + wl3 * 32 + ml * 16 + rl + jj;
            size_t ro = (size_t)srow * N;
            #pragma unroll
            for (int Qn = 0; Qn < 2; ++Qn)
            #pragma unroll
            for (int nl = 0; nl < 4; ++nl) {
                int col = bn + Qn * 128 + wn1 * 64 + nl * 16 + l15;
                Yp[ro + col] = acc[Qm][ml][Qn][nl][jj] + bsv[Qn][nl];
            }
        }
    }
#undef WINDOW
#undef LA
#undef LB
#undef STA
#undef STB
}

// ---------------- host launch ----------------

extern "C" void kernel_launch(void* const* d_in, const int* in_sizes, int n_in,
                              void* d_out, int out_size, void* d_ws, size_t ws_size,
                              hipStream_t stream)
{
    const float* x     = (const float*)d_in[0];
    // d_in[1] = gate (unused by reference forward)
    const float* probs = (const float*)d_in[2];
    const int*   tidx  = (const int*)d_in[3];
    const float* W1    = (const float*)d_in[4];
    const float* b1    = (const float*)d_in[5];
    const float* W2    = (const float*)d_in[6];
    const float* b2    = (const float*)d_in[7];
    const float* W3    = (const float*)d_in[8];
    const float* b3    = (const float*)d_in[9];
    float* out = (float*)d_out;

    // workspace layout (bytes); total ~439 MB of the 512 MiB d_ws
    char* ws = (char*)d_ws;
    const size_t xb_off  = 0;
    const size_t w1t_off = xb_off  + (size_t)B_TOK * IN_DIM * 2;
    const size_t w2t_off = w1t_off + (size_t)NEXP * IN_DIM * H1_DIM * 2;
    const size_t w3t_off = w2t_off + (size_t)NEXP * H1_DIM * H2_DIM * 2;
    const size_t h1_off  = w3t_off + (size_t)NEXP * H2_DIM * D_DIM * 2;
    const size_t h2_off  = h1_off  + (size_t)NEXP * B_TOK * H1_DIM * 2;
    const size_t y_off   = h2_off  + (size_t)NEXP * B_TOK * H2_DIM * 2;
    const size_t li_off  = y_off   + (size_t)NEXP * B_TOK * D_DIM * 4;
    const size_t iv_off  = li_off  + (size_t)NEXP * B_TOK * 4;
    const size_t cn_off  = iv_off  + (size_t)NEXP * B_TOK * 4;
    const size_t cp_off  = cn_off  + 256;

    unsigned short* xb  = (unsigned short*)(ws + xb_off);
    unsigned short* W1t = (unsigned short*)(ws + w1t_off);
    unsigned short* W2t = (unsigned short*)(ws + w2t_off);
    unsigned short* W3t = (unsigned short*)(ws + w3t_off);
    unsigned short* h1  = (unsigned short*)(ws + h1_off);
    unsigned short* h2  = (unsigned short*)(ws + h2_off);
    float*          y   = (float*)(ws + y_off);
    int*            lst = (int*)(ws + li_off);
    int*            inv = (int*)(ws + iv_off);
    int*            cnt = (int*)(ws + cn_off);
    int*            cnp = (int*)(ws + cp_off);

    hipMemsetAsync(cnt, 0, 256, stream);

    convert_f32_bf16<<<2048, 256, 0, stream>>>(x, xb, (size_t)B_TOK * IN_DIM);
    transpose_convert<<<dim3(H1_DIM / 64, IN_DIM / 64, NEXP), 256, 0, stream>>>(W1, W1t, IN_DIM, H1_DIM);
    transpose_convert<<<dim3(H2_DIM / 64, H1_DIM / 64, NEXP), 256, 0, stream>>>(W2, W2t, H1_DIM, H2_DIM);
    transpose_convert<<<dim3(D_DIM / 64, H2_DIM / 64, NEXP), 256, 0, stream>>>(W3, W3t, H2_DIM, D_DIM);
    route_tokens<<<B_TOK / 256, 256, 0, stream>>>(probs, tidx, cnt, lst, inv);
    finalize_counts<<<NEXP, 256, 0, stream>>>(cnt, cnp, lst);

    const size_t h1pl = (size_t)B_TOK * H1_DIM;
    const size_t h2pl = (size_t)B_TOK * H2_DIM;
    const size_t ypl  = (size_t)B_TOK * D_DIM;

    // L1 grouped across experts: gathered x rows -> h1 planes (bf16)
    gemm8<1, 0, 1><<<dim3(NEXP * 64 * 4), 512, 0, stream>>>(
        xb, 0, W1t, b1, h1, nullptr, h1pl,
        lst, cnp, H1_DIM, IN_DIM, 4, 0);
    // L2 grouped: h1 planes -> h2 planes (bf16)
    gemm8<1, 0, 0><<<dim3(NEXP * 64 * 2), 512, 0, stream>>>(
        h1, h1pl, W2t, b2, h2, nullptr, h2pl,
        lst, cnp, H2_DIM, H1_DIM, 2, 0);
    // L3 grouped: h2 planes -> compact y planes (f32, bias applied, no weight)
    gemm8<0, 1, 0><<<dim3(NEXP * 64 * 4), 512, 0, stream>>>(
        h2, h2pl, W3t, b3, nullptr, y, ypl,
        lst, cnp, D_DIM, H2_DIM, 4, 0);
    // combine: out[tok] = p0*y[i0][slot0] + p1*y[i1][slot1]
    combine_out<<<dim3(B_TOK * 128 / 256), 256, 0, stream>>>(
        probs, tidx, inv, y, ypl, out);
}

// Round 7
// 286.380 us; speedup vs baseline: 1.8636x; 1.0568x over previous
//
#include <hip/hip_runtime.h>
#include <cstdint>
#include <cstddef>

// Problem constants (match reference setup_inputs)
#define B_TOK   16384
#define IN_DIM  2048
#define D_DIM   1024
#define NEXP    3
#define TOPK    2
#define H1_DIM  1024
#define H2_DIM  512

typedef __bf16 bf16x8 __attribute__((ext_vector_type(8)));
typedef float  f32x4  __attribute__((ext_vector_type(4)));
typedef unsigned short ushort8_t __attribute__((ext_vector_type(8)));

__device__ __forceinline__ unsigned short f2bf(float f) {
    unsigned int u = __builtin_bit_cast(unsigned int, f);
    return (unsigned short)((u + 0x7fffu + ((u >> 16) & 1u)) >> 16);
}
__device__ __forceinline__ float bf2f(unsigned short v) {
    return __builtin_bit_cast(float, (unsigned int)v << 16);
}

// async global->LDS, 16B per lane. LDS dest is wave-uniform base + lane*16;
// global source address IS per-lane (enables gather + inverse-swizzle).
__device__ __forceinline__ void glds16(const void* gsrc, void* ldst) {
    __builtin_amdgcn_global_load_lds(
        (__attribute__((address_space(1))) void*)(gsrc),
        (__attribute__((address_space(3))) void*)(ldst),
        16, 0, 0);
}

// ---------------- prepass kernels ----------------

__global__ __launch_bounds__(256) void convert_f32_bf16(
    const float* __restrict__ in, unsigned short* __restrict__ out, size_t n)
{
    size_t i = ((size_t)blockIdx.x * blockDim.x + threadIdx.x) * 8;
    size_t stride = (size_t)gridDim.x * blockDim.x * 8;
    for (; i < n; i += stride) {
        float4 a = *(const float4*)(in + i);
        float4 b = *(const float4*)(in + i + 4);
        ushort8_t o;
        o[0] = f2bf(a.x); o[1] = f2bf(a.y); o[2] = f2bf(a.z); o[3] = f2bf(a.w);
        o[4] = f2bf(b.x); o[5] = f2bf(b.y); o[6] = f2bf(b.z); o[7] = f2bf(b.w);
        *(ushort8_t*)(out + i) = o;
    }
}

// W [E][K][N] f32 -> Wt [E][N][K] bf16, 64x64 tiles through LDS
__global__ __launch_bounds__(256) void transpose_convert(
    const float* __restrict__ W, unsigned short* __restrict__ Wt, int K, int N)
{
    __shared__ unsigned short tile[64][68];
    int e = blockIdx.z;
    const float* Wp = W + (size_t)e * K * N;
    unsigned short* Wtp = Wt + (size_t)e * N * K;
    int n0 = blockIdx.x * 64, k0 = blockIdx.y * 64;
    int t = threadIdx.x;
    int nn = (t & 15) * 4;
    int kk = t >> 4;
    #pragma unroll
    for (int r = 0; r < 4; ++r) {
        int k = kk + r * 16;
        float4 v = *(const float4*)(Wp + (size_t)(k0 + k) * N + (n0 + nn));
        tile[k][nn + 0] = f2bf(v.x);
        tile[k][nn + 1] = f2bf(v.y);
        tile[k][nn + 2] = f2bf(v.z);
        tile[k][nn + 3] = f2bf(v.w);
    }
    __syncthreads();
    int n  = t >> 2;
    int kb = (t & 3) * 16;
    ushort8_t o0, o1;
    #pragma unroll
    for (int i = 0; i < 8; ++i) o0[i] = tile[kb + i][n];
    #pragma unroll
    for (int i = 0; i < 8; ++i) o1[i] = tile[kb + 8 + i][n];
    unsigned short* dst = Wtp + (size_t)(n0 + n) * K + (k0 + kb);
    *(ushort8_t*)dst = o0;
    *(ushort8_t*)(dst + 8) = o1;
}

// Two-phase token routing. Also writes inv[e][tok] = compact slot of tok in
// expert e's list (used by the combine pass). Slot order is nondeterministic
// across replays, but every per-token output value is slot-independent, so
// d_out stays deterministic.
__global__ __launch_bounds__(256) void route_tokens(
    const float* __restrict__ probs, const int* __restrict__ idx,
    int* __restrict__ cnt, int* __restrict__ list, int* __restrict__ inv)
{
    __shared__ int lcnt[NEXP];
    __shared__ int lbase[NEXP];
    __shared__ int ltok[NEXP][256];
    int t = threadIdx.x;
    int b = blockIdx.x * 256 + t;
    if (t < NEXP) lcnt[t] = 0;
    __syncthreads();
    int i0 = idx[b * TOPK + 0], i1 = idx[b * TOPK + 1];
    #pragma unroll
    for (int e = 0; e < NEXP; ++e) {
        if (i0 == e || i1 == e) {
            int s = atomicAdd(&lcnt[e], 1);
            ltok[e][s] = b;
        }
    }
    __syncthreads();
    if (t < NEXP) lbase[t] = atomicAdd(&cnt[t], lcnt[t]);
    __syncthreads();
    #pragma unroll
    for (int e = 0; e < NEXP; ++e) {
        int n = lcnt[e], base = lbase[e];
        for (int s = t; s < n; s += 256) {
            int tk = ltok[e][s];
            list[e * B_TOK + base + s] = tk;
            inv[e * B_TOK + tk] = base + s;
        }
    }
}

// round counts up to 256-tile multiple; pad list with token 0
__global__ void finalize_counts(const int* __restrict__ cnt, int* __restrict__ cntp,
                                int* __restrict__ list)
{
    int e = blockIdx.x;
    int c = cnt[e];
    int cp = (c + 255) & ~255;
    if (threadIdx.x == 0) cntp[e] = cp;
    for (int s = c + threadIdx.x; s < cp; s += blockDim.x)
        list[e * B_TOK + s] = 0;
}

// combine: out[tok] = p0 * y[i0][inv[i0][tok]] + p1 * y[i1][inv[i1][tok]]
// y planes are bf16. Handles i0==i1 naturally. Writes EVERY output element.
__global__ __launch_bounds__(256) void combine_out(
    const float* __restrict__ probs, const int* __restrict__ tidx,
    const int* __restrict__ inv, const unsigned short* __restrict__ y, size_t ypl,
    float* __restrict__ out)
{
    int gid = blockIdx.x * 256 + threadIdx.x;
    int tok = gid >> 7;              // 128 threads per token
    int dc  = (gid & 127) << 3;      // 8 cols per thread
    float p0 = probs[tok * TOPK + 0], p1 = probs[tok * TOPK + 1];
    int   i0 = tidx [tok * TOPK + 0], i1 = tidx [tok * TOPK + 1];
    size_t r0 = (size_t)i0 * ypl + (size_t)inv[(size_t)i0 * B_TOK + tok] * D_DIM + dc;
    size_t r1 = (size_t)i1 * ypl + (size_t)inv[(size_t)i1 * B_TOK + tok] * D_DIM + dc;
    ushort8_t a = *(const ushort8_t*)(y + r0);
    ushort8_t b = *(const ushort8_t*)(y + r1);
    float4 o0, o1;
    o0.x = p0 * bf2f(a[0]) + p1 * bf2f(b[0]);
    o0.y = p0 * bf2f(a[1]) + p1 * bf2f(b[1]);
    o0.z = p0 * bf2f(a[2]) + p1 * bf2f(b[2]);
    o0.w = p0 * bf2f(a[3]) + p1 * bf2f(b[3]);
    o1.x = p0 * bf2f(a[4]) + p1 * bf2f(b[4]);
    o1.y = p0 * bf2f(a[5]) + p1 * bf2f(b[5]);
    o1.z = p0 * bf2f(a[6]) + p1 * bf2f(b[6]);
    o1.w = p0 * bf2f(a[7]) + p1 * bf2f(b[7]);
    float* op = out + (size_t)tok * D_DIM + dc;
    *(float4*)op = o0;
    *(float4*)(op + 4) = o1;
}

// ---------------- 8-phase 256x256 GEMM, pipelined windows ----------------
// C = act(A[slots,K] @ Bt[N,K]^T + bias) -> bf16 planes.
// BM=BN=256, BK=64, 8 waves (512 thr), LDS 128KiB = 2dbuf x {A,B} x 2half x
// [128][64] bf16. Round-6 post-mortem: the sched_barrier(0) between the MFMA
// cluster and the next window's ds_reads FORBADE interleave -> serial
// {MFMA burst}{read burst} -> 42% MfmaUtil. This version leaves the reads
// unfenced inside the setprio region so the compiler interleaves ds_read
// issue among the 16 independent MFMA chains (AITER-style), with counted
// per-use lgkm waits. Ordering still pinned where it matters:
//  - vmcnt(4) asm ("memory" clobber) precedes the MFMA+reads in the 2 windows
//    whose reads touch freshly staged regions (compiler can't hoist mem ops
//    above it);
//  - sched_barrier(0)+s_barrier at window end stops cross-window motion.
// WAR ledger: >=3 barriers between any read-issue and that region's re-stage.
// RAW: vmcnt(4)@ph4 covers prologue tail + ph1 (regions read @ph4);
//      vmcnt(4)@ph8 covers ph3..ph6 (regions read @ph8/ph1'..ph3').
template<int ACT, int GATHER>
__global__ __launch_bounds__(512, 2) void gemm8(
    const unsigned short* __restrict__ Ab, size_t Aplane,  // bf16 [slots][K] (per-expert plane if !GATHER)
    const unsigned short* __restrict__ Bb,                 // bf16 [E][N][K]
    const float* __restrict__ biasb,                       // [E][N]
    unsigned short* __restrict__ Hb,                       // bf16 planes out
    size_t plane,                                          // elements per plane
    const int* __restrict__ listb,                         // [E][B_TOK]
    const int* __restrict__ cntp,                          // [E] padded count
    int N, int K, int NT, int e0)
{
    // bijective tile->XCD mapping: xcd=bid&7; XCD x walks A-tiles {x,x+8,...}
    // with the NT N-blocks of each A-tile consecutive (L2 A-reuse); live
    // tiles (early-exit) spread evenly across XCDs.
    const int bid  = blockIdx.x;
    const int xcd  = bid & 7;
    const int slot = bid >> 3;
    const int q    = slot / NT;
    const int nt   = slot % NT;
    const int ti   = q * 8 + xcd;
    const int e    = e0 + (ti >> 6);
    const int mt   = ti & 63;
    const int bm   = mt << 8;
    if (bm >= cntp[e]) return;
    const int bn   = nt << 8;

    __shared__ char smem[131072];   // A: [0,64K)  B: [64K,128K)

    const int tid  = threadIdx.x;
    const int lane = tid & 63;
    const int w    = tid >> 6;      // wave 0..7
    const int wl3  = w & 3;         // A 32-row band within half
    const int wn1  = w >> 2;        // B 64-col band within half
    const int l15  = lane & 15;
    const int ug8  = (((tid & 7) ^ ((tid >> 3) & 7)) << 3);          // src swz (shorts)
    const int sw0  = ((((lane >> 4) + 0) ^ (lane & 7)) << 4);        // read swz k0 (bytes)
    const int sw1  = ((((lane >> 4) + 4) ^ (lane & 7)) << 4);        // read swz k1 (bytes)

    const int* listp = listb + (size_t)e * B_TOK;
    const unsigned short* Ae = Ab + (size_t)e * Aplane;
    const unsigned short* Be = Bb + (size_t)e * ((size_t)N * K);
    const float* biasp = biasb + (size_t)e * N;

    // per-thread stage source pointers: half h, load j covers tile row
    // h*128 + j*64 + (tid>>3); 16B unit = (tid&7) ^ ((tid>>3)&7)  (inverse swz)
    const unsigned short* sA[2][2];
    const unsigned short* sB[2][2];
    #pragma unroll
    for (int h = 0; h < 2; ++h)
        #pragma unroll
        for (int j = 0; j < 2; ++j) {
            int lrow = h * 128 + j * 64 + (tid >> 3);
            int arow;
            if constexpr (GATHER) arow = listp[bm + lrow];
            else                  arow = bm + lrow;
            sA[h][j] = Ae + (size_t)arow * K + ug8;
            sB[h][j] = Be + (size_t)(bn + lrow) * K + ug8;
        }

    char* const stA = smem + (w << 10);            // + db*32768 + h*16384 (+8192 for j=1)
    char* const stB = smem + 65536 + (w << 10);
    const char* const rA = smem + (wl3 * 32 + l15) * 128;           // + db*32768 + Qm*16384 + ml*2048 + sw
    const char* const rB = smem + 65536 + (wn1 * 64 + l15) * 128;   // + db*32768 + Qn*16384 + nl*2048 + sw

    f32x4 acc[2][2][2][4] = {};   // [Qm][ml][Qn][nl]
    bf16x8 av[2][2];              // A operand regs (current quadrant)
    bf16x8 bv[4][2];              // B operand regs (current quadrant)

#define STA(db, h, kt) do {                                                     \
    glds16(sA[h][0] + (size_t)(kt) * 64, stA + (db) * 32768 + (h) * 16384);     \
    glds16(sA[h][1] + (size_t)(kt) * 64, stA + (db) * 32768 + (h) * 16384 + 8192); } while (0)
#define STB(db, h, kt) do {                                                     \
    glds16(sB[h][0] + (size_t)(kt) * 64, stB + (db) * 32768 + (h) * 16384);     \
    glds16(sB[h][1] + (size_t)(kt) * 64, stB + (db) * 32768 + (h) * 16384 + 8192); } while (0)

#define LA(db, Qm) do {                                                         \
    _Pragma("unroll")                                                           \
    for (int ml = 0; ml < 2; ++ml) {                                            \
        av[ml][0] = *(const bf16x8*)(rA + (db)*32768 + (Qm)*16384 + ml*2048 + sw0); \
        av[ml][1] = *(const bf16x8*)(rA + (db)*32768 + (Qm)*16384 + ml*2048 + sw1); \
    } } while (0)
#define LB(db, Qn) do {                                                         \
    _Pragma("unroll")                                                           \
    for (int nl = 0; nl < 4; ++nl) {                                            \
        bv[nl][0] = *(const bf16x8*)(rB + (db)*32768 + (Qn)*16384 + nl*2048 + sw0); \
        bv[nl][1] = *(const bf16x8*)(rB + (db)*32768 + (Qn)*16384 + nl*2048 + sw1); \
    } } while (0)

// window: stage; [counted vmcnt]; MFMA on current regs with next window's
// reads free to interleave; fence; barrier.
#define WINDOW(Qm, Qn, STAGE_STMT, VM_STMT, NEXT_LOADS) do {                    \
    STAGE_STMT;                                                                 \
    VM_STMT;                                                                    \
    __builtin_amdgcn_s_setprio(1);                                              \
    _Pragma("unroll")                                                           \
    for (int ml = 0; ml < 2; ++ml)                                              \
        _Pragma("unroll")                                                       \
        for (int nl = 0; nl < 4; ++nl) {                                        \
            acc[Qm][ml][Qn][nl] = __builtin_amdgcn_mfma_f32_16x16x32_bf16(      \
                av[ml][0], bv[nl][0], acc[Qm][ml][Qn][nl], 0, 0, 0);            \
            acc[Qm][ml][Qn][nl] = __builtin_amdgcn_mfma_f32_16x16x32_bf16(      \
                av[ml][1], bv[nl][1], acc[Qm][ml][Qn][nl], 0, 0, 0);            \
        }                                                                       \
    NEXT_LOADS;                                                                 \
    __builtin_amdgcn_s_setprio(0);                                              \
    __builtin_amdgcn_sched_barrier(0);                                          \
    __builtin_amdgcn_s_barrier();                                               \
} while (0)

    const int nkt = K >> 6;           // 64-wide K-tiles (even for all layers)
    // prologue: buf0 = tile0 full; buf1 h0 = tile1 {A,B}; then first reads
    STA(0, 0, 0); STA(0, 1, 0); STB(0, 0, 0); STB(0, 1, 0);
    STA(1, 0, 1); STB(1, 0, 1);
    asm volatile("s_waitcnt vmcnt(4)" ::: "memory");   // buf0's 8 loads landed
    __builtin_amdgcn_s_barrier();
    LA(0, 1); LB(0, 0);                                // regs for window 1

    const int niter = nkt >> 1;
    for (int it = 0; it < niter; ++it) {
        const int t1 = 2 * it + 1;
        const int t2 = (2 * it + 2 < nkt) ? 2 * it + 2 : nkt - 1;  // clamped: dead stages
        const int t3 = (2 * it + 3 < nkt) ? 2 * it + 3 : nkt - 1;
        WINDOW(1, 0, STA(1, 1, t1), ((void)0), LA(0, 0));
        WINDOW(0, 0, STB(1, 1, t1), ((void)0), LB(0, 1));
        WINDOW(0, 1, STA(0, 0, t2), ((void)0), LA(0, 1));
        WINDOW(1, 1, STB(0, 0, t2),
               asm volatile("s_waitcnt vmcnt(4)" ::: "memory"), LA(1, 1); LB(1, 0));
        WINDOW(1, 0, STA(0, 1, t2), ((void)0), LA(1, 0));
        WINDOW(0, 0, STB(0, 1, t2), ((void)0), LB(1, 1));
        WINDOW(0, 1, STA(1, 0, t3), ((void)0), LA(1, 1));
        WINDOW(1, 1, STB(1, 0, t3),
               asm volatile("s_waitcnt vmcnt(4)" ::: "memory"), LA(0, 1); LB(0, 0));
    }
    asm volatile("s_waitcnt vmcnt(0)" ::: "memory");   // drain tail stages

    // epilogue. C/D (m89-verified): col = lane&15 (B side), row = (lane>>4)*4+jj
    const int rl = (lane >> 4) << 2;
    float bsv[2][4];
    #pragma unroll
    for (int Qn = 0; Qn < 2; ++Qn)
        #pragma unroll
        for (int nl = 0; nl < 4; ++nl)
            bsv[Qn][nl] = biasp[bn + Qn * 128 + wn1 * 64 + nl * 16 + l15];

    unsigned short* Hp = Hb + (size_t)e * plane;
    #pragma unroll
    for (int Qm = 0; Qm < 2; ++Qm)
    #pragma unroll
    for (int ml = 0; ml < 2; ++ml)
    #pragma unroll
    for (int jj = 0; jj < 4; ++jj) {
        int srow = bm + Qm * 128 + wl3 * 32 + ml * 16 + rl + jj;
        size_t ro = (size_t)srow * N;
        #pragma unroll
        for (int Qn = 0; Qn < 2; ++Qn)
        #pragma unroll
        for (int nl = 0; nl < 4; ++nl) {
            int col = bn + Qn * 128 + wn1 * 64 + nl * 16 + l15;
            float v = acc[Qm][ml][Qn][nl][jj] + bsv[Qn][nl];
            if (ACT) v = v > 0.f ? v : 0.2f * v;
            Hp[ro + col] = f2bf(v);
        }
    }
#undef WINDOW
#undef LA
#undef LB
#undef STA
#undef STB
}

// ---------------- host launch ----------------

extern "C" void kernel_launch(void* const* d_in, const int* in_sizes, int n_in,
                              void* d_out, int out_size, void* d_ws, size_t ws_size,
                              hipStream_t stream)
{
    const float* x     = (const float*)d_in[0];
    // d_in[1] = gate (unused by reference forward)
    const float* probs = (const float*)d_in[2];
    const int*   tidx  = (const int*)d_in[3];
    const float* W1    = (const float*)d_in[4];
    const float* b1    = (const float*)d_in[5];
    const float* W2    = (const float*)d_in[6];
    const float* b2    = (const float*)d_in[7];
    const float* W3    = (const float*)d_in[8];
    const float* b3    = (const float*)d_in[9];
    float* out = (float*)d_out;

    // workspace layout (bytes); total ~340 MB of the 512 MiB d_ws
    char* ws = (char*)d_ws;
    const size_t xb_off  = 0;
    const size_t w1t_off = xb_off  + (size_t)B_TOK * IN_DIM * 2;
    const size_t w2t_off = w1t_off + (size_t)NEXP * IN_DIM * H1_DIM * 2;
    const size_t w3t_off = w2t_off + (size_t)NEXP * H1_DIM * H2_DIM * 2;
    const size_t h1_off  = w3t_off + (size_t)NEXP * H2_DIM * D_DIM * 2;
    const size_t h2_off  = h1_off  + (size_t)NEXP * B_TOK * H1_DIM * 2;
    const size_t y_off   = h2_off  + (size_t)NEXP * B_TOK * H2_DIM * 2;
    const size_t li_off  = y_off   + (size_t)NEXP * B_TOK * D_DIM * 2;   // y bf16
    const size_t iv_off  = li_off  + (size_t)NEXP * B_TOK * 4;
    const size_t cn_off  = iv_off  + (size_t)NEXP * B_TOK * 4;
    const size_t cp_off  = cn_off  + 256;

    unsigned short* xb  = (unsigned short*)(ws + xb_off);
    unsigned short* W1t = (unsigned short*)(ws + w1t_off);
    unsigned short* W2t = (unsigned short*)(ws + w2t_off);
    unsigned short* W3t = (unsigned short*)(ws + w3t_off);
    unsigned short* h1  = (unsigned short*)(ws + h1_off);
    unsigned short* h2  = (unsigned short*)(ws + h2_off);
    unsigned short* y   = (unsigned short*)(ws + y_off);
    int*            lst = (int*)(ws + li_off);
    int*            inv = (int*)(ws + iv_off);
    int*            cnt = (int*)(ws + cn_off);
    int*            cnp = (int*)(ws + cp_off);

    hipMemsetAsync(cnt, 0, 256, stream);

    convert_f32_bf16<<<2048, 256, 0, stream>>>(x, xb, (size_t)B_TOK * IN_DIM);
    transpose_convert<<<dim3(H1_DIM / 64, IN_DIM / 64, NEXP), 256, 0, stream>>>(W1, W1t, IN_DIM, H1_DIM);
    transpose_convert<<<dim3(H2_DIM / 64, H1_DIM / 64, NEXP), 256, 0, stream>>>(W2, W2t, H1_DIM, H2_DIM);
    transpose_convert<<<dim3(D_DIM / 64, H2_DIM / 64, NEXP), 256, 0, stream>>>(W3, W3t, H2_DIM, D_DIM);
    route_tokens<<<B_TOK / 256, 256, 0, stream>>>(probs, tidx, cnt, lst, inv);
    finalize_counts<<<NEXP, 256, 0, stream>>>(cnt, cnp, lst);

    const size_t h1pl = (size_t)B_TOK * H1_DIM;
    const size_t h2pl = (size_t)B_TOK * H2_DIM;
    const size_t ypl  = (size_t)B_TOK * D_DIM;

    // L1 grouped across experts: gathered x rows -> h1 planes (bf16)
    gemm8<1, 1><<<dim3(NEXP * 64 * 4), 512, 0, stream>>>(
        xb, 0, W1t, b1, h1, h1pl,
        lst, cnp, H1_DIM, IN_DIM, 4, 0);
    // L2 grouped: h1 planes -> h2 planes (bf16)
    gemm8<1, 0><<<dim3(NEXP * 64 * 2), 512, 0, stream>>>(
        h1, h1pl, W2t, b2, h2, h2pl,
        lst, cnp, H2_DIM, H1_DIM, 2, 0);
    // L3 grouped: h2 planes -> compact y planes (bf16, bias applied, no weight)
    gemm8<0, 0><<<dim3(NEXP * 64 * 4), 512, 0, stream>>>(
        h2, h2pl, W3t, b3, y, ypl,
        lst, cnp, D_DIM, H2_DIM, 4, 0);
    // combine: out[tok] = p0*y[i0][slot0] + p1*y[i1][slot1]
    combine_out<<<dim3(B_TOK * 128 / 256), 256, 0, stream>>>(
        probs, tidx, inv, y, ypl, out);
}

// Round 8
// 286.110 us; speedup vs baseline: 1.8653x; 1.0009x over previous
//
#include <hip/hip_runtime.h>
#include <cstdint>
#include <cstddef>

// Problem constants (match reference setup_inputs)
#define B_TOK   16384
#define IN_DIM  2048
#define D_DIM   1024
#define NEXP    3
#define TOPK    2
#define H1_DIM  1024
#define H2_DIM  512

typedef __bf16 bf16x8 __attribute__((ext_vector_type(8)));
typedef float  f32x4  __attribute__((ext_vector_type(4)));
typedef unsigned short ushort8_t __attribute__((ext_vector_type(8)));

__device__ __forceinline__ unsigned short f2bf(float f) {
    unsigned int u = __builtin_bit_cast(unsigned int, f);
    return (unsigned short)((u + 0x7fffu + ((u >> 16) & 1u)) >> 16);
}
__device__ __forceinline__ float bf2f(unsigned short v) {
    return __builtin_bit_cast(float, (unsigned int)v << 16);
}

// async global->LDS, 16B per lane. LDS dest is wave-uniform base + lane*16;
// global source address IS per-lane (enables gather + inverse-swizzle).
__device__ __forceinline__ void glds16(const void* gsrc, void* ldst) {
    __builtin_amdgcn_global_load_lds(
        (__attribute__((address_space(1))) void*)(gsrc),
        (__attribute__((address_space(3))) void*)(ldst),
        16, 0, 0);
}

// ---------------- prepass kernels ----------------

__global__ __launch_bounds__(256) void convert_f32_bf16(
    const float* __restrict__ in, unsigned short* __restrict__ out, size_t n)
{
    size_t i = ((size_t)blockIdx.x * blockDim.x + threadIdx.x) * 8;
    size_t stride = (size_t)gridDim.x * blockDim.x * 8;
    for (; i < n; i += stride) {
        float4 a = *(const float4*)(in + i);
        float4 b = *(const float4*)(in + i + 4);
        ushort8_t o;
        o[0] = f2bf(a.x); o[1] = f2bf(a.y); o[2] = f2bf(a.z); o[3] = f2bf(a.w);
        o[4] = f2bf(b.x); o[5] = f2bf(b.y); o[6] = f2bf(b.z); o[7] = f2bf(b.w);
        *(ushort8_t*)(out + i) = o;
    }
}

// W [E][K][N] f32 -> Wt [E][N][K] bf16, 64x64 tiles through LDS
__global__ __launch_bounds__(256) void transpose_convert(
    const float* __restrict__ W, unsigned short* __restrict__ Wt, int K, int N)
{
    __shared__ unsigned short tile[64][68];
    int e = blockIdx.z;
    const float* Wp = W + (size_t)e * K * N;
    unsigned short* Wtp = Wt + (size_t)e * N * K;
    int n0 = blockIdx.x * 64, k0 = blockIdx.y * 64;
    int t = threadIdx.x;
    int nn = (t & 15) * 4;
    int kk = t >> 4;
    #pragma unroll
    for (int r = 0; r < 4; ++r) {
        int k = kk + r * 16;
        float4 v = *(const float4*)(Wp + (size_t)(k0 + k) * N + (n0 + nn));
        tile[k][nn + 0] = f2bf(v.x);
        tile[k][nn + 1] = f2bf(v.y);
        tile[k][nn + 2] = f2bf(v.z);
        tile[k][nn + 3] = f2bf(v.w);
    }
    __syncthreads();
    int n  = t >> 2;
    int kb = (t & 3) * 16;
    ushort8_t o0, o1;
    #pragma unroll
    for (int i = 0; i < 8; ++i) o0[i] = tile[kb + i][n];
    #pragma unroll
    for (int i = 0; i < 8; ++i) o1[i] = tile[kb + 8 + i][n];
    unsigned short* dst = Wtp + (size_t)(n0 + n) * K + (k0 + kb);
    *(ushort8_t*)dst = o0;
    *(ushort8_t*)(dst + 8) = o1;
}

// Two-phase token routing. Also writes inv[e][tok] = compact slot of tok in
// expert e's list (used by the combine pass). Slot order is nondeterministic
// across replays, but every per-token output value is slot-independent, so
// d_out stays deterministic.
__global__ __launch_bounds__(256) void route_tokens(
    const float* __restrict__ probs, const int* __restrict__ idx,
    int* __restrict__ cnt, int* __restrict__ list, int* __restrict__ inv)
{
    __shared__ int lcnt[NEXP];
    __shared__ int lbase[NEXP];
    __shared__ int ltok[NEXP][256];
    int t = threadIdx.x;
    int b = blockIdx.x * 256 + t;
    if (t < NEXP) lcnt[t] = 0;
    __syncthreads();
    int i0 = idx[b * TOPK + 0], i1 = idx[b * TOPK + 1];
    #pragma unroll
    for (int e = 0; e < NEXP; ++e) {
        if (i0 == e || i1 == e) {
            int s = atomicAdd(&lcnt[e], 1);
            ltok[e][s] = b;
        }
    }
    __syncthreads();
    if (t < NEXP) lbase[t] = atomicAdd(&cnt[t], lcnt[t]);
    __syncthreads();
    #pragma unroll
    for (int e = 0; e < NEXP; ++e) {
        int n = lcnt[e], base = lbase[e];
        for (int s = t; s < n; s += 256) {
            int tk = ltok[e][s];
            list[e * B_TOK + base + s] = tk;
            inv[e * B_TOK + tk] = base + s;
        }
    }
}

// round counts up to 256-tile multiple; pad list with token 0
__global__ void finalize_counts(const int* __restrict__ cnt, int* __restrict__ cntp,
                                int* __restrict__ list)
{
    int e = blockIdx.x;
    int c = cnt[e];
    int cp = (c + 255) & ~255;
    if (threadIdx.x == 0) cntp[e] = cp;
    for (int s = c + threadIdx.x; s < cp; s += blockDim.x)
        list[e * B_TOK + s] = 0;
}

// combine: out[tok] = p0 * y[i0][inv[i0][tok]] + p1 * y[i1][inv[i1][tok]]
// y planes are bf16. Handles i0==i1 naturally. Writes EVERY output element.
__global__ __launch_bounds__(256) void combine_out(
    const float* __restrict__ probs, const int* __restrict__ tidx,
    const int* __restrict__ inv, const unsigned short* __restrict__ y, size_t ypl,
    float* __restrict__ out)
{
    int gid = blockIdx.x * 256 + threadIdx.x;
    int tok = gid >> 7;              // 128 threads per token
    int dc  = (gid & 127) << 3;      // 8 cols per thread
    float p0 = probs[tok * TOPK + 0], p1 = probs[tok * TOPK + 1];
    int   i0 = tidx [tok * TOPK + 0], i1 = tidx [tok * TOPK + 1];
    size_t r0 = (size_t)i0 * ypl + (size_t)inv[(size_t)i0 * B_TOK + tok] * D_DIM + dc;
    size_t r1 = (size_t)i1 * ypl + (size_t)inv[(size_t)i1 * B_TOK + tok] * D_DIM + dc;
    ushort8_t a = *(const ushort8_t*)(y + r0);
    ushort8_t b = *(const ushort8_t*)(y + r1);
    float4 o0, o1;
    o0.x = p0 * bf2f(a[0]) + p1 * bf2f(b[0]);
    o0.y = p0 * bf2f(a[1]) + p1 * bf2f(b[1]);
    o0.z = p0 * bf2f(a[2]) + p1 * bf2f(b[2]);
    o0.w = p0 * bf2f(a[3]) + p1 * bf2f(b[3]);
    o1.x = p0 * bf2f(a[4]) + p1 * bf2f(b[4]);
    o1.y = p0 * bf2f(a[5]) + p1 * bf2f(b[5]);
    o1.z = p0 * bf2f(a[6]) + p1 * bf2f(b[6]);
    o1.w = p0 * bf2f(a[7]) + p1 * bf2f(b[7]);
    float* op = out + (size_t)tok * D_DIM + dc;
    *(float4*)op = o0;
    *(float4*)(op + 4) = o1;
}

// ---------------- 8-window 256x256 GEMM, k-split interleaved ----------------
// C = act(A[slots,K] @ Bt[N,K]^T + bias) -> bf16 planes.
// BM=BN=256, BK=64, 8 waves (512 thr), LDS 128KiB = 2dbuf x {A,B} x 2half x
// [128][64] bf16. Round-7 post-mortem: next-window ds_reads issued AFTER the
// MFMA cluster -> per-window critical path = LDS latency (~200cy) + MFMA
// (155cy) -> 42% MfmaUtil across 3 variants. This version splits the cluster
// k-major into two 8-MFMA groups and pins the next-window loads BETWEEN them:
//   [8 MFMA k=0][loads k0-slice][8 MFMA k=1][loads k1-slice][barrier]
// Each load gets >=8-MFMA (77cy) + barrier of lead before first use (next
// window also consumes k=0 regs first). WAR safe: each k-slice load overwrites
// exactly the regs the preceding MFMA group just finished reading.
// RAW ledger (identical to r7, re-verified by outstanding-count):
//   vmcnt(4)@W4 drains W7p,W8p,W1,W2; vmcnt(4)@W8 drains W3..W6. Every load's
//   staged region is covered; never drained to 0 in-loop.
template<int ACT, int GATHER>
__global__ __launch_bounds__(512, 2) void gemm8(
    const unsigned short* __restrict__ Ab, size_t Aplane,  // bf16 [slots][K] (per-expert plane if !GATHER)
    const unsigned short* __restrict__ Bb,                 // bf16 [E][N][K]
    const float* __restrict__ biasb,                       // [E][N]
    unsigned short* __restrict__ Hb,                       // bf16 planes out
    size_t plane,                                          // elements per plane
    const int* __restrict__ listb,                         // [E][B_TOK]
    const int* __restrict__ cntp,                          // [E] padded count
    int N, int K, int NT, int e0)
{
    // bijective tile->XCD mapping: xcd=bid&7; XCD x walks A-tiles {x,x+8,...}
    // with the NT N-blocks of each A-tile consecutive (L2 A-reuse); live
    // tiles (early-exit) spread evenly across XCDs.
    const int bid  = blockIdx.x;
    const int xcd  = bid & 7;
    const int slot = bid >> 3;
    const int q    = slot / NT;
    const int nt   = slot % NT;
    const int ti   = q * 8 + xcd;
    const int e    = e0 + (ti >> 6);
    const int mt   = ti & 63;
    const int bm   = mt << 8;
    if (bm >= cntp[e]) return;
    const int bn   = nt << 8;

    __shared__ char smem[131072];   // A: [0,64K)  B: [64K,128K)

    const int tid  = threadIdx.x;
    const int lane = tid & 63;
    const int w    = tid >> 6;      // wave 0..7
    const int wl3  = w & 3;         // A 32-row band within half
    const int wn1  = w >> 2;        // B 64-col band within half
    const int l15  = lane & 15;
    const int ug8  = (((tid & 7) ^ ((tid >> 3) & 7)) << 3);          // src swz (shorts)
    const int sw0  = ((((lane >> 4) + 0) ^ (lane & 7)) << 4);        // read swz k0 (bytes)
    const int sw1  = ((((lane >> 4) + 4) ^ (lane & 7)) << 4);        // read swz k1 (bytes)

    const int* listp = listb + (size_t)e * B_TOK;
    const unsigned short* Ae = Ab + (size_t)e * Aplane;
    const unsigned short* Be = Bb + (size_t)e * ((size_t)N * K);
    const float* biasp = biasb + (size_t)e * N;

    // per-thread stage source pointers: half h, load j covers tile row
    // h*128 + j*64 + (tid>>3); 16B unit = (tid&7) ^ ((tid>>3)&7)  (inverse swz)
    const unsigned short* sA[2][2];
    const unsigned short* sB[2][2];
    #pragma unroll
    for (int h = 0; h < 2; ++h)
        #pragma unroll
        for (int j = 0; j < 2; ++j) {
            int lrow = h * 128 + j * 64 + (tid >> 3);
            int arow;
            if constexpr (GATHER) arow = listp[bm + lrow];
            else                  arow = bm + lrow;
            sA[h][j] = Ae + (size_t)arow * K + ug8;
            sB[h][j] = Be + (size_t)(bn + lrow) * K + ug8;
        }

    char* const stA = smem + (w << 10);            // + db*32768 + h*16384 (+8192 for j=1)
    char* const stB = smem + 65536 + (w << 10);
    const char* const rA = smem + (wl3 * 32 + l15) * 128;           // + db*32768 + Qm*16384 + ml*2048 + sw
    const char* const rB = smem + 65536 + (wn1 * 64 + l15) * 128;   // + db*32768 + Qn*16384 + nl*2048 + sw

    f32x4 acc[2][2][2][4] = {};   // [Qm][ml][Qn][nl]
    bf16x8 av[2][2];              // A operand regs [ml][k]
    bf16x8 bv[4][2];              // B operand regs [nl][k]

#define STA(db, h, kt) do {                                                     \
    glds16(sA[h][0] + (size_t)(kt) * 64, stA + (db) * 32768 + (h) * 16384);     \
    glds16(sA[h][1] + (size_t)(kt) * 64, stA + (db) * 32768 + (h) * 16384 + 8192); } while (0)
#define STB(db, h, kt) do {                                                     \
    glds16(sB[h][0] + (size_t)(kt) * 64, stB + (db) * 32768 + (h) * 16384);     \
    glds16(sB[h][1] + (size_t)(kt) * 64, stB + (db) * 32768 + (h) * 16384 + 8192); } while (0)

// k-sliced operand loads (2 reads for A-slice, 4 for B-slice)
#define LAk(db, Qm, kk) do {                                                    \
    _Pragma("unroll")                                                           \
    for (int ml = 0; ml < 2; ++ml)                                              \
        av[ml][kk] = *(const bf16x8*)(rA + (db)*32768 + (Qm)*16384 + ml*2048    \
                                      + ((kk) ? sw1 : sw0));                    \
    } while (0)
#define LBk(db, Qn, kk) do {                                                    \
    _Pragma("unroll")                                                           \
    for (int nl = 0; nl < 4; ++nl)                                              \
        bv[nl][kk] = *(const bf16x8*)(rB + (db)*32768 + (Qn)*16384 + nl*2048    \
                                      + ((kk) ? sw1 : sw0));                    \
    } while (0)

// 8-MFMA group for one k-slice of quadrant (Qm,Qn)
#define GK(Qm, Qn, kk) do {                                                     \
    _Pragma("unroll")                                                           \
    for (int ml = 0; ml < 2; ++ml)                                              \
        _Pragma("unroll")                                                       \
        for (int nl = 0; nl < 4; ++nl)                                          \
            acc[Qm][ml][Qn][nl] = __builtin_amdgcn_mfma_f32_16x16x32_bf16(      \
                av[ml][kk], bv[nl][kk], acc[Qm][ml][Qn][nl], 0, 0, 0);          \
    } while (0)

// window: stage; [counted vmcnt]; then k-split MFMA with next-window loads
// pinned mid-cluster via sched_barrier(0); single barrier at end.
#define WINDOW(Qm, Qn, STAGE_STMT, VM_STMT, LK0, LK1) do {                      \
    STAGE_STMT;                                                                 \
    VM_STMT;                                                                    \
    __builtin_amdgcn_s_setprio(1);                                              \
    GK(Qm, Qn, 0);                                                              \
    __builtin_amdgcn_sched_barrier(0);                                          \
    LK0;                                                                        \
    __builtin_amdgcn_sched_barrier(0);                                          \
    GK(Qm, Qn, 1);                                                              \
    __builtin_amdgcn_sched_barrier(0);                                          \
    LK1;                                                                        \
    __builtin_amdgcn_s_setprio(0);                                              \
    __builtin_amdgcn_sched_barrier(0);                                          \
    __builtin_amdgcn_s_barrier();                                               \
} while (0)

    const int nkt = K >> 6;           // 64-wide K-tiles (even for all layers)
    // prologue: buf0 = tile0 full; buf1 h0 = tile1 {A,B}; then first reads
    STA(0, 0, 0); STA(0, 1, 0); STB(0, 0, 0); STB(0, 1, 0);
    STA(1, 0, 1); STB(1, 0, 1);
    asm volatile("s_waitcnt vmcnt(4)" ::: "memory");   // buf0's 8 loads landed
    __builtin_amdgcn_s_barrier();
    LAk(0, 1, 0); LAk(0, 1, 1); LBk(0, 0, 0); LBk(0, 0, 1);  // regs for window 1

    const int niter = nkt >> 1;
    for (int it = 0; it < niter; ++it) {
        const int t1 = 2 * it + 1;
        const int t2 = (2 * it + 2 < nkt) ? 2 * it + 2 : nkt - 1;  // clamped: dead stages
        const int t3 = (2 * it + 3 < nkt) ? 2 * it + 3 : nkt - 1;
        WINDOW(1, 0, STA(1, 1, t1), ((void)0), LAk(0, 0, 0), LAk(0, 0, 1));
        WINDOW(0, 0, STB(1, 1, t1), ((void)0), LBk(0, 1, 0), LBk(0, 1, 1));
        WINDOW(0, 1, STA(0, 0, t2), ((void)0), LAk(0, 1, 0), LAk(0, 1, 1));
        WINDOW(1, 1, STB(0, 0, t2),
               asm volatile("s_waitcnt vmcnt(4)" ::: "memory"),
               LAk(1, 1, 0); LBk(1, 0, 0), LAk(1, 1, 1); LBk(1, 0, 1));
        WINDOW(1, 0, STA(0, 1, t2), ((void)0), LAk(1, 0, 0), LAk(1, 0, 1));
        WINDOW(0, 0, STB(0, 1, t2), ((void)0), LBk(1, 1, 0), LBk(1, 1, 1));
        WINDOW(0, 1, STA(1, 0, t3), ((void)0), LAk(1, 1, 0), LAk(1, 1, 1));
        WINDOW(1, 1, STB(1, 0, t3),
               asm volatile("s_waitcnt vmcnt(4)" ::: "memory"),
               LAk(0, 1, 0); LBk(0, 0, 0), LAk(0, 1, 1); LBk(0, 0, 1));
    }
    asm volatile("s_waitcnt vmcnt(0)" ::: "memory");   // drain tail stages

    // epilogue. C/D (m89-verified): col = lane&15 (B side), row = (lane>>4)*4+jj
    const int rl = (lane >> 4) << 2;
    float bsv[2][4];
    #pragma unroll
    for (int Qn = 0; Qn < 2; ++Qn)
        #pragma unroll
        for (int nl = 0; nl < 4; ++nl)
            bsv[Qn][nl] = biasp[bn + Qn * 128 + wn1 * 64 + nl * 16 + l15];

    unsigned short* Hp = Hb + (size_t)e * plane;
    #pragma unroll
    for (int Qm = 0; Qm < 2; ++Qm)
    #pragma unroll
    for (int ml = 0; ml < 2; ++ml)
    #pragma unroll
    for (int jj = 0; jj < 4; ++jj) {
        int srow = bm + Qm * 128 + wl3 * 32 + ml * 16 + rl + jj;
        size_t ro = (size_t)srow * N;
        #pragma unroll
        for (int Qn = 0; Qn < 2; ++Qn)
        #pragma unroll
        for (int nl = 0; nl < 4; ++nl) {
            int col = bn + Qn * 128 + wn1 * 64 + nl * 16 + l15;
            float v = acc[Qm][ml][Qn][nl][jj] + bsv[Qn][nl];
            if (ACT) v = v > 0.f ? v : 0.2f * v;
            Hp[ro + col] = f2bf(v);
        }
    }
#undef WINDOW
#undef GK
#undef LAk
#undef LBk
#undef STA
#undef STB
}

// ---------------- host launch ----------------

extern "C" void kernel_launch(void* const* d_in, const int* in_sizes, int n_in,
                              void* d_out, int out_size, void* d_ws, size_t ws_size,
                              hipStream_t stream)
{
    const float* x     = (const float*)d_in[0];
    // d_in[1] = gate (unused by reference forward)
    const float* probs = (const float*)d_in[2];
    const int*   tidx  = (const int*)d_in[3];
    const float* W1    = (const float*)d_in[4];
    const float* b1    = (const float*)d_in[5];
    const float* W2    = (const float*)d_in[6];
    const float* b2    = (const float*)d_in[7];
    const float* W3    = (const float*)d_in[8];
    const float* b3    = (const float*)d_in[9];
    float* out = (float*)d_out;

    // workspace layout (bytes); total ~340 MB of the 512 MiB d_ws
    char* ws = (char*)d_ws;
    const size_t xb_off  = 0;
    const size_t w1t_off = xb_off  + (size_t)B_TOK * IN_DIM * 2;
    const size_t w2t_off = w1t_off + (size_t)NEXP * IN_DIM * H1_DIM * 2;
    const size_t w3t_off = w2t_off + (size_t)NEXP * H1_DIM * H2_DIM * 2;
    const size_t h1_off  = w3t_off + (size_t)NEXP * H2_DIM * D_DIM * 2;
    const size_t h2_off  = h1_off  + (size_t)NEXP * B_TOK * H1_DIM * 2;
    const size_t y_off   = h2_off  + (size_t)NEXP * B_TOK * H2_DIM * 2;
    const size_t li_off  = y_off   + (size_t)NEXP * B_TOK * D_DIM * 2;   // y bf16
    const size_t iv_off  = li_off  + (size_t)NEXP * B_TOK * 4;
    const size_t cn_off  = iv_off  + (size_t)NEXP * B_TOK * 4;
    const size_t cp_off  = cn_off  + 256;

    unsigned short* xb  = (unsigned short*)(ws + xb_off);
    unsigned short* W1t = (unsigned short*)(ws + w1t_off);
    unsigned short* W2t = (unsigned short*)(ws + w2t_off);
    unsigned short* W3t = (unsigned short*)(ws + w3t_off);
    unsigned short* h1  = (unsigned short*)(ws + h1_off);
    unsigned short* h2  = (unsigned short*)(ws + h2_off);
    unsigned short* y   = (unsigned short*)(ws + y_off);
    int*            lst = (int*)(ws + li_off);
    int*            inv = (int*)(ws + iv_off);
    int*            cnt = (int*)(ws + cn_off);
    int*            cnp = (int*)(ws + cp_off);

    hipMemsetAsync(cnt, 0, 256, stream);

    convert_f32_bf16<<<2048, 256, 0, stream>>>(x, xb, (size_t)B_TOK * IN_DIM);
    transpose_convert<<<dim3(H1_DIM / 64, IN_DIM / 64, NEXP), 256, 0, stream>>>(W1, W1t, IN_DIM, H1_DIM);
    transpose_convert<<<dim3(H2_DIM / 64, H1_DIM / 64, NEXP), 256, 0, stream>>>(W2, W2t, H1_DIM, H2_DIM);
    transpose_convert<<<dim3(D_DIM / 64, H2_DIM / 64, NEXP), 256, 0, stream>>>(W3, W3t, H2_DIM, D_DIM);
    route_tokens<<<B_TOK / 256, 256, 0, stream>>>(probs, tidx, cnt, lst, inv);
    finalize_counts<<<NEXP, 256, 0, stream>>>(cnt, cnp, lst);

    const size_t h1pl = (size_t)B_TOK * H1_DIM;
    const size_t h2pl = (size_t)B_TOK * H2_DIM;
    const size_t ypl  = (size_t)B_TOK * D_DIM;

    // L1 grouped across experts: gathered x rows -> h1 planes (bf16)
    gemm8<1, 1><<<dim3(NEXP * 64 * 4), 512, 0, stream>>>(
        xb, 0, W1t, b1, h1, h1pl,
        lst, cnp, H1_DIM, IN_DIM, 4, 0);
    // L2 grouped: h1 planes -> h2 planes (bf16)
    gemm8<1, 0><<<dim3(NEXP * 64 * 2), 512, 0, stream>>>(
        h1, h1pl, W2t, b2, h2, h2pl,
        lst, cnp, H2_DIM, H1_DIM, 2, 0);
    // L3 grouped: h2 planes -> compact y planes (bf16, bias applied, no weight)
    gemm8<0, 0><<<dim3(NEXP * 64 * 4), 512, 0, stream>>>(
        h2, h2pl, W3t, b3, y, ypl,
        lst, cnp, D_DIM, H2_DIM, 4, 0);
    // combine: out[tok] = p0*y[i0][slot0] + p1*y[i1][slot1]
    combine_out<<<dim3(B_TOK * 128 / 256), 256, 0, stream>>>(
        probs, tidx, inv, y, ypl, out);
}

// Round 10
// 282.535 us; speedup vs baseline: 1.8890x; 1.0127x over previous
//
#include <hip/hip_runtime.h>
#include <cstdint>
#include <cstddef>

// Problem constants (match reference setup_inputs)
#define B_TOK   16384
#define IN_DIM  2048
#define D_DIM   1024
#define NEXP    3
#define TOPK    2
#define H1_DIM  1024
#define H2_DIM  512

typedef __bf16 bf16x8 __attribute__((ext_vector_type(8)));
typedef float  f32x4  __attribute__((ext_vector_type(4)));
typedef unsigned short ushort8_t __attribute__((ext_vector_type(8)));

__device__ __forceinline__ unsigned short f2bf(float f) {
    unsigned int u = __builtin_bit_cast(unsigned int, f);
    return (unsigned short)((u + 0x7fffu + ((u >> 16) & 1u)) >> 16);
}
__device__ __forceinline__ float bf2f(unsigned short v) {
    return __builtin_bit_cast(float, (unsigned int)v << 16);
}

// async global->LDS, 16B per lane. LDS dest is wave-uniform base + lane*16;
// global source address IS per-lane (enables gather + inverse-swizzle).
__device__ __forceinline__ void glds16(const void* gsrc, void* ldst) {
    __builtin_amdgcn_global_load_lds(
        (__attribute__((address_space(1))) void*)(gsrc),
        (__attribute__((address_space(3))) void*)(ldst),
        16, 0, 0);
}

// ---------------- prepass kernels ----------------

__global__ __launch_bounds__(256) void convert_f32_bf16(
    const float* __restrict__ in, unsigned short* __restrict__ out, size_t n)
{
    size_t i = ((size_t)blockIdx.x * blockDim.x + threadIdx.x) * 8;
    size_t stride = (size_t)gridDim.x * blockDim.x * 8;
    for (; i < n; i += stride) {
        float4 a = *(const float4*)(in + i);
        float4 b = *(const float4*)(in + i + 4);
        ushort8_t o;
        o[0] = f2bf(a.x); o[1] = f2bf(a.y); o[2] = f2bf(a.z); o[3] = f2bf(a.w);
        o[4] = f2bf(b.x); o[5] = f2bf(b.y); o[6] = f2bf(b.z); o[7] = f2bf(b.w);
        *(ushort8_t*)(out + i) = o;
    }
}

// All three W [E][K][N] f32 -> Wt [E][N][K] bf16 transposes in ONE launch.
// Per expert: W1 = 16x32 = 512 tiles, W2 = 8x16 = 128, W3 = 16x8 = 128
// -> 768 blocks/expert, 2304 total. Body identical to the per-weight version.
__global__ __launch_bounds__(256) void transpose_convert_all(
    const float* __restrict__ W1s, const float* __restrict__ W2s,
    const float* __restrict__ W3s,
    unsigned short* __restrict__ W1d, unsigned short* __restrict__ W2d,
    unsigned short* __restrict__ W3d)
{
    __shared__ unsigned short tile[64][68];
    int bid = blockIdx.x;
    int e = bid / 768;
    int r = bid % 768;
    const float* W; unsigned short* Wt; int K, N, tx;
    if (r < 512)      { W = W1s; Wt = W1d; K = IN_DIM; N = H1_DIM; tx = r; }
    else if (r < 640) { W = W2s; Wt = W2d; K = H1_DIM; N = H2_DIM; tx = r - 512; }
    else              { W = W3s; Wt = W3d; K = H2_DIM; N = D_DIM;  tx = r - 640; }
    const int ntx = N >> 6;
    const float* Wp = W + (size_t)e * K * N;
    unsigned short* Wtp = Wt + (size_t)e * N * K;
    int n0 = (tx % ntx) * 64, k0 = (tx / ntx) * 64;
    int t = threadIdx.x;
    int nn = (t & 15) * 4;
    int kk = t >> 4;
    #pragma unroll
    for (int rr = 0; rr < 4; ++rr) {
        int k = kk + rr * 16;
        float4 v = *(const float4*)(Wp + (size_t)(k0 + k) * N + (n0 + nn));
        tile[k][nn + 0] = f2bf(v.x);
        tile[k][nn + 1] = f2bf(v.y);
        tile[k][nn + 2] = f2bf(v.z);
        tile[k][nn + 3] = f2bf(v.w);
    }
    __syncthreads();
    int n  = t >> 2;
    int kb = (t & 3) * 16;
    ushort8_t o0, o1;
    #pragma unroll
    for (int i = 0; i < 8; ++i) o0[i] = tile[kb + i][n];
    #pragma unroll
    for (int i = 0; i < 8; ++i) o1[i] = tile[kb + 8 + i][n];
    unsigned short* dst = Wtp + (size_t)(n0 + n) * K + (k0 + kb);
    *(ushort8_t*)dst = o0;
    *(ushort8_t*)(dst + 8) = o1;
}

// Two-phase token routing. Also writes inv[e][tok] = compact slot of tok in
// expert e's list (used by the combine pass). Slot order is nondeterministic
// across replays, but every per-token output value is slot-independent, so
// d_out stays deterministic.
__global__ __launch_bounds__(256) void route_tokens(
    const float* __restrict__ probs, const int* __restrict__ idx,
    int* __restrict__ cnt, int* __restrict__ list, int* __restrict__ inv)
{
    __shared__ int lcnt[NEXP];
    __shared__ int lbase[NEXP];
    __shared__ int ltok[NEXP][256];
    int t = threadIdx.x;
    int b = blockIdx.x * 256 + t;
    if (t < NEXP) lcnt[t] = 0;
    __syncthreads();
    int i0 = idx[b * TOPK + 0], i1 = idx[b * TOPK + 1];
    #pragma unroll
    for (int e = 0; e < NEXP; ++e) {
        if (i0 == e || i1 == e) {
            int s = atomicAdd(&lcnt[e], 1);
            ltok[e][s] = b;
        }
    }
    __syncthreads();
    if (t < NEXP) lbase[t] = atomicAdd(&cnt[t], lcnt[t]);
    __syncthreads();
    #pragma unroll
    for (int e = 0; e < NEXP; ++e) {
        int n = lcnt[e], base = lbase[e];
        for (int s = t; s < n; s += 256) {
            int tk = ltok[e][s];
            list[e * B_TOK + base + s] = tk;
            inv[e * B_TOK + tk] = base + s;
        }
    }
}

// round counts up to 256-tile multiple; pad list with token 0
__global__ void finalize_counts(const int* __restrict__ cnt, int* __restrict__ cntp,
                                int* __restrict__ list)
{
    int e = blockIdx.x;
    int c = cnt[e];
    int cp = (c + 255) & ~255;
    if (threadIdx.x == 0) cntp[e] = cp;
    for (int s = c + threadIdx.x; s < cp; s += blockDim.x)
        list[e * B_TOK + s] = 0;
}

// combine: out[tok] = p0 * y[i0][inv[i0][tok]] + p1 * y[i1][inv[i1][tok]]
// y planes are bf16. Handles i0==i1 naturally. Writes EVERY output element.
__global__ __launch_bounds__(256) void combine_out(
    const float* __restrict__ probs, const int* __restrict__ tidx,
    const int* __restrict__ inv, const unsigned short* __restrict__ y, size_t ypl,
    float* __restrict__ out)
{
    int gid = blockIdx.x * 256 + threadIdx.x;
    int tok = gid >> 7;              // 128 threads per token
    int dc  = (gid & 127) << 3;      // 8 cols per thread
    float p0 = probs[tok * TOPK + 0], p1 = probs[tok * TOPK + 1];
    int   i0 = tidx [tok * TOPK + 0], i1 = tidx [tok * TOPK + 1];
    size_t r0 = (size_t)i0 * ypl + (size_t)inv[(size_t)i0 * B_TOK + tok] * D_DIM + dc;
    size_t r1 = (size_t)i1 * ypl + (size_t)inv[(size_t)i1 * B_TOK + tok] * D_DIM + dc;
    ushort8_t a = *(const ushort8_t*)(y + r0);
    ushort8_t b = *(const ushort8_t*)(y + r1);
    float4 o0, o1;
    o0.x = p0 * bf2f(a[0]) + p1 * bf2f(b[0]);
    o0.y = p0 * bf2f(a[1]) + p1 * bf2f(b[1]);
    o0.z = p0 * bf2f(a[2]) + p1 * bf2f(b[2]);
    o0.w = p0 * bf2f(a[3]) + p1 * bf2f(b[3]);
    o1.x = p0 * bf2f(a[4]) + p1 * bf2f(b[4]);
    o1.y = p0 * bf2f(a[5]) + p1 * bf2f(b[5]);
    o1.z = p0 * bf2f(a[6]) + p1 * bf2f(b[6]);
    o1.w = p0 * bf2f(a[7]) + p1 * bf2f(b[7]);
    float* op = out + (size_t)tok * D_DIM + dc;
    *(float4*)op = o0;
    *(float4*)(op + 4) = o1;
}

// ---------------- 8-window 256x256 GEMM, k-split interleaved ----------------
// C = act(A[slots,K] @ Bt[N,K]^T + bias) -> bf16 planes.
// EXACT round-8 passing version (re-verified ledger). Round-9's 4-window
// variant FAILED: avv+bv+acc > 256 VGPR forced scratch spills, whose VMEM ops
// corrupt the counted-vmcnt semantics (stale LDS reads). Rule: counted-vmcnt
// schedules require a provably spill-free loop body.
template<int ACT, int GATHER>
__global__ __launch_bounds__(512, 2) void gemm8(
    const unsigned short* __restrict__ Ab, size_t Aplane,  // bf16 [slots][K] (per-expert plane if !GATHER)
    const unsigned short* __restrict__ Bb,                 // bf16 [E][N][K]
    const float* __restrict__ biasb,                       // [E][N]
    unsigned short* __restrict__ Hb,                       // bf16 planes out
    size_t plane,                                          // elements per plane
    const int* __restrict__ listb,                         // [E][B_TOK]
    const int* __restrict__ cntp,                          // [E] padded count
    int N, int K, int NT, int e0)
{
    // bijective tile->XCD mapping: xcd=bid&7; XCD x walks A-tiles {x,x+8,...}
    // with the NT N-blocks of each A-tile consecutive (L2 A-reuse); live
    // tiles (early-exit) spread evenly across XCDs.
    const int bid  = blockIdx.x;
    const int xcd  = bid & 7;
    const int slot = bid >> 3;
    const int q    = slot / NT;
    const int nt   = slot % NT;
    const int ti   = q * 8 + xcd;
    const int e    = e0 + (ti >> 6);
    const int mt   = ti & 63;
    const int bm   = mt << 8;
    if (bm >= cntp[e]) return;
    const int bn   = nt << 8;

    __shared__ char smem[131072];   // A: [0,64K)  B: [64K,128K)

    const int tid  = threadIdx.x;
    const int lane = tid & 63;
    const int w    = tid >> 6;      // wave 0..7
    const int wl3  = w & 3;         // A 32-row band within half
    const int wn1  = w >> 2;        // B 64-col band within half
    const int l15  = lane & 15;
    const int ug8  = (((tid & 7) ^ ((tid >> 3) & 7)) << 3);          // src swz (shorts)
    const int sw0  = ((((lane >> 4) + 0) ^ (lane & 7)) << 4);        // read swz k0 (bytes)
    const int sw1  = ((((lane >> 4) + 4) ^ (lane & 7)) << 4);        // read swz k1 (bytes)

    const int* listp = listb + (size_t)e * B_TOK;
    const unsigned short* Ae = Ab + (size_t)e * Aplane;
    const unsigned short* Be = Bb + (size_t)e * ((size_t)N * K);
    const float* biasp = biasb + (size_t)e * N;

    // per-thread stage source pointers: half h, load j covers tile row
    // h*128 + j*64 + (tid>>3); 16B unit = (tid&7) ^ ((tid>>3)&7)  (inverse swz)
    const unsigned short* sA[2][2];
    const unsigned short* sB[2][2];
    #pragma unroll
    for (int h = 0; h < 2; ++h)
        #pragma unroll
        for (int j = 0; j < 2; ++j) {
            int lrow = h * 128 + j * 64 + (tid >> 3);
            int arow;
            if constexpr (GATHER) arow = listp[bm + lrow];
            else                  arow = bm + lrow;
            sA[h][j] = Ae + (size_t)arow * K + ug8;
            sB[h][j] = Be + (size_t)(bn + lrow) * K + ug8;
        }

    char* const stA = smem + (w << 10);            // + db*32768 + h*16384 (+8192 for j=1)
    char* const stB = smem + 65536 + (w << 10);
    const char* const rA = smem + (wl3 * 32 + l15) * 128;           // + db*32768 + Qm*16384 + ml*2048 + sw
    const char* const rB = smem + 65536 + (wn1 * 64 + l15) * 128;   // + db*32768 + Qn*16384 + nl*2048 + sw

    f32x4 acc[2][2][2][4] = {};   // [Qm][ml][Qn][nl]
    bf16x8 av[2][2];              // A operand regs [ml][k]
    bf16x8 bv[4][2];              // B operand regs [nl][k]

#define STA(db, h, kt) do {                                                     \
    glds16(sA[h][0] + (size_t)(kt) * 64, stA + (db) * 32768 + (h) * 16384);     \
    glds16(sA[h][1] + (size_t)(kt) * 64, stA + (db) * 32768 + (h) * 16384 + 8192); } while (0)
#define STB(db, h, kt) do {                                                     \
    glds16(sB[h][0] + (size_t)(kt) * 64, stB + (db) * 32768 + (h) * 16384);     \
    glds16(sB[h][1] + (size_t)(kt) * 64, stB + (db) * 32768 + (h) * 16384 + 8192); } while (0)

// k-sliced operand loads (2 reads for A-slice, 4 for B-slice)
#define LAk(db, Qm, kk) do {                                                    \
    _Pragma("unroll")                                                           \
    for (int ml = 0; ml < 2; ++ml)                                              \
        av[ml][kk] = *(const bf16x8*)(rA + (db)*32768 + (Qm)*16384 + ml*2048    \
                                      + ((kk) ? sw1 : sw0));                    \
    } while (0)
#define LBk(db, Qn, kk) do {                                                    \
    _Pragma("unroll")                                                           \
    for (int nl = 0; nl < 4; ++nl)                                              \
        bv[nl][kk] = *(const bf16x8*)(rB + (db)*32768 + (Qn)*16384 + nl*2048    \
                                      + ((kk) ? sw1 : sw0));                    \
    } while (0)

// 8-MFMA group for one k-slice of quadrant (Qm,Qn)
#define GK(Qm, Qn, kk) do {                                                     \
    _Pragma("unroll")                                                           \
    for (int ml = 0; ml < 2; ++ml)                                              \
        _Pragma("unroll")                                                       \
        for (int nl = 0; nl < 4; ++nl)                                          \
            acc[Qm][ml][Qn][nl] = __builtin_amdgcn_mfma_f32_16x16x32_bf16(      \
                av[ml][kk], bv[nl][kk], acc[Qm][ml][Qn][nl], 0, 0, 0);          \
    } while (0)

// window: stage; [counted vmcnt]; then k-split MFMA with next-window loads
// pinned mid-cluster via sched_barrier(0); single barrier at end.
#define WINDOW(Qm, Qn, STAGE_STMT, VM_STMT, LK0, LK1) do {                      \
    STAGE_STMT;                                                                 \
    VM_STMT;                                                                    \
    __builtin_amdgcn_s_setprio(1);                                              \
    GK(Qm, Qn, 0);                                                              \
    __builtin_amdgcn_sched_barrier(0);                                          \
    LK0;                                                                        \
    __builtin_amdgcn_sched_barrier(0);                                          \
    GK(Qm, Qn, 1);                                                              \
    __builtin_amdgcn_sched_barrier(0);                                          \
    LK1;                                                                        \
    __builtin_amdgcn_s_setprio(0);                                              \
    __builtin_amdgcn_sched_barrier(0);                                          \
    __builtin_amdgcn_s_barrier();                                               \
} while (0)

    const int nkt = K >> 6;           // 64-wide K-tiles (even for all layers)
    // prologue: buf0 = tile0 full; buf1 h0 = tile1 {A,B}; then first reads
    STA(0, 0, 0); STA(0, 1, 0); STB(0, 0, 0); STB(0, 1, 0);
    STA(1, 0, 1); STB(1, 0, 1);
    asm volatile("s_waitcnt vmcnt(4)" ::: "memory");   // buf0's 8 loads landed
    __builtin_amdgcn_s_barrier();
    LAk(0, 1, 0); LAk(0, 1, 1); LBk(0, 0, 0); LBk(0, 0, 1);  // regs for window 1

    const int niter = nkt >> 1;
    for (int it = 0; it < niter; ++it) {
        const int t1 = 2 * it + 1;
        const int t2 = (2 * it + 2 < nkt) ? 2 * it + 2 : nkt - 1;  // clamped: dead stages
        const int t3 = (2 * it + 3 < nkt) ? 2 * it + 3 : nkt - 1;
        WINDOW(1, 0, STA(1, 1, t1), ((void)0), LAk(0, 0, 0), LAk(0, 0, 1));
        WINDOW(0, 0, STB(1, 1, t1), ((void)0), LBk(0, 1, 0), LBk(0, 1, 1));
        WINDOW(0, 1, STA(0, 0, t2), ((void)0), LAk(0, 1, 0), LAk(0, 1, 1));
        WINDOW(1, 1, STB(0, 0, t2),
               asm volatile("s_waitcnt vmcnt(4)" ::: "memory"),
               LAk(1, 1, 0); LBk(1, 0, 0), LAk(1, 1, 1); LBk(1, 0, 1));
        WINDOW(1, 0, STA(0, 1, t2), ((void)0), LAk(1, 0, 0), LAk(1, 0, 1));
        WINDOW(0, 0, STB(0, 1, t2), ((void)0), LBk(1, 1, 0), LBk(1, 1, 1));
        WINDOW(0, 1, STA(1, 0, t3), ((void)0), LAk(1, 1, 0), LAk(1, 1, 1));
        WINDOW(1, 1, STB(1, 0, t3),
               asm volatile("s_waitcnt vmcnt(4)" ::: "memory"),
               LAk(0, 1, 0); LBk(0, 0, 0), LAk(0, 1, 1); LBk(0, 0, 1));
    }
    asm volatile("s_waitcnt vmcnt(0)" ::: "memory");   // drain tail stages

    // epilogue. C/D (m89-verified): col = lane&15 (B side), row = (lane>>4)*4+jj
    const int rl = (lane >> 4) << 2;
    float bsv[2][4];
    #pragma unroll
    for (int Qn = 0; Qn < 2; ++Qn)
        #pragma unroll
        for (int nl = 0; nl < 4; ++nl)
            bsv[Qn][nl] = biasp[bn + Qn * 128 + wn1 * 64 + nl * 16 + l15];

    unsigned short* Hp = Hb + (size_t)e * plane;
    #pragma unroll
    for (int Qm = 0; Qm < 2; ++Qm)
    #pragma unroll
    for (int ml = 0; ml < 2; ++ml)
    #pragma unroll
    for (int jj = 0; jj < 4; ++jj) {
        int srow = bm + Qm * 128 + wl3 * 32 + ml * 16 + rl + jj;
        size_t ro = (size_t)srow * N;
        #pragma unroll
        for (int Qn = 0; Qn < 2; ++Qn)
        #pragma unroll
        for (int nl = 0; nl < 4; ++nl) {
            int col = bn + Qn * 128 + wn1 * 64 + nl * 16 + l15;
            float v = acc[Qm][ml][Qn][nl][jj] + bsv[Qn][nl];
            if (ACT) v = v > 0.f ? v : 0.2f * v;
            Hp[ro + col] = f2bf(v);
        }
    }
#undef WINDOW
#undef GK
#undef LAk
#undef LBk
#undef STA
#undef STB
}

// ---------------- host launch ----------------

extern "C" void kernel_launch(void* const* d_in, const int* in_sizes, int n_in,
                              void* d_out, int out_size, void* d_ws, size_t ws_size,
                              hipStream_t stream)
{
    const float* x     = (const float*)d_in[0];
    // d_in[1] = gate (unused by reference forward)
    const float* probs = (const float*)d_in[2];
    const int*   tidx  = (const int*)d_in[3];
    const float* W1    = (const float*)d_in[4];
    const float* b1    = (const float*)d_in[5];
    const float* W2    = (const float*)d_in[6];
    const float* b2    = (const float*)d_in[7];
    const float* W3    = (const float*)d_in[8];
    const float* b3    = (const float*)d_in[9];
    float* out = (float*)d_out;

    // workspace layout (bytes); total ~340 MB of the 512 MiB d_ws
    char* ws = (char*)d_ws;
    const size_t xb_off  = 0;
    const size_t w1t_off = xb_off  + (size_t)B_TOK * IN_DIM * 2;
    const size_t w2t_off = w1t_off + (size_t)NEXP * IN_DIM * H1_DIM * 2;
    const size_t w3t_off = w2t_off + (size_t)NEXP * H1_DIM * H2_DIM * 2;
    const size_t h1_off  = w3t_off + (size_t)NEXP * H2_DIM * D_DIM * 2;
    const size_t h2_off  = h1_off  + (size_t)NEXP * B_TOK * H1_DIM * 2;
    const size_t y_off   = h2_off  + (size_t)NEXP * B_TOK * H2_DIM * 2;
    const size_t li_off  = y_off   + (size_t)NEXP * B_TOK * D_DIM * 2;   // y bf16
    const size_t iv_off  = li_off  + (size_t)NEXP * B_TOK * 4;
    const size_t cn_off  = iv_off  + (size_t)NEXP * B_TOK * 4;
    const size_t cp_off  = cn_off  + 256;

    unsigned short* xb  = (unsigned short*)(ws + xb_off);
    unsigned short* W1t = (unsigned short*)(ws + w1t_off);
    unsigned short* W2t = (unsigned short*)(ws + w2t_off);
    unsigned short* W3t = (unsigned short*)(ws + w3t_off);
    unsigned short* h1  = (unsigned short*)(ws + h1_off);
    unsigned short* h2  = (unsigned short*)(ws + h2_off);
    unsigned short* y   = (unsigned short*)(ws + y_off);
    int*            lst = (int*)(ws + li_off);
    int*            inv = (int*)(ws + iv_off);
    int*            cnt = (int*)(ws + cn_off);
    int*            cnp = (int*)(ws + cp_off);

    hipMemsetAsync(cnt, 0, 256, stream);

    convert_f32_bf16<<<2048, 256, 0, stream>>>(x, xb, (size_t)B_TOK * IN_DIM);
    transpose_convert_all<<<NEXP * 768, 256, 0, stream>>>(W1, W2, W3, W1t, W2t, W3t);
    route_tokens<<<B_TOK / 256, 256, 0, stream>>>(probs, tidx, cnt, lst, inv);
    finalize_counts<<<NEXP, 256, 0, stream>>>(cnt, cnp, lst);

    const size_t h1pl = (size_t)B_TOK * H1_DIM;
    const size_t h2pl = (size_t)B_TOK * H2_DIM;
    const size_t ypl  = (size_t)B_TOK * D_DIM;

    // L1 grouped across experts: gathered x rows -> h1 planes (bf16)
    gemm8<1, 1><<<dim3(NEXP * 64 * 4), 512, 0, stream>>>(
        xb, 0, W1t, b1, h1, h1pl,
        lst, cnp, H1_DIM, IN_DIM, 4, 0);
    // L2 grouped: h1 planes -> h2 planes (bf16)
    gemm8<1, 0><<<dim3(NEXP * 64 * 2), 512, 0, stream>>>(
        h1, h1pl, W2t, b2, h2, h2pl,
        lst, cnp, H2_DIM, H1_DIM, 2, 0);
    // L3 grouped: h2 planes -> compact y planes (bf16, bias applied, no weight)
    gemm8<0, 0><<<dim3(NEXP * 64 * 4), 512, 0, stream>>>(
        h2, h2pl, W3t, b3, y, ypl,
        lst, cnp, D_DIM, H2_DIM, 4, 0);
    // combine: out[tok] = p0*y[i0][slot0] + p1*y[i1][slot1]
    combine_out<<<dim3(B_TOK * 128 / 256), 256, 0, stream>>>(
        probs, tidx, inv, y, ypl, out);
}

// Round 11
// 276.647 us; speedup vs baseline: 1.9292x; 1.0213x over previous
//
#include <hip/hip_runtime.h>
#include <cstdint>
#include <cstddef>

// Problem constants (match reference setup_inputs)
#define B_TOK   16384
#define IN_DIM  2048
#define D_DIM   1024
#define NEXP    3
#define TOPK    2
#define H1_DIM  1024
#define H2_DIM  512

typedef __bf16 bf16x8 __attribute__((ext_vector_type(8)));
typedef float  f32x4  __attribute__((ext_vector_type(4)));
typedef unsigned short ushort8_t __attribute__((ext_vector_type(8)));

__device__ __forceinline__ unsigned short f2bf(float f) {
    unsigned int u = __builtin_bit_cast(unsigned int, f);
    return (unsigned short)((u + 0x7fffu + ((u >> 16) & 1u)) >> 16);
}
__device__ __forceinline__ float bf2f(unsigned short v) {
    return __builtin_bit_cast(float, (unsigned int)v << 16);
}

// async global->LDS, 16B per lane. LDS dest is wave-uniform base + lane*16;
// global source address IS per-lane (enables gather + inverse-swizzle).
__device__ __forceinline__ void glds16(const void* gsrc, void* ldst) {
    __builtin_amdgcn_global_load_lds(
        (__attribute__((address_space(1))) void*)(gsrc),
        (__attribute__((address_space(3))) void*)(ldst),
        16, 0, 0);
}

// ---------------- fused prepass ----------------
// blocks [0,2048)      : x f32 -> bf16 (grid-stride, fixed stride)
// blocks [2048,4352)   : W1/W2/W3 [E][K][N] f32 -> [E][N][K] bf16 transpose
// blocks [4352,4416)   : token routing (cnt/list/inv); list pre-zeroed by
//                        host-side memset, so pad slots already hold token 0.
// All three parts are mutually independent -> they overlap across CUs.
__global__ __launch_bounds__(256) void prepass(
    const float* __restrict__ x, unsigned short* __restrict__ xb,
    const float* __restrict__ W1s, const float* __restrict__ W2s,
    const float* __restrict__ W3s,
    unsigned short* __restrict__ W1d, unsigned short* __restrict__ W2d,
    unsigned short* __restrict__ W3d,
    const float* __restrict__ probs, const int* __restrict__ tidx,
    int* __restrict__ cnt, int* __restrict__ list, int* __restrict__ inv)
{
    const int bid = blockIdx.x;
    const int t = threadIdx.x;

    if (bid < 2048) {
        // ---- convert x ----
        const size_t n = (size_t)B_TOK * IN_DIM;
        const size_t stride = (size_t)2048 * 256 * 8;
        size_t i = ((size_t)bid * 256 + t) * 8;
        for (; i < n; i += stride) {
            float4 a = *(const float4*)(x + i);
            float4 b = *(const float4*)(x + i + 4);
            ushort8_t o;
            o[0] = f2bf(a.x); o[1] = f2bf(a.y); o[2] = f2bf(a.z); o[3] = f2bf(a.w);
            o[4] = f2bf(b.x); o[5] = f2bf(b.y); o[6] = f2bf(b.z); o[7] = f2bf(b.w);
            *(ushort8_t*)(xb + i) = o;
        }
    } else if (bid < 4352) {
        // ---- transpose W ----
        __shared__ unsigned short tile[64][68];
        int r = (bid - 2048) % 768;
        int e = (bid - 2048) / 768;
        const float* W; unsigned short* Wt; int K, N, tx;
        if (r < 512)      { W = W1s; Wt = W1d; K = IN_DIM; N = H1_DIM; tx = r; }
        else if (r < 640) { W = W2s; Wt = W2d; K = H1_DIM; N = H2_DIM; tx = r - 512; }
        else              { W = W3s; Wt = W3d; K = H2_DIM; N = D_DIM;  tx = r - 640; }
        const int ntx = N >> 6;
        const float* Wp = W + (size_t)e * K * N;
        unsigned short* Wtp = Wt + (size_t)e * N * K;
        int n0 = (tx % ntx) * 64, k0 = (tx / ntx) * 64;
        int nn = (t & 15) * 4;
        int kk = t >> 4;
        #pragma unroll
        for (int rr = 0; rr < 4; ++rr) {
            int k = kk + rr * 16;
            float4 v = *(const float4*)(Wp + (size_t)(k0 + k) * N + (n0 + nn));
            tile[k][nn + 0] = f2bf(v.x);
            tile[k][nn + 1] = f2bf(v.y);
            tile[k][nn + 2] = f2bf(v.z);
            tile[k][nn + 3] = f2bf(v.w);
        }
        __syncthreads();
        int n  = t >> 2;
        int kb = (t & 3) * 16;
        ushort8_t o0, o1;
        #pragma unroll
        for (int i = 0; i < 8; ++i) o0[i] = tile[kb + i][n];
        #pragma unroll
        for (int i = 0; i < 8; ++i) o1[i] = tile[kb + 8 + i][n];
        unsigned short* dst = Wtp + (size_t)(n0 + n) * K + (k0 + kb);
        *(ushort8_t*)dst = o0;
        *(ushort8_t*)(dst + 8) = o1;
    } else {
        // ---- route tokens ----
        __shared__ int lcnt[NEXP];
        __shared__ int lbase[NEXP];
        __shared__ int ltok[NEXP][256];
        int b = (bid - 4352) * 256 + t;
        if (t < NEXP) lcnt[t] = 0;
        __syncthreads();
        int i0 = tidx[b * TOPK + 0], i1 = tidx[b * TOPK + 1];
        #pragma unroll
        for (int e = 0; e < NEXP; ++e) {
            if (i0 == e || i1 == e) {
                int s = atomicAdd(&lcnt[e], 1);
                ltok[e][s] = b;
            }
        }
        __syncthreads();
        if (t < NEXP) lbase[t] = atomicAdd(&cnt[t], lcnt[t]);
        __syncthreads();
        #pragma unroll
        for (int e = 0; e < NEXP; ++e) {
            int n = lcnt[e], base = lbase[e];
            for (int s = t; s < n; s += 256) {
                int tk = ltok[e][s];
                list[e * B_TOK + base + s] = tk;
                inv[e * B_TOK + tk] = base + s;
            }
        }
    }
}

// combine: out[tok] = p0 * y[i0][inv[i0][tok]] + p1 * y[i1][inv[i1][tok]]
// y planes are bf16. Handles i0==i1 naturally. Writes EVERY output element.
__global__ __launch_bounds__(256) void combine_out(
    const float* __restrict__ probs, const int* __restrict__ tidx,
    const int* __restrict__ inv, const unsigned short* __restrict__ y, size_t ypl,
    float* __restrict__ out)
{
    int gid = blockIdx.x * 256 + threadIdx.x;
    int tok = gid >> 7;              // 128 threads per token
    int dc  = (gid & 127) << 3;      // 8 cols per thread
    float p0 = probs[tok * TOPK + 0], p1 = probs[tok * TOPK + 1];
    int   i0 = tidx [tok * TOPK + 0], i1 = tidx [tok * TOPK + 1];
    size_t r0 = (size_t)i0 * ypl + (size_t)inv[(size_t)i0 * B_TOK + tok] * D_DIM + dc;
    size_t r1 = (size_t)i1 * ypl + (size_t)inv[(size_t)i1 * B_TOK + tok] * D_DIM + dc;
    ushort8_t a = *(const ushort8_t*)(y + r0);
    ushort8_t b = *(const ushort8_t*)(y + r1);
    float4 o0, o1;
    o0.x = p0 * bf2f(a[0]) + p1 * bf2f(b[0]);
    o0.y = p0 * bf2f(a[1]) + p1 * bf2f(b[1]);
    o0.z = p0 * bf2f(a[2]) + p1 * bf2f(b[2]);
    o0.w = p0 * bf2f(a[3]) + p1 * bf2f(b[3]);
    o1.x = p0 * bf2f(a[4]) + p1 * bf2f(b[4]);
    o1.y = p0 * bf2f(a[5]) + p1 * bf2f(b[5]);
    o1.z = p0 * bf2f(a[6]) + p1 * bf2f(b[6]);
    o1.w = p0 * bf2f(a[7]) + p1 * bf2f(b[7]);
    float* op = out + (size_t)tok * D_DIM + dc;
    *(float4*)op = o0;
    *(float4*)(op + 4) = o1;
}

// ---------------- 8-window 256x256 GEMM, k-split interleaved ----------------
// C = act(A[slots,K] @ Bt[N,K]^T + bias) -> bf16 planes.
// EXACT round-8/10 passing GEMM (frozen; 7 schedule variants all 42-43%
// MfmaUtil -> structural ceiling under the 256-reg/2-wave cap). Only change:
// padded count computed inline from cnt[e] (finalize_counts deleted; list
// pad slots are pre-zeroed by the host memset -> gather token 0).
template<int ACT, int GATHER>
__global__ __launch_bounds__(512, 2) void gemm8(
    const unsigned short* __restrict__ Ab, size_t Aplane,  // bf16 [slots][K] (per-expert plane if !GATHER)
    const unsigned short* __restrict__ Bb,                 // bf16 [E][N][K]
    const float* __restrict__ biasb,                       // [E][N]
    unsigned short* __restrict__ Hb,                       // bf16 planes out
    size_t plane,                                          // elements per plane
    const int* __restrict__ listb,                         // [E][B_TOK]
    const int* __restrict__ cntb,                          // [E] actual count
    int N, int K, int NT, int e0)
{
    // bijective tile->XCD mapping: xcd=bid&7; XCD x walks A-tiles {x,x+8,...}
    // with the NT N-blocks of each A-tile consecutive (L2 A-reuse); live
    // tiles (early-exit) spread evenly across XCDs.
    const int bid  = blockIdx.x;
    const int xcd  = bid & 7;
    const int slot = bid >> 3;
    const int q    = slot / NT;
    const int nt   = slot % NT;
    const int ti   = q * 8 + xcd;
    const int e    = e0 + (ti >> 6);
    const int mt   = ti & 63;
    const int bm   = mt << 8;
    const int cp   = (cntb[e] + 255) & ~255;   // padded count, inline
    if (bm >= cp) return;
    const int bn   = nt << 8;

    __shared__ char smem[131072];   // A: [0,64K)  B: [64K,128K)

    const int tid  = threadIdx.x;
    const int lane = tid & 63;
    const int w    = tid >> 6;      // wave 0..7
    const int wl3  = w & 3;         // A 32-row band within half
    const int wn1  = w >> 2;        // B 64-col band within half
    const int l15  = lane & 15;
    const int ug8  = (((tid & 7) ^ ((tid >> 3) & 7)) << 3);          // src swz (shorts)
    const int sw0  = ((((lane >> 4) + 0) ^ (lane & 7)) << 4);        // read swz k0 (bytes)
    const int sw1  = ((((lane >> 4) + 4) ^ (lane & 7)) << 4);        // read swz k1 (bytes)

    const int* listp = listb + (size_t)e * B_TOK;
    const unsigned short* Ae = Ab + (size_t)e * Aplane;
    const unsigned short* Be = Bb + (size_t)e * ((size_t)N * K);
    const float* biasp = biasb + (size_t)e * N;

    // per-thread stage source pointers: half h, load j covers tile row
    // h*128 + j*64 + (tid>>3); 16B unit = (tid&7) ^ ((tid>>3)&7)  (inverse swz)
    const unsigned short* sA[2][2];
    const unsigned short* sB[2][2];
    #pragma unroll
    for (int h = 0; h < 2; ++h)
        #pragma unroll
        for (int j = 0; j < 2; ++j) {
            int lrow = h * 128 + j * 64 + (tid >> 3);
            int arow;
            if constexpr (GATHER) arow = listp[bm + lrow];
            else                  arow = bm + lrow;
            sA[h][j] = Ae + (size_t)arow * K + ug8;
            sB[h][j] = Be + (size_t)(bn + lrow) * K + ug8;
        }

    char* const stA = smem + (w << 10);            // + db*32768 + h*16384 (+8192 for j=1)
    char* const stB = smem + 65536 + (w << 10);
    const char* const rA = smem + (wl3 * 32 + l15) * 128;           // + db*32768 + Qm*16384 + ml*2048 + sw
    const char* const rB = smem + 65536 + (wn1 * 64 + l15) * 128;   // + db*32768 + Qn*16384 + nl*2048 + sw

    f32x4 acc[2][2][2][4] = {};   // [Qm][ml][Qn][nl]
    bf16x8 av[2][2];              // A operand regs [ml][k]
    bf16x8 bv[4][2];              // B operand regs [nl][k]

#define STA(db, h, kt) do {                                                     \
    glds16(sA[h][0] + (size_t)(kt) * 64, stA + (db) * 32768 + (h) * 16384);     \
    glds16(sA[h][1] + (size_t)(kt) * 64, stA + (db) * 32768 + (h) * 16384 + 8192); } while (0)
#define STB(db, h, kt) do {                                                     \
    glds16(sB[h][0] + (size_t)(kt) * 64, stB + (db) * 32768 + (h) * 16384);     \
    glds16(sB[h][1] + (size_t)(kt) * 64, stB + (db) * 32768 + (h) * 16384 + 8192); } while (0)

// k-sliced operand loads (2 reads for A-slice, 4 for B-slice)
#define LAk(db, Qm, kk) do {                                                    \
    _Pragma("unroll")                                                           \
    for (int ml = 0; ml < 2; ++ml)                                              \
        av[ml][kk] = *(const bf16x8*)(rA + (db)*32768 + (Qm)*16384 + ml*2048    \
                                      + ((kk) ? sw1 : sw0));                    \
    } while (0)
#define LBk(db, Qn, kk) do {                                                    \
    _Pragma("unroll")                                                           \
    for (int nl = 0; nl < 4; ++nl)                                              \
        bv[nl][kk] = *(const bf16x8*)(rB + (db)*32768 + (Qn)*16384 + nl*2048    \
                                      + ((kk) ? sw1 : sw0));                    \
    } while (0)

// 8-MFMA group for one k-slice of quadrant (Qm,Qn)
#define GK(Qm, Qn, kk) do {                                                     \
    _Pragma("unroll")                                                           \
    for (int ml = 0; ml < 2; ++ml)                                              \
        _Pragma("unroll")                                                       \
        for (int nl = 0; nl < 4; ++nl)                                          \
            acc[Qm][ml][Qn][nl] = __builtin_amdgcn_mfma_f32_16x16x32_bf16(      \
                av[ml][kk], bv[nl][kk], acc[Qm][ml][Qn][nl], 0, 0, 0);          \
    } while (0)

// window: stage; [counted vmcnt]; then k-split MFMA with next-window loads
// pinned mid-cluster via sched_barrier(0); single barrier at end.
#define WINDOW(Qm, Qn, STAGE_STMT, VM_STMT, LK0, LK1) do {                      \
    STAGE_STMT;                                                                 \
    VM_STMT;                                                                    \
    __builtin_amdgcn_s_setprio(1);                                              \
    GK(Qm, Qn, 0);                                                              \
    __builtin_amdgcn_sched_barrier(0);                                          \
    LK0;                                                                        \
    __builtin_amdgcn_sched_barrier(0);                                          \
    GK(Qm, Qn, 1);                                                              \
    __builtin_amdgcn_sched_barrier(0);                                          \
    LK1;                                                                        \
    __builtin_amdgcn_s_setprio(0);                                              \
    __builtin_amdgcn_sched_barrier(0);                                          \
    __builtin_amdgcn_s_barrier();                                               \
} while (0)

    const int nkt = K >> 6;           // 64-wide K-tiles (even for all layers)
    // prologue: buf0 = tile0 full; buf1 h0 = tile1 {A,B}; then first reads
    STA(0, 0, 0); STA(0, 1, 0); STB(0, 0, 0); STB(0, 1, 0);
    STA(1, 0, 1); STB(1, 0, 1);
    asm volatile("s_waitcnt vmcnt(4)" ::: "memory");   // buf0's 8 loads landed
    __builtin_amdgcn_s_barrier();
    LAk(0, 1, 0); LAk(0, 1, 1); LBk(0, 0, 0); LBk(0, 0, 1);  // regs for window 1

    const int niter = nkt >> 1;
    for (int it = 0; it < niter; ++it) {
        const int t1 = 2 * it + 1;
        const int t2 = (2 * it + 2 < nkt) ? 2 * it + 2 : nkt - 1;  // clamped: dead stages
        const int t3 = (2 * it + 3 < nkt) ? 2 * it + 3 : nkt - 1;
        WINDOW(1, 0, STA(1, 1, t1), ((void)0), LAk(0, 0, 0), LAk(0, 0, 1));
        WINDOW(0, 0, STB(1, 1, t1), ((void)0), LBk(0, 1, 0), LBk(0, 1, 1));
        WINDOW(0, 1, STA(0, 0, t2), ((void)0), LAk(0, 1, 0), LAk(0, 1, 1));
        WINDOW(1, 1, STB(0, 0, t2),
               asm volatile("s_waitcnt vmcnt(4)" ::: "memory"),
               LAk(1, 1, 0); LBk(1, 0, 0), LAk(1, 1, 1); LBk(1, 0, 1));
        WINDOW(1, 0, STA(0, 1, t2), ((void)0), LAk(1, 0, 0), LAk(1, 0, 1));
        WINDOW(0, 0, STB(0, 1, t2), ((void)0), LBk(1, 1, 0), LBk(1, 1, 1));
        WINDOW(0, 1, STA(1, 0, t3), ((void)0), LAk(1, 1, 0), LAk(1, 1, 1));
        WINDOW(1, 1, STB(1, 0, t3),
               asm volatile("s_waitcnt vmcnt(4)" ::: "memory"),
               LAk(0, 1, 0); LBk(0, 0, 0), LAk(0, 1, 1); LBk(0, 0, 1));
    }
    asm volatile("s_waitcnt vmcnt(0)" ::: "memory");   // drain tail stages

    // epilogue. C/D (m89-verified): col = lane&15 (B side), row = (lane>>4)*4+jj
    const int rl = (lane >> 4) << 2;
    float bsv[2][4];
    #pragma unroll
    for (int Qn = 0; Qn < 2; ++Qn)
        #pragma unroll
        for (int nl = 0; nl < 4; ++nl)
            bsv[Qn][nl] = biasp[bn + Qn * 128 + wn1 * 64 + nl * 16 + l15];

    unsigned short* Hp = Hb + (size_t)e * plane;
    #pragma unroll
    for (int Qm = 0; Qm < 2; ++Qm)
    #pragma unroll
    for (int ml = 0; ml < 2; ++ml)
    #pragma unroll
    for (int jj = 0; jj < 4; ++jj) {
        int srow = bm + Qm * 128 + wl3 * 32 + ml * 16 + rl + jj;
        size_t ro = (size_t)srow * N;
        #pragma unroll
        for (int Qn = 0; Qn < 2; ++Qn)
        #pragma unroll
        for (int nl = 0; nl < 4; ++nl) {
            int col = bn + Qn * 128 + wn1 * 64 + nl * 16 + l15;
            float v = acc[Qm][ml][Qn][nl][jj] + bsv[Qn][nl];
            if (ACT) v = v > 0.f ? v : 0.2f * v;
            Hp[ro + col] = f2bf(v);
        }
    }
#undef WINDOW
#undef GK
#undef LAk
#undef LBk
#undef STA
#undef STB
}

// ---------------- host launch ----------------

extern "C" void kernel_launch(void* const* d_in, const int* in_sizes, int n_in,
                              void* d_out, int out_size, void* d_ws, size_t ws_size,
                              hipStream_t stream)
{
    const float* x     = (const float*)d_in[0];
    // d_in[1] = gate (unused by reference forward)
    const float* probs = (const float*)d_in[2];
    const int*   tidx  = (const int*)d_in[3];
    const float* W1    = (const float*)d_in[4];
    const float* b1    = (const float*)d_in[5];
    const float* W2    = (const float*)d_in[6];
    const float* b2    = (const float*)d_in[7];
    const float* W3    = (const float*)d_in[8];
    const float* b3    = (const float*)d_in[9];
    float* out = (float*)d_out;

    // workspace layout (bytes); total ~340 MB of the 512 MiB d_ws.
    // lst and cnt are ADJACENT so one memset zeroes both (list pad slots
    // must be token 0; cnt must start at 0).
    char* ws = (char*)d_ws;
    const size_t xb_off  = 0;
    const size_t w1t_off = xb_off  + (size_t)B_TOK * IN_DIM * 2;
    const size_t w2t_off = w1t_off + (size_t)NEXP * IN_DIM * H1_DIM * 2;
    const size_t w3t_off = w2t_off + (size_t)NEXP * H1_DIM * H2_DIM * 2;
    const size_t h1_off  = w3t_off + (size_t)NEXP * H2_DIM * D_DIM * 2;
    const size_t h2_off  = h1_off  + (size_t)NEXP * B_TOK * H1_DIM * 2;
    const size_t y_off   = h2_off  + (size_t)NEXP * B_TOK * H2_DIM * 2;
    const size_t li_off  = y_off   + (size_t)NEXP * B_TOK * D_DIM * 2;   // y bf16
    const size_t cn_off  = li_off  + (size_t)NEXP * B_TOK * 4;
    const size_t iv_off  = cn_off  + 256;

    unsigned short* xb  = (unsigned short*)(ws + xb_off);
    unsigned short* W1t = (unsigned short*)(ws + w1t_off);
    unsigned short* W2t = (unsigned short*)(ws + w2t_off);
    unsigned short* W3t = (unsigned short*)(ws + w3t_off);
    unsigned short* h1  = (unsigned short*)(ws + h1_off);
    unsigned short* h2  = (unsigned short*)(ws + h2_off);
    unsigned short* y   = (unsigned short*)(ws + y_off);
    int*            lst = (int*)(ws + li_off);
    int*            cnt = (int*)(ws + cn_off);
    int*            inv = (int*)(ws + iv_off);

    // zero list + cnt in one shot (192 KB + 256 B)
    hipMemsetAsync(lst, 0, (size_t)NEXP * B_TOK * 4 + 256, stream);

    // fused prepass: convert x || transpose W1/W2/W3 || route tokens
    prepass<<<4416, 256, 0, stream>>>(x, xb, W1, W2, W3, W1t, W2t, W3t,
                                      probs, tidx, cnt, lst, inv);

    const size_t h1pl = (size_t)B_TOK * H1_DIM;
    const size_t h2pl = (size_t)B_TOK * H2_DIM;
    const size_t ypl  = (size_t)B_TOK * D_DIM;

    // L1 grouped across experts: gathered x rows -> h1 planes (bf16)
    gemm8<1, 1><<<dim3(NEXP * 64 * 4), 512, 0, stream>>>(
        xb, 0, W1t, b1, h1, h1pl,
        lst, cnt, H1_DIM, IN_DIM, 4, 0);
    // L2 grouped: h1 planes -> h2 planes (bf16)
    gemm8<1, 0><<<dim3(NEXP * 64 * 2), 512, 0, stream>>>(
        h1, h1pl, W2t, b2, h2, h2pl,
        lst, cnt, H2_DIM, H1_DIM, 2, 0);
    // L3 grouped: h2 planes -> compact y planes (bf16, bias applied, no weight)
    gemm8<0, 0><<<dim3(NEXP * 64 * 4), 512, 0, stream>>>(
        h2, h2pl, W3t, b3, y, ypl,
        lst, cnt, D_DIM, H2_DIM, 4, 0);
    // combine: out[tok] = p0*y[i0][slot0] + p1*y[i1][slot1]
    combine_out<<<dim3(B_TOK * 128 / 256), 256, 0, stream>>>(
        probs, tidx, inv, y, ypl, out);
}

// Round 12
// 272.429 us; speedup vs baseline: 1.9590x; 1.0155x over previous
//
#include <hip/hip_runtime.h>
#include <cstdint>
#include <cstddef>

// Problem constants (match reference setup_inputs)
#define B_TOK   16384
#define IN_DIM  2048
#define D_DIM   1024
#define NEXP    3
#define TOPK    2
#define H1_DIM  1024
#define H2_DIM  512

typedef __bf16 bf16x8 __attribute__((ext_vector_type(8)));
typedef float  f32x4  __attribute__((ext_vector_type(4)));
typedef unsigned short ushort8_t __attribute__((ext_vector_type(8)));

__device__ __forceinline__ unsigned short f2bf(float f) {
    unsigned int u = __builtin_bit_cast(unsigned int, f);
    return (unsigned short)((u + 0x7fffu + ((u >> 16) & 1u)) >> 16);
}
__device__ __forceinline__ float bf2f(unsigned short v) {
    return __builtin_bit_cast(float, (unsigned int)v << 16);
}

// async global->LDS, 16B per lane. LDS dest is wave-uniform base + lane*16;
// global source address IS per-lane (enables gather + inverse-swizzle).
__device__ __forceinline__ void glds16(const void* gsrc, void* ldst) {
    __builtin_amdgcn_global_load_lds(
        (__attribute__((address_space(1))) void*)(gsrc),
        (__attribute__((address_space(3))) void*)(ldst),
        16, 0, 0);
}

// shared 64x64 transpose-tile body (256 threads), tile scratch provided
__device__ __forceinline__ void transpose_tile_256(
    const float* __restrict__ Wp, unsigned short* __restrict__ Wtp,
    int K, int N, int n0, int k0, int t, unsigned short (*tile)[68])
{
    int nn = (t & 15) * 4;
    int kk = t >> 4;
    #pragma unroll
    for (int rr = 0; rr < 4; ++rr) {
        int k = kk + rr * 16;
        float4 v = *(const float4*)(Wp + (size_t)(k0 + k) * N + (n0 + nn));
        tile[k][nn + 0] = f2bf(v.x);
        tile[k][nn + 1] = f2bf(v.y);
        tile[k][nn + 2] = f2bf(v.z);
        tile[k][nn + 3] = f2bf(v.w);
    }
    __syncthreads();
    int n  = t >> 2;
    int kb = (t & 3) * 16;
    ushort8_t o0, o1;
    #pragma unroll
    for (int i = 0; i < 8; ++i) o0[i] = tile[kb + i][n];
    #pragma unroll
    for (int i = 0; i < 8; ++i) o1[i] = tile[kb + 8 + i][n];
    unsigned short* dst = Wtp + (size_t)(n0 + n) * K + (k0 + kb);
    *(ushort8_t*)dst = o0;
    *(ushort8_t*)(dst + 8) = o1;
}

// ---------------- fused prepass ----------------
// blocks [0,2048)      : x f32 -> bf16 (grid-stride)
// blocks [2048,3584)   : W1 [E][K][N] f32 -> [E][N][K] bf16 transpose
// blocks [3584,3648)   : token routing (cnt/list/inv); list pre-zeroed by
//                        host-side memset, so pad slots already hold token 0.
// W2/W3 transposes ride inside the L1 GEMM launch (idle-CU capacity).
__global__ __launch_bounds__(256) void prepass(
    const float* __restrict__ x, unsigned short* __restrict__ xb,
    const float* __restrict__ W1s, unsigned short* __restrict__ W1d,
    const int* __restrict__ tidx,
    int* __restrict__ cnt, int* __restrict__ list, int* __restrict__ inv)
{
    const int bid = blockIdx.x;
    const int t = threadIdx.x;

    if (bid < 2048) {
        // ---- convert x ----
        const size_t n = (size_t)B_TOK * IN_DIM;
        const size_t stride = (size_t)2048 * 256 * 8;
        size_t i = ((size_t)bid * 256 + t) * 8;
        for (; i < n; i += stride) {
            float4 a = *(const float4*)(x + i);
            float4 b = *(const float4*)(x + i + 4);
            ushort8_t o;
            o[0] = f2bf(a.x); o[1] = f2bf(a.y); o[2] = f2bf(a.z); o[3] = f2bf(a.w);
            o[4] = f2bf(b.x); o[5] = f2bf(b.y); o[6] = f2bf(b.z); o[7] = f2bf(b.w);
            *(ushort8_t*)(xb + i) = o;
        }
    } else if (bid < 3584) {
        // ---- transpose W1 (512 tiles/expert) ----
        __shared__ unsigned short tile[64][68];
        int g = bid - 2048;
        int e = g / 512;
        int r = g % 512;
        const int ntx = H1_DIM >> 6;   // 16
        int n0 = (r % ntx) * 64, k0 = (r / ntx) * 64;
        transpose_tile_256(W1s + (size_t)e * IN_DIM * H1_DIM,
                           W1d + (size_t)e * H1_DIM * IN_DIM,
                           IN_DIM, H1_DIM, n0, k0, t, tile);
    } else {
        // ---- route tokens ----
        __shared__ int lcnt[NEXP];
        __shared__ int lbase[NEXP];
        __shared__ int ltok[NEXP][256];
        int b = (bid - 3584) * 256 + t;
        if (t < NEXP) lcnt[t] = 0;
        __syncthreads();
        int i0 = tidx[b * TOPK + 0], i1 = tidx[b * TOPK + 1];
        #pragma unroll
        for (int e = 0; e < NEXP; ++e) {
            if (i0 == e || i1 == e) {
                int s = atomicAdd(&lcnt[e], 1);
                ltok[e][s] = b;
            }
        }
        __syncthreads();
        if (t < NEXP) lbase[t] = atomicAdd(&cnt[t], lcnt[t]);
        __syncthreads();
        #pragma unroll
        for (int e = 0; e < NEXP; ++e) {
            int n = lcnt[e], base = lbase[e];
            for (int s = t; s < n; s += 256) {
                int tk = ltok[e][s];
                list[e * B_TOK + base + s] = tk;
                inv[e * B_TOK + tk] = base + s;
            }
        }
    }
}

// combine: out[tok] = p0 * y[i0][inv[i0][tok]] + p1 * y[i1][inv[i1][tok]]
// y planes are bf16. Handles i0==i1 naturally. Writes EVERY output element.
__global__ __launch_bounds__(256) void combine_out(
    const float* __restrict__ probs, const int* __restrict__ tidx,
    const int* __restrict__ inv, const unsigned short* __restrict__ y, size_t ypl,
    float* __restrict__ out)
{
    int gid = blockIdx.x * 256 + threadIdx.x;
    int tok = gid >> 7;              // 128 threads per token
    int dc  = (gid & 127) << 3;      // 8 cols per thread
    float p0 = probs[tok * TOPK + 0], p1 = probs[tok * TOPK + 1];
    int   i0 = tidx [tok * TOPK + 0], i1 = tidx [tok * TOPK + 1];
    size_t r0 = (size_t)i0 * ypl + (size_t)inv[(size_t)i0 * B_TOK + tok] * D_DIM + dc;
    size_t r1 = (size_t)i1 * ypl + (size_t)inv[(size_t)i1 * B_TOK + tok] * D_DIM + dc;
    ushort8_t a = *(const ushort8_t*)(y + r0);
    ushort8_t b = *(const ushort8_t*)(y + r1);
    float4 o0, o1;
    o0.x = p0 * bf2f(a[0]) + p1 * bf2f(b[0]);
    o0.y = p0 * bf2f(a[1]) + p1 * bf2f(b[1]);
    o0.z = p0 * bf2f(a[2]) + p1 * bf2f(b[2]);
    o0.w = p0 * bf2f(a[3]) + p1 * bf2f(b[3]);
    o1.x = p0 * bf2f(a[4]) + p1 * bf2f(b[4]);
    o1.y = p0 * bf2f(a[5]) + p1 * bf2f(b[5]);
    o1.z = p0 * bf2f(a[6]) + p1 * bf2f(b[6]);
    o1.w = p0 * bf2f(a[7]) + p1 * bf2f(b[7]);
    float* op = out + (size_t)tok * D_DIM + dc;
    *(float4*)op = o0;
    *(float4*)(op + 4) = o1;
}

// ---------------- 8-window 256x256 GEMM, k-split interleaved ----------------
// C = act(A[slots,K] @ Bt[N,K]^T + bias) -> bf16 planes.
// EXACT round-8/10/11 passing GEMM (frozen; 8 consistent measurements at
// 42-43% MfmaUtil -> structural ceiling under the 256-reg/2-wave cap).
// XTRA=1 (L1 launch only): blocks [NTOT, NTOT+384) each transpose TWO 64x64
// W2/W3 tiles (f32->bf16, [E][K][N]->[E][N][K]) reusing smem as scratch.
// They dispatch after the GEMM blocks and ride idle-CU capacity (L1 fill is
// 84%); stream order guarantees W2t/W3t are complete before L2/L3 launch.
template<int ACT, int GATHER, int XTRA>
__global__ __launch_bounds__(512, 2) void gemm8(
    const unsigned short* __restrict__ Ab, size_t Aplane,  // bf16 [slots][K] (per-expert plane if !GATHER)
    const unsigned short* __restrict__ Bb,                 // bf16 [E][N][K]
    const float* __restrict__ biasb,                       // [E][N]
    unsigned short* __restrict__ Hb,                       // bf16 planes out
    size_t plane,                                          // elements per plane
    const int* __restrict__ listb,                         // [E][B_TOK]
    const int* __restrict__ cntb,                          // [E] actual count
    int N, int K, int NT, int e0, int NTOT,
    const float* __restrict__ W2s, const float* __restrict__ W3s,
    unsigned short* __restrict__ W2d, unsigned short* __restrict__ W3d)
{
    __shared__ char smem[131072];   // GEMM: A [0,64K) B [64K,128K); XTRA: tiles

    const int bid  = blockIdx.x;
    const int tid  = threadIdx.x;

    if constexpr (XTRA) {
        if (bid >= NTOT) {
            // two 64x64 transpose tiles per block (threads 0-255 / 256-511)
            int half = tid >> 8;
            int t    = tid & 255;
            int g = (bid - NTOT) * 2 + half;   // [0,768): 384 W2 then 384 W3
            const float* W; unsigned short* Wt; int K2, N2, e, r;
            if (g < 384) { e = g / 128; r = g % 128; W = W2s; Wt = W2d; K2 = H1_DIM; N2 = H2_DIM; }
            else { g -= 384; e = g / 128; r = g % 128; W = W3s; Wt = W3d; K2 = H2_DIM; N2 = D_DIM; }
            const int ntx = N2 >> 6;
            int n0 = (r % ntx) * 64, k0 = (r / ntx) * 64;
            unsigned short (*tile)[68] = (unsigned short(*)[68])(smem + half * 8704);
            transpose_tile_256(W + (size_t)e * K2 * N2, Wt + (size_t)e * N2 * K2,
                               K2, N2, n0, k0, t, tile);
            return;
        }
    }

    // bijective tile->XCD mapping: xcd=bid&7; XCD x walks A-tiles {x,x+8,...}
    // with the NT N-blocks of each A-tile consecutive (L2 A-reuse); live
    // tiles (early-exit) spread evenly across XCDs.
    const int xcd  = bid & 7;
    const int slot = bid >> 3;
    const int q    = slot / NT;
    const int nt   = slot % NT;
    const int ti   = q * 8 + xcd;
    const int e    = e0 + (ti >> 6);
    const int mt   = ti & 63;
    const int bm   = mt << 8;
    const int cp   = (cntb[e] + 255) & ~255;   // padded count, inline
    if (bm >= cp) return;
    const int bn   = nt << 8;

    const int lane = tid & 63;
    const int w    = tid >> 6;      // wave 0..7
    const int wl3  = w & 3;         // A 32-row band within half
    const int wn1  = w >> 2;        // B 64-col band within half
    const int l15  = lane & 15;
    const int ug8  = (((tid & 7) ^ ((tid >> 3) & 7)) << 3);          // src swz (shorts)
    const int sw0  = ((((lane >> 4) + 0) ^ (lane & 7)) << 4);        // read swz k0 (bytes)
    const int sw1  = ((((lane >> 4) + 4) ^ (lane & 7)) << 4);        // read swz k1 (bytes)

    const int* listp = listb + (size_t)e * B_TOK;
    const unsigned short* Ae = Ab + (size_t)e * Aplane;
    const unsigned short* Be = Bb + (size_t)e * ((size_t)N * K);
    const float* biasp = biasb + (size_t)e * N;

    // per-thread stage source pointers: half h, load j covers tile row
    // h*128 + j*64 + (tid>>3); 16B unit = (tid&7) ^ ((tid>>3)&7)  (inverse swz)
    const unsigned short* sA[2][2];
    const unsigned short* sB[2][2];
    #pragma unroll
    for (int h = 0; h < 2; ++h)
        #pragma unroll
        for (int j = 0; j < 2; ++j) {
            int lrow = h * 128 + j * 64 + (tid >> 3);
            int arow;
            if constexpr (GATHER) arow = listp[bm + lrow];
            else                  arow = bm + lrow;
            sA[h][j] = Ae + (size_t)arow * K + ug8;
            sB[h][j] = Be + (size_t)(bn + lrow) * K + ug8;
        }

    char* const stA = smem + (w << 10);            // + db*32768 + h*16384 (+8192 for j=1)
    char* const stB = smem + 65536 + (w << 10);
    const char* const rA = smem + (wl3 * 32 + l15) * 128;           // + db*32768 + Qm*16384 + ml*2048 + sw
    const char* const rB = smem + 65536 + (wn1 * 64 + l15) * 128;   // + db*32768 + Qn*16384 + nl*2048 + sw

    f32x4 acc[2][2][2][4] = {};   // [Qm][ml][Qn][nl]
    bf16x8 av[2][2];              // A operand regs [ml][k]
    bf16x8 bv[4][2];              // B operand regs [nl][k]

#define STA(db, h, kt) do {                                                     \
    glds16(sA[h][0] + (size_t)(kt) * 64, stA + (db) * 32768 + (h) * 16384);     \
    glds16(sA[h][1] + (size_t)(kt) * 64, stA + (db) * 32768 + (h) * 16384 + 8192); } while (0)
#define STB(db, h, kt) do {                                                     \
    glds16(sB[h][0] + (size_t)(kt) * 64, stB + (db) * 32768 + (h) * 16384);     \
    glds16(sB[h][1] + (size_t)(kt) * 64, stB + (db) * 32768 + (h) * 16384 + 8192); } while (0)

// k-sliced operand loads (2 reads for A-slice, 4 for B-slice)
#define LAk(db, Qm, kk) do {                                                    \
    _Pragma("unroll")                                                           \
    for (int ml = 0; ml < 2; ++ml)                                              \
        av[ml][kk] = *(const bf16x8*)(rA + (db)*32768 + (Qm)*16384 + ml*2048    \
                                      + ((kk) ? sw1 : sw0));                    \
    } while (0)
#define LBk(db, Qn, kk) do {                                                    \
    _Pragma("unroll")                                                           \
    for (int nl = 0; nl < 4; ++nl)                                              \
        bv[nl][kk] = *(const bf16x8*)(rB + (db)*32768 + (Qn)*16384 + nl*2048    \
                                      + ((kk) ? sw1 : sw0));                    \
    } while (0)

// 8-MFMA group for one k-slice of quadrant (Qm,Qn)
#define GK(Qm, Qn, kk) do {                                                     \
    _Pragma("unroll")                                                           \
    for (int ml = 0; ml < 2; ++ml)                                              \
        _Pragma("unroll")                                                       \
        for (int nl = 0; nl < 4; ++nl)                                          \
            acc[Qm][ml][Qn][nl] = __builtin_amdgcn_mfma_f32_16x16x32_bf16(      \
                av[ml][kk], bv[nl][kk], acc[Qm][ml][Qn][nl], 0, 0, 0);          \
    } while (0)

// window: stage; [counted vmcnt]; then k-split MFMA with next-window loads
// pinned mid-cluster via sched_barrier(0); single barrier at end.
#define WINDOW(Qm, Qn, STAGE_STMT, VM_STMT, LK0, LK1) do {                      \
    STAGE_STMT;                                                                 \
    VM_STMT;                                                                    \
    __builtin_amdgcn_s_setprio(1);                                              \
    GK(Qm, Qn, 0);                                                              \
    __builtin_amdgcn_sched_barrier(0);                                          \
    LK0;                                                                        \
    __builtin_amdgcn_sched_barrier(0);                                          \
    GK(Qm, Qn, 1);                                                              \
    __builtin_amdgcn_sched_barrier(0);                                          \
    LK1;                                                                        \
    __builtin_amdgcn_s_setprio(0);                                              \
    __builtin_amdgcn_sched_barrier(0);                                          \
    __builtin_amdgcn_s_barrier();                                               \
} while (0)

    const int nkt = K >> 6;           // 64-wide K-tiles (even for all layers)
    // prologue: buf0 = tile0 full; buf1 h0 = tile1 {A,B}; then first reads
    STA(0, 0, 0); STA(0, 1, 0); STB(0, 0, 0); STB(0, 1, 0);
    STA(1, 0, 1); STB(1, 0, 1);
    asm volatile("s_waitcnt vmcnt(4)" ::: "memory");   // buf0's 8 loads landed
    __builtin_amdgcn_s_barrier();
    LAk(0, 1, 0); LAk(0, 1, 1); LBk(0, 0, 0); LBk(0, 0, 1);  // regs for window 1

    const int niter = nkt >> 1;
    for (int it = 0; it < niter; ++it) {
        const int t1 = 2 * it + 1;
        const int t2 = (2 * it + 2 < nkt) ? 2 * it + 2 : nkt - 1;  // clamped: dead stages
        const int t3 = (2 * it + 3 < nkt) ? 2 * it + 3 : nkt - 1;
        WINDOW(1, 0, STA(1, 1, t1), ((void)0), LAk(0, 0, 0), LAk(0, 0, 1));
        WINDOW(0, 0, STB(1, 1, t1), ((void)0), LBk(0, 1, 0), LBk(0, 1, 1));
        WINDOW(0, 1, STA(0, 0, t2), ((void)0), LAk(0, 1, 0), LAk(0, 1, 1));
        WINDOW(1, 1, STB(0, 0, t2),
               asm volatile("s_waitcnt vmcnt(4)" ::: "memory"),
               LAk(1, 1, 0); LBk(1, 0, 0), LAk(1, 1, 1); LBk(1, 0, 1));
        WINDOW(1, 0, STA(0, 1, t2), ((void)0), LAk(1, 0, 0), LAk(1, 0, 1));
        WINDOW(0, 0, STB(0, 1, t2), ((void)0), LBk(1, 1, 0), LBk(1, 1, 1));
        WINDOW(0, 1, STA(1, 0, t3), ((void)0), LAk(1, 1, 0), LAk(1, 1, 1));
        WINDOW(1, 1, STB(1, 0, t3),
               asm volatile("s_waitcnt vmcnt(4)" ::: "memory"),
               LAk(0, 1, 0); LBk(0, 0, 0), LAk(0, 1, 1); LBk(0, 0, 1));
    }
    asm volatile("s_waitcnt vmcnt(0)" ::: "memory");   // drain tail stages

    // epilogue. C/D (m89-verified): col = lane&15 (B side), row = (lane>>4)*4+jj
    const int rl = (lane >> 4) << 2;
    float bsv[2][4];
    #pragma unroll
    for (int Qn = 0; Qn < 2; ++Qn)
        #pragma unroll
        for (int nl = 0; nl < 4; ++nl)
            bsv[Qn][nl] = biasp[bn + Qn * 128 + wn1 * 64 + nl * 16 + l15];

    unsigned short* Hp = Hb + (size_t)e * plane;
    #pragma unroll
    for (int Qm = 0; Qm < 2; ++Qm)
    #pragma unroll
    for (int ml = 0; ml < 2; ++ml)
    #pragma unroll
    for (int jj = 0; jj < 4; ++jj) {
        int srow = bm + Qm * 128 + wl3 * 32 + ml * 16 + rl + jj;
        size_t ro = (size_t)srow * N;
        #pragma unroll
        for (int Qn = 0; Qn < 2; ++Qn)
        #pragma unroll
        for (int nl = 0; nl < 4; ++nl) {
            int col = bn + Qn * 128 + wn1 * 64 + nl * 16 + l15;
            float v = acc[Qm][ml][Qn][nl][jj] + bsv[Qn][nl];
            if (ACT) v = v > 0.f ? v : 0.2f * v;
            Hp[ro + col] = f2bf(v);
        }
    }
#undef WINDOW
#undef GK
#undef LAk
#undef LBk
#undef STA
#undef STB
}

// ---------------- host launch ----------------

extern "C" void kernel_launch(void* const* d_in, const int* in_sizes, int n_in,
                              void* d_out, int out_size, void* d_ws, size_t ws_size,
                              hipStream_t stream)
{
    const float* x     = (const float*)d_in[0];
    // d_in[1] = gate (unused by reference forward)
    const float* probs = (const float*)d_in[2];
    const int*   tidx  = (const int*)d_in[3];
    const float* W1    = (const float*)d_in[4];
    const float* b1    = (const float*)d_in[5];
    const float* W2    = (const float*)d_in[6];
    const float* b2    = (const float*)d_in[7];
    const float* W3    = (const float*)d_in[8];
    const float* b3    = (const float*)d_in[9];
    float* out = (float*)d_out;

    // workspace layout (bytes); total ~340 MB of the 512 MiB d_ws.
    // lst and cnt are ADJACENT so one memset zeroes both (list pad slots
    // must be token 0; cnt must start at 0).
    char* ws = (char*)d_ws;
    const size_t xb_off  = 0;
    const size_t w1t_off = xb_off  + (size_t)B_TOK * IN_DIM * 2;
    const size_t w2t_off = w1t_off + (size_t)NEXP * IN_DIM * H1_DIM * 2;
    const size_t w3t_off = w2t_off + (size_t)NEXP * H1_DIM * H2_DIM * 2;
    const size_t h1_off  = w3t_off + (size_t)NEXP * H2_DIM * D_DIM * 2;
    const size_t h2_off  = h1_off  + (size_t)NEXP * B_TOK * H1_DIM * 2;
    const size_t y_off   = h2_off  + (size_t)NEXP * B_TOK * H2_DIM * 2;
    const size_t li_off  = y_off   + (size_t)NEXP * B_TOK * D_DIM * 2;   // y bf16
    const size_t cn_off  = li_off  + (size_t)NEXP * B_TOK * 4;
    const size_t iv_off  = cn_off  + 256;

    unsigned short* xb  = (unsigned short*)(ws + xb_off);
    unsigned short* W1t = (unsigned short*)(ws + w1t_off);
    unsigned short* W2t = (unsigned short*)(ws + w2t_off);
    unsigned short* W3t = (unsigned short*)(ws + w3t_off);
    unsigned short* h1  = (unsigned short*)(ws + h1_off);
    unsigned short* h2  = (unsigned short*)(ws + h2_off);
    unsigned short* y   = (unsigned short*)(ws + y_off);
    int*            lst = (int*)(ws + li_off);
    int*            cnt = (int*)(ws + cn_off);
    int*            inv = (int*)(ws + iv_off);

    // zero list + cnt in one shot (192 KB + 256 B)
    hipMemsetAsync(lst, 0, (size_t)NEXP * B_TOK * 4 + 256, stream);

    // fused prepass: convert x || transpose W1 || route tokens
    prepass<<<3648, 256, 0, stream>>>(x, xb, W1, W1t, tidx, cnt, lst, inv);

    const size_t h1pl = (size_t)B_TOK * H1_DIM;
    const size_t h2pl = (size_t)B_TOK * H2_DIM;
    const size_t ypl  = (size_t)B_TOK * D_DIM;

    // L1 grouped across experts: gathered x rows -> h1 planes (bf16).
    // +384 trailing blocks transpose W2/W3 on idle CUs during the GEMM.
    gemm8<1, 1, 1><<<dim3(NEXP * 64 * 4 + 384), 512, 0, stream>>>(
        xb, 0, W1t, b1, h1, h1pl,
        lst, cnt, H1_DIM, IN_DIM, 4, 0, NEXP * 64 * 4,
        W2, W3, W2t, W3t);
    // L2 grouped: h1 planes -> h2 planes (bf16)
    gemm8<1, 0, 0><<<dim3(NEXP * 64 * 2), 512, 0, stream>>>(
        h1, h1pl, W2t, b2, h2, h2pl,
        lst, cnt, H2_DIM, H1_DIM, 2, 0, NEXP * 64 * 2,
        nullptr, nullptr, nullptr, nullptr);
    // L3 grouped: h2 planes -> compact y planes (bf16, bias applied, no weight)
    gemm8<0, 0, 0><<<dim3(NEXP * 64 * 4), 512, 0, stream>>>(
        h2, h2pl, W3t, b3, y, ypl,
        lst, cnt, D_DIM, H2_DIM, 4, 0, NEXP * 64 * 4,
        nullptr, nullptr, nullptr, nullptr);
    // combine: out[tok] = p0*y[i0][slot0] + p1*y[i1][slot1]
    combine_out<<<dim3(B_TOK * 128 / 256), 256, 0, stream>>>(
        probs, tidx, inv, y, ypl, out);
}